// Round 5
// baseline (414.780 us; speedup 1.0000x reference)
//
#include <hip/hip_runtime.h>
#include <hip/hip_bf16.h>
#include <math.h>

typedef __attribute__((ext_vector_type(8))) short short8;
typedef __attribute__((ext_vector_type(4))) float f32x4;

#define DIM 256
#define NROWS 32768      // T*B*Ltot rows
#define PERT 2097152     // B*Ltot*D elements per timestep
#define SAMP_TOK 4096    // tokens per (t,b) sample

__device__ __forceinline__ float b2f(__hip_bfloat16 h){ return __bfloat162float(h); }
__device__ __forceinline__ __hip_bfloat16 f2b(float f){ return __float2bfloat16(f); }
__device__ __forceinline__ unsigned short f2bu(float f){
  __hip_bfloat16 h = __float2bfloat16(f);
  unsigned short u; __builtin_memcpy(&u, &h, 2); return u;
}

// async global -> LDS, 16B per lane (wave-uniform base + lane*16 on LDS side)
#define GLD_LDS16(gp, lp) __builtin_amdgcn_global_load_lds( \
    (const __attribute__((address_space(1))) unsigned int*)(gp), \
    (__attribute__((address_space(3))) unsigned int*)(lp), 16, 0, 0)

// branchless erf-based exact gelu (A&S 7.1.26, |err| <= ~3e-7: below bf16 ulp)
__device__ __forceinline__ float gelu_fast(float v){
  float z  = v * 0.70710678118654752f;
  float az = fabsf(z);
  float t  = __builtin_amdgcn_rcpf(fmaf(0.3275911f, az, 1.0f));
  float p  = fmaf(fmaf(fmaf(fmaf(1.061405429f, t, -1.453152027f), t,
                            1.421413741f), t, -0.284496736f), t, 0.254829592f);
  p *= t;
  float e  = __expf(-z * z);
  float y  = fmaf(-p, e, 1.0f);                 // erf(|z|)
  return fmaf(0.5f * fabsf(v), y, 0.5f * v);    // 0.5*v*(1+sign(v)*erf(|z|))
}

// ---------------- fp32 -> bf16 weight conversion (all 4 weights, one launch) ---
__global__ void f2ball_k(const float* __restrict__ w_qkv, const float* __restrict__ w_proj,
                         const float* __restrict__ w_f1, const float* __restrict__ w_f2,
                         __hip_bfloat16* __restrict__ o_qkv, __hip_bfloat16* __restrict__ o_proj,
                         __hip_bfloat16* __restrict__ o_f1, __hip_bfloat16* __restrict__ o_f2){
  int i = blockIdx.x * 256 + threadIdx.x;        // 0 .. 786431
  if (i < 196608)          o_qkv[i]           = f2b(w_qkv[i]);
  else if (i < 262144)     o_proj[i - 196608] = f2b(w_proj[i - 196608]);
  else if (i < 524288)     o_f1[i - 262144]   = f2b(w_f1[i - 262144]);
  else                     o_f2[i - 524288]   = f2b(w_f2[i - 524288]);
}

// ---------------- BN stats: per-channel sum / sumsq over 32768 tokens ----------
// Vectorized: thread = (row-subset r = t>>6, 4-channel group g = t&63); float4
// loads (16B/lane, coalesced 1KB/wave); LDS 4-way reduce; 1 atomic pair/channel.
__global__ void bn_stats_k(const float* __restrict__ x, float* __restrict__ sum, float* __restrict__ sumsq){
  __shared__ __align__(16) float rs[4][256];
  __shared__ __align__(16) float rq[4][256];
  int t = threadIdx.x;
  int g = t & 63, r = t >> 6;
  size_t base = ((size_t)blockIdx.x * 128 + r) * DIM + g * 4;   // 128 rows per block
  float4 s = {0.f,0.f,0.f,0.f}, q = {0.f,0.f,0.f,0.f};
  for (int i = 0; i < 32; ++i){
    float4 v = *reinterpret_cast<const float4*>(x + base + (size_t)i * 4 * DIM);
    s.x += v.x; s.y += v.y; s.z += v.z; s.w += v.w;
    q.x += v.x*v.x; q.y += v.y*v.y; q.z += v.z*v.z; q.w += v.w*v.w;
  }
  *reinterpret_cast<float4*>(&rs[r][g*4]) = s;
  *reinterpret_cast<float4*>(&rq[r][g*4]) = q;
  __syncthreads();
  int c = t;   // one channel per thread
  atomicAdd(&sum[c],   rs[0][c] + rs[1][c] + rs[2][c] + rs[3][c]);
  atomicAdd(&sumsq[c], rq[0][c] + rq[1][c] + rq[2][c] + rq[3][c]);
}

__global__ void bn_fin_k(const float* __restrict__ sum, const float* __restrict__ sumsq,
                         const float* __restrict__ g, const float* __restrict__ b,
                         float* __restrict__ a_out, float* __restrict__ b_out){
  int c = threadIdx.x;
  float mean = sum[c] * (1.f/32768.f);
  float var  = sumsq[c] * (1.f/32768.f) - mean*mean;
  float a = g[c] / sqrtf(var + 1e-5f);
  a_out[c] = a;
  b_out[c] = b[c] - mean * a;
}

// ---------------- LIF over T=4 (binary spike out, bf16 exact) ------------------
// Vectorized 4 elems/thread: float4 reads, ushort4 writes (same arithmetic).
__global__ void lif_k(const float* __restrict__ x, const float* __restrict__ av,
                      const float* __restrict__ bv, __hip_bfloat16* __restrict__ s){
  int i = blockIdx.x * 256 + threadIdx.x;       // 0 .. PERT/4-1 (exact grid)
  int e4 = i * 4;
  int c4 = e4 & (DIM - 1);
  float4 a = *reinterpret_cast<const float4*>(av + c4);
  float4 b = *reinterpret_cast<const float4*>(bv + c4);
  float4 v = {0.f,0.f,0.f,0.f};
  #pragma unroll
  for (int t = 0; t < 4; ++t){
    float4 xn = *reinterpret_cast<const float4*>(x + (size_t)t * PERT + e4);
    xn.x = fmaf(xn.x, a.x, b.x); xn.y = fmaf(xn.y, a.y, b.y);
    xn.z = fmaf(xn.z, a.z, b.z); xn.w = fmaf(xn.w, a.w, b.w);
    v.x += (xn.x - v.x) * 0.5f; v.y += (xn.y - v.y) * 0.5f;
    v.z += (xn.z - v.z) * 0.5f; v.w += (xn.w - v.w) * 0.5f;
    ushort4 sp;
    sp.x = (v.x >= 1.0f) ? 0x3F80 : 0;  v.x = (v.x >= 1.0f) ? 0.f : v.x;
    sp.y = (v.y >= 1.0f) ? 0x3F80 : 0;  v.y = (v.y >= 1.0f) ? 0.f : v.y;
    sp.z = (v.z >= 1.0f) ? 0x3F80 : 0;  v.z = (v.z >= 1.0f) ? 0.f : v.z;
    sp.w = (v.w >= 1.0f) ? 0x3F80 : 0;  v.w = (v.w >= 1.0f) ? 0.f : v.w;
    *reinterpret_cast<ushort4*>(reinterpret_cast<unsigned short*>(s) + (size_t)t * PERT + e4) = sp;
  }
}

// ---------------- region means of binary s1 (exact fp32) -----------------------
// Vectorized: thread = (token-subset sub, 4-ch group g); ushort4 loads; spikes
// counted as (bits != 0) — exact for binary bf16 {0, 0x3F80}.
__global__ void region_sum_k(const __hip_bfloat16* __restrict__ s, float* __restrict__ sm){
  __shared__ __align__(16) float red[4][256];
  int r = blockIdx.x, t = threadIdx.x;    // r = (sample*64 + region), 512 total
  int g = t & 63, sub = t >> 6;
  const unsigned short* sp = reinterpret_cast<const unsigned short*>(s);
  size_t base = ((size_t)r * 64 + sub * 16) * DIM + g * 4;
  float4 acc = {0.f,0.f,0.f,0.f};
  for (int i = 0; i < 16; ++i){
    ushort4 u = *reinterpret_cast<const ushort4*>(sp + base + (size_t)i * DIM);
    acc.x += (u.x != 0) ? 1.f : 0.f; acc.y += (u.y != 0) ? 1.f : 0.f;
    acc.z += (u.z != 0) ? 1.f : 0.f; acc.w += (u.w != 0) ? 1.f : 0.f;
  }
  *reinterpret_cast<float4*>(&red[sub][g*4]) = acc;
  __syncthreads();
  if (sub == 0){
    float4 o;
    o.x = (red[0][g*4+0] + red[1][g*4+0] + red[2][g*4+0] + red[3][g*4+0]) * 0.015625f;
    o.y = (red[0][g*4+1] + red[1][g*4+1] + red[2][g*4+1] + red[3][g*4+1]) * 0.015625f;
    o.z = (red[0][g*4+2] + red[1][g*4+2] + red[2][g*4+2] + red[3][g*4+2]) * 0.015625f;
    o.w = (red[0][g*4+3] + red[1][g*4+3] + red[2][g*4+3] + red[3][g*4+3]) * 0.015625f;
    *reinterpret_cast<float4*>(sm + (size_t)r * DIM + g * 4) = o;
  }
}

// ---------------- routing GEMM fp32: qkm[r][j] = smr[r]·qkv_w[j] + b[j], j<512 -
__global__ void rgemm_k(const float* __restrict__ smr, const float* __restrict__ w,
                        const float* __restrict__ bias, float* __restrict__ qkm){
  __shared__ float arow[256];
  int r = blockIdx.x, t = threadIdx.x;
  arow[t] = smr[(size_t)r * 256 + t];
  __syncthreads();
  for (int j = t; j < 512; j += 256){
    const float* wr = w + (size_t)j * 256;
    float acc = 0.f;
    for (int k = 0; k < 256; ++k) acc += arow[k] * wr[k];
    qkm[(size_t)r * 512 + j] = acc + bias[j];
  }
}

// ---------------- GEMM: C[M,N] = A[M,K] @ W[N,K]^T (+bias, epilogue) -----------
// 2-phase double-buffered staging; linear LDS dest + source-side bank swizzle.
// MFMA operand-swapped: mfma(wf, af) -> lane holds row=l16, cols=quad*4+[0..3].
// bf16 epilogues (EPI 0/2) route C through wave-private LDS (dead staging buf).
// EPI 0: bf16 out = v+bias                  (qkv)
// EPI 1: f32  out = x_f32 + v*scale         (proj + residual) + FUSED bn2 stats
// EPI 2: bf16 out = gelu_exact(v+bias)      (ffn1)
// EPI 3: f32  out = x2_f32 + v*scale        (ffn2 + residual, in-place on d_out)
template<int EPI>
__global__ __launch_bounds__(256) void gemm_bt(
    const __hip_bfloat16* __restrict__ A, const __hip_bfloat16* __restrict__ W,
    const float* __restrict__ bias, void* __restrict__ outp,
    const void* __restrict__ extra, const float* __restrict__ scaleptr,
    float* __restrict__ bsum, float* __restrict__ bsq,
    int K, int N)
{
  __shared__ __align__(16) short As0[128 * 32];   // 8KB each, linear layout
  __shared__ __align__(16) short Ws0[128 * 32];
  __shared__ __align__(16) short As1[128 * 32];
  __shared__ __align__(16) short Ws1[128 * 32];
  int tid = threadIdx.x;
  int bm = blockIdx.x, bn = blockIdx.y;
  int lane = tid & 63;
  int l16 = lane & 15, quad = lane >> 4;
  int wv = tid >> 6;
  int wm = (wv >> 1) << 6, wn = (wv & 1) << 6;

  // staging: thread tid owns LDS granule tid (16B) = row tid>>2, col-block tid&3.
  // source col-block is swizzle-inverse: sq = (tid&3) ^ ((row>>1)&3).
  const int srow = tid >> 2;
  const int sq   = (tid & 3) ^ ((srow >> 1) & 3);
  const __hip_bfloat16* Ag = A + (size_t)(bm * 128 + srow) * K + (sq << 3);
  const __hip_bfloat16* Wg = W + (size_t)(bn * 128 + srow) * K + (sq << 3);
  const size_t rstep = (size_t)64 * K;

  // swizzled ds_read offsets (shorts), hoisted out of the loop
  int roA[4], roW[4];
  #pragma unroll
  for (int i = 0; i < 4; ++i){
    int Ra = wm + i * 16 + l16;
    roA[i] = Ra * 32 + ((quad ^ ((Ra >> 1) & 3)) << 3);
    int Rw = wn + i * 16 + l16;
    roW[i] = Rw * 32 + ((quad ^ ((Rw >> 1) & 3)) << 3);
  }

  f32x4 zero = {0.f, 0.f, 0.f, 0.f};
  f32x4 acc[4][4];
  #pragma unroll
  for (int i = 0; i < 4; ++i)
    #pragma unroll
    for (int j = 0; j < 4; ++j) acc[i][j] = zero;

  auto stage = [&](short* Ad, short* Wd, int k0){
    GLD_LDS16(Ag + k0,         Ad + tid * 8);
    GLD_LDS16(Ag + rstep + k0, Ad + tid * 8 + 2048);
    GLD_LDS16(Wg + k0,         Wd + tid * 8);
    GLD_LDS16(Wg + rstep + k0, Wd + tid * 8 + 2048);
  };
  auto compute = [&](const short* Asb, const short* Wsb){
    short8 af[4];
    #pragma unroll
    for (int mi = 0; mi < 4; ++mi)
      af[mi] = *reinterpret_cast<const short8*>(Asb + roA[mi]);
    #pragma unroll
    for (int ni = 0; ni < 4; ++ni){
      short8 wf = *reinterpret_cast<const short8*>(Wsb + roW[ni]);
      #pragma unroll
      for (int mi = 0; mi < 4; ++mi)
        acc[mi][ni] = __builtin_amdgcn_mfma_f32_16x16x32_bf16(wf, af[mi], acc[mi][ni], 0, 0, 0);
    }
  };

  // K is a multiple of 64 for every call site (256 or 1024)
  stage(As0, Ws0, 0);
  __syncthreads();
  for (int k0 = 0; k0 < K; k0 += 64){
    if (k0 + 32 < K) stage(As1, Ws1, k0 + 32);
    compute(As0, Ws0);
    __syncthreads();                       // drains prefetch (vmcnt 0) + barrier
    if (k0 + 64 < K) stage(As0, Ws0, k0 + 64);
    if (k0 + 32 < K) compute(As1, Ws1);
    __syncthreads();
  }

  if (EPI == 0 || EPI == 2){
    // ---- coalesced bf16 epilogue: wave-private 64x64 C-tile via dead staging LDS
    short* Cw = (wv == 0) ? As0 : (wv == 1) ? Ws0 : (wv == 2) ? As1 : Ws1;
    #pragma unroll
    for (int ni = 0; ni < 4; ++ni){
      int col0 = (bn << 7) + wn + ni * 16 + (quad << 2);
      float4 bv = *reinterpret_cast<const float4*>(bias + col0);
      #pragma unroll
      for (int mi = 0; mi < 4; ++mi){
        float v0 = acc[mi][ni][0] + bv.x;
        float v1 = acc[mi][ni][1] + bv.y;
        float v2 = acc[mi][ni][2] + bv.z;
        float v3 = acc[mi][ni][3] + bv.w;
        if (EPI == 2){
          v0 = gelu_fast(v0); v1 = gelu_fast(v1);
          v2 = gelu_fast(v2); v3 = gelu_fast(v3);
        }
        unsigned lo = (unsigned)f2bu(v0) | ((unsigned)f2bu(v1) << 16);
        unsigned hi = (unsigned)f2bu(v2) | ((unsigned)f2bu(v3) << 16);
        int row = mi * 16 + l16;                                 // 0..63 in wave tile
        int cb  = (ni * 32 + (quad << 3)) ^ ((row & 7) << 4);    // swizzled byte col
        *reinterpret_cast<uint2*>(reinterpret_cast<char*>(Cw) + row * 128 + cb) =
            make_uint2(lo, hi);
      }
    }
    asm volatile("s_waitcnt lgkmcnt(0)" ::: "memory");   // wave-internal ds drain
    #pragma unroll
    for (int p = 0; p < 8; ++p){
      int row = p * 8 + (lane >> 3);
      int cb  = ((lane & 7) << 4) ^ ((row & 7) << 4);    // un-swizzles to col (lane&7)*16B
      uint4 val = *reinterpret_cast<const uint4*>(
          reinterpret_cast<const char*>(Cw) + row * 128 + cb);
      int rowg = (bm << 7) + wm + row;
      int colg = (bn << 7) + wn + ((lane & 7) << 3);     // shorts
      *reinterpret_cast<uint4*>((__hip_bfloat16*)outp + (size_t)rowg * N + colg) = val;
    }
  } else {
    // ---- f32 epilogues: float4 stores already cover full 64B sectors per row.
    // EPI 1 additionally accumulates per-channel sum/sumsq of the stored x2
    // (fused BN2 statistics: eliminates the bn_stats re-read of 32MB).
    float sc = scaleptr[0];
    float4 ts[4], tq[4];
    if (EPI == 1){
      #pragma unroll
      for (int ni = 0; ni < 4; ++ni){ ts[ni] = {0.f,0.f,0.f,0.f}; tq[ni] = {0.f,0.f,0.f,0.f}; }
    }
    #pragma unroll
    for (int ni = 0; ni < 4; ++ni){
      int col0 = (bn << 7) + wn + ni * 16 + (quad << 2);
      float4 bv = *reinterpret_cast<const float4*>(bias + col0);
      #pragma unroll
      for (int mi = 0; mi < 4; ++mi){
        int rowg = (bm << 7) + wm + mi * 16 + l16;
        size_t off = (size_t)rowg * N + col0;
        float v0 = acc[mi][ni][0] + bv.x;
        float v1 = acc[mi][ni][1] + bv.y;
        float v2 = acc[mi][ni][2] + bv.z;
        float v3 = acc[mi][ni][3] + bv.w;
        float4 xr = *reinterpret_cast<const float4*>((const float*)extra + off);
        float4 ov;
        ov.x = xr.x + v0 * sc; ov.y = xr.y + v1 * sc;
        ov.z = xr.z + v2 * sc; ov.w = xr.w + v3 * sc;
        *reinterpret_cast<float4*>((float*)outp + off) = ov;
        if (EPI == 1){
          ts[ni].x += ov.x; ts[ni].y += ov.y; ts[ni].z += ov.z; ts[ni].w += ov.w;
          tq[ni].x += ov.x*ov.x; tq[ni].y += ov.y*ov.y;
          tq[ni].z += ov.z*ov.z; tq[ni].w += ov.w*ov.w;
        }
      }
    }
    if (EPI == 1){
      #pragma unroll
      for (int ni = 0; ni < 4; ++ni){
        float4 S = ts[ni], Q = tq[ni];
        #pragma unroll
        for (int m = 1; m < 16; m <<= 1){
          S.x += __shfl_xor(S.x, m); S.y += __shfl_xor(S.y, m);
          S.z += __shfl_xor(S.z, m); S.w += __shfl_xor(S.w, m);
          Q.x += __shfl_xor(Q.x, m); Q.y += __shfl_xor(Q.y, m);
          Q.z += __shfl_xor(Q.z, m); Q.w += __shfl_xor(Q.w, m);
        }
        if (l16 == 0){
          int col0 = (bn << 7) + wn + ni * 16 + (quad << 2);
          atomicAdd(&bsum[col0+0], S.x); atomicAdd(&bsum[col0+1], S.y);
          atomicAdd(&bsum[col0+2], S.z); atomicAdd(&bsum[col0+3], S.w);
          atomicAdd(&bsq[col0+0], Q.x);  atomicAdd(&bsq[col0+1], Q.y);
          atomicAdd(&bsq[col0+2], Q.z);  atomicAdd(&bsq[col0+3], Q.w);
        }
      }
    }
  }
}

// ---------------- top-k routing: aff = qm @ km^T per sample, pick top-4 --------
__global__ void topk_k(const float* __restrict__ qkm, int* __restrict__ idx){
  __shared__ float aff[64];
  int r = blockIdx.x;           // sample*64 + query region
  int m = threadIdx.x;          // candidate region 0..63
  int b = r >> 6;
  const float4* qrow = reinterpret_cast<const float4*>(qkm + (size_t)r * 512);
  const float4* krow = reinterpret_cast<const float4*>(qkm + (size_t)(b * 64 + m) * 512 + 256);
  float dot = 0.f;
  for (int d = 0; d < 64; ++d){
    float4 qv = qrow[d], kv = krow[d];
    dot += qv.x * kv.x + qv.y * kv.y + qv.z * kv.z + qv.w * kv.w;
  }
  aff[m] = dot;
  __syncthreads();
  if (m == 0){
    #pragma unroll
    for (int t = 0; t < 4; ++t){
      float best = -INFINITY; int bi = 0;
      for (int i = 0; i < 64; ++i){
        if (aff[i] > best){ best = aff[i]; bi = i; }   // strict >: lowest index on ties (jax top_k)
      }
      aff[bi] = -INFINITY;
      idx[r * 4 + t] = bi;
    }
  }
}

// ---------------- MFMA routed attention: block per (region, head) --------------
// 256 threads = 4 waves; wave w owns q rows [w*16, w*16+16).
// SWAPPED QK^T: s = mfma(kf, qf) -> lane holds S[q=l16][k=nt*16+quad*4+r]:
//   * softmax becomes lane-local (64 vals) + 2 shfl_xor (16,32); den stays in-reg
//   * P write is 16x ds_write_b64 (4 consecutive k packed), not 64x ds_write_b16
// LDS: Ks[256][40] (20480B) -> aliased by Vt[32][264] (16896B) after S;
//      P per wave [16][264] bf16 at short-offset 10240 + w*4224. Total 54272B.
__global__ __launch_bounds__(256) void attn_mfma_k(
    const __hip_bfloat16* __restrict__ qkv, const int* __restrict__ idx,
    __hip_bfloat16* __restrict__ o_out, int rbase)
{
  __shared__ __align__(16) short lds[27136];
  const int rl = blockIdx.x;       // local region in this chunk
  const int h  = blockIdx.y;       // head
  const int rg = rbase + rl;       // global region (for idx)
  const int bl = rl >> 6;          // local sample
  const int tid = threadIdx.x;
  const int w = tid >> 6, lane = tid & 63;
  const int l16 = lane & 15, quad = lane >> 4;
  short* Pw = lds + 10240 + w * 4224;

  // --- staging: thread tid handles gathered token tid (4 regions x 64) ---
  const int reg = idx[rg * 4 + (tid >> 6)] & 63;       // clamp: never OOB
  const size_t srow = (size_t)bl * SAMP_TOK + (size_t)reg * 64 + (tid & 63);
  const __hip_bfloat16* kvsrc = qkv + srow * 768 + 256 + (size_t)h * 32;

  // Q fragment: lane l16 -> q row w*16+l16; k-elems quad*8..+7
  const size_t qrow = (size_t)rl * 64 + w * 16 + l16;
  short8 qf = *reinterpret_cast<const short8*>(qkv + qrow * 768 + (size_t)h * 32 + quad * 8);

  // V into registers now (LDS write deferred until K is dead)
  uint4 vreg[4];
  #pragma unroll
  for (int c = 0; c < 4; ++c)
    vreg[c] = *reinterpret_cast<const uint4*>(kvsrc + 256 + c * 8);

  // K -> Ks[token][40]
  #pragma unroll
  for (int c = 0; c < 4; ++c)
    *reinterpret_cast<uint4*>(&lds[tid * 40 + c * 8]) =
      *reinterpret_cast<const uint4*>(kvsrc + c * 8);
  __syncthreads();

  // --- S^T = K Q^T : A = K-tile rows (k-tokens), B = Q^T (col = q-row l16) ---
  f32x4 s[16];
  #pragma unroll
  for (int nt = 0; nt < 16; ++nt){
    short8 kf = *reinterpret_cast<const short8*>(&lds[(nt * 16 + l16) * 40 + quad * 8]);
    f32x4 z = {0.f, 0.f, 0.f, 0.f};
    s[nt] = __builtin_amdgcn_mfma_f32_16x16x32_bf16(kf, qf, z, 0, 0, 0);
  }
  __syncthreads();   // all waves done reading Ks

  // --- write Vt[d][tok] (overwrites Ks space) ---
  #pragma unroll
  for (int c = 0; c < 4; ++c){
    short8 vv = *reinterpret_cast<short8*>(&vreg[c]);
    #pragma unroll
    for (int e = 0; e < 8; ++e)
      lds[(c * 8 + e) * 264 + tid] = vv[e];
  }

  // --- softmax for q = w*16+l16: lane holds k = {nt*16 + quad*4 + r} ---
  float mx = -1e30f;
  #pragma unroll
  for (int nt = 0; nt < 16; ++nt)
    #pragma unroll
    for (int r = 0; r < 4; ++r) mx = fmaxf(mx, s[nt][r]);
  mx = fmaxf(mx, __shfl_xor(mx, 16));
  mx = fmaxf(mx, __shfl_xor(mx, 32));
  float den = 0.f;
  #pragma unroll
  for (int nt = 0; nt < 16; ++nt)
    #pragma unroll
    for (int r = 0; r < 4; ++r){
      float e = __expf((s[nt][r] - mx) * 0.17677669529663687f);  // scale folded in
      s[nt][r] = e; den += e;
    }
  den += __shfl_xor(den, 16);
  den += __shfl_xor(den, 32);

  // P bf16 [16 q][264 k] per wave: lane writes P[l16][nt*16+quad*4 .. +3] (8B)
  #pragma unroll
  for (int nt = 0; nt < 16; ++nt){
    unsigned lo = (unsigned)f2bu(s[nt][0]) | ((unsigned)f2bu(s[nt][1]) << 16);
    unsigned hi = (unsigned)f2bu(s[nt][2]) | ((unsigned)f2bu(s[nt][3]) << 16);
    *reinterpret_cast<uint2*>(&Pw[l16 * 264 + nt * 16 + quad * 4]) = make_uint2(lo, hi);
  }
  __syncthreads();

  // --- O^T = V^T P^T : M=d (2 tiles), N=q (16), K=256 (8 steps) ---
  f32x4 o0 = {0.f, 0.f, 0.f, 0.f}, o1 = o0;
  #pragma unroll
  for (int kk = 0; kk < 8; ++kk){
    short8 pb = *reinterpret_cast<const short8*>(&Pw[l16 * 264 + kk * 32 + quad * 8]);
    short8 a0 = *reinterpret_cast<const short8*>(&lds[l16 * 264 + kk * 32 + quad * 8]);
    short8 a1 = *reinterpret_cast<const short8*>(&lds[(16 + l16) * 264 + kk * 32 + quad * 8]);
    o0 = __builtin_amdgcn_mfma_f32_16x16x32_bf16(a0, pb, o0, 0, 0, 0);
    o1 = __builtin_amdgcn_mfma_f32_16x16x32_bf16(a1, pb, o1, 0, 0, 0);
  }
  // normalize + store: col(l16)=q_local, row(quad*4+r)=d; o1 tile d+16.
  float inv = 1.f / den;
  size_t obase = ((size_t)rl * 64 + w * 16 + l16) * 256 + (size_t)h * 32;
  unsigned pk0 = (unsigned)f2bu(o0[0] * inv) | ((unsigned)f2bu(o0[1] * inv) << 16);
  unsigned pk1 = (unsigned)f2bu(o0[2] * inv) | ((unsigned)f2bu(o0[3] * inv) << 16);
  unsigned pk2 = (unsigned)f2bu(o1[0] * inv) | ((unsigned)f2bu(o1[1] * inv) << 16);
  unsigned pk3 = (unsigned)f2bu(o1[2] * inv) | ((unsigned)f2bu(o1[3] * inv) << 16);
  *reinterpret_cast<uint2*>(o_out + obase + quad * 4)      = make_uint2(pk0, pk1);
  *reinterpret_cast<uint2*>(o_out + obase + 16 + quad * 4) = make_uint2(pk2, pk3);
}

// -------------------------------------------------------------------------------
// STRICT ws budget (never write beyond ws_size):
//   [0,4MB)   misc: BN sums/coeffs, idxb, smr, qkm, bf16 weights
//   [4,20MB)  s1 (branch1) then s2 (branch2), bf16 16MB
//   [20MB,..) chunk buffers, adaptively sized from ws_size.
// x2 (fp32 [32768,256], 32MB) lives in d_out; ffn2 updates d_out in place.
// Minimum ws_size supported: 28MB.
extern "C" void kernel_launch(void* const* d_in, const int* in_sizes, int n_in,
                              void* d_out, int out_size, void* d_ws, size_t ws_size,
                              hipStream_t stream)
{
  const float* x      = (const float*)d_in[0];
  const float* bn1_g  = (const float*)d_in[1];
  const float* bn1_b  = (const float*)d_in[2];
  const float* bn2_g  = (const float*)d_in[3];
  const float* bn2_b  = (const float*)d_in[4];
  const float* qkv_w  = (const float*)d_in[5];
  const float* qkv_b  = (const float*)d_in[6];
  const float* proj_w = (const float*)d_in[7];
  const float* proj_b = (const float*)d_in[8];
  const float* ffn_w1 = (const float*)d_in[9];
  const float* ffn_b1 = (const float*)d_in[10];
  const float* ffn_w2 = (const float*)d_in[11];
  const float* ffn_b2 = (const float*)d_in[12];
  const float* scale  = (const float*)d_in[13];
  float* x2 = (float*)d_out;       // residual lives in d_out

  char* ws = (char*)d_ws;
  const size_t MB = 1024 * 1024;
  // misc block [0,4MB)
  float* sum1 = (float*)(ws + 0);
  float* sq1  = (float*)(ws + 1024);
  float* sum2 = (float*)(ws + 2048);
  float* sq2  = (float*)(ws + 3072);
  float* a1   = (float*)(ws + 4096);
  float* b1   = (float*)(ws + 5120);
  float* a2   = (float*)(ws + 6144);
  float* b2   = (float*)(ws + 7168);
  int*   idxb = (int*)(ws + 8192);                              // 8KB
  float* smr  = (float*)(ws + 16384);                           // 512KB
  float* qkm  = (float*)(ws + 540672);                          // 1MB
  __hip_bfloat16* qkv_wb  = (__hip_bfloat16*)(ws + 1589248);    // 384KB
  __hip_bfloat16* proj_wb = (__hip_bfloat16*)(ws + 1982464);    // 128KB
  __hip_bfloat16* ffn_w1b = (__hip_bfloat16*)(ws + 2113536);    // 512KB
  __hip_bfloat16* ffn_w2b = (__hip_bfloat16*)(ws + 2637824);    // 512KB, ends 3162112 < 4MB
  __hip_bfloat16* s1 = (__hip_bfloat16*)(ws + 4 * MB);          // 16MB (s2 reuses)
  __hip_bfloat16* s2 = s1;
  char* chunkbuf = ws + 20 * MB;

  // adaptive chunk sizes from ws_size (constant across calls -> graph-safe)
  size_t avail = (ws_size > 20 * MB) ? (ws_size - 20 * MB) : (8 * MB);
  int nc = (avail >= 64 * MB) ? 8 : (avail >= 32 * MB) ? 4 : (avail >= 16 * MB) ? 2 : 1;   // samples/chunk (8MB each)
  int crows = 32768;
  while ((size_t)crows * 2048 > avail && crows > 2048) crows >>= 1;                         // ffn rows/chunk

  __hip_bfloat16* qkvc = (__hip_bfloat16*)chunkbuf;                        // nc*6MB
  __hip_bfloat16* oc   = (__hip_bfloat16*)(chunkbuf + (size_t)nc * 6 * MB); // nc*2MB
  __hip_bfloat16* h1   = (__hip_bfloat16*)chunkbuf;                        // crows*2KB

  hipMemsetAsync(d_ws, 0, 4096, stream);   // zero BN accumulators

  // one-time weight conversions fp32 -> bf16 (single launch)
  f2ball_k<<<3072, 256, 0, stream>>>(qkv_w, proj_w, ffn_w1, ffn_w2,
                                     qkv_wb, proj_wb, ffn_w1b, ffn_w2b);

  // branch 1: BN -> LIF -> routing, then per-chunk qkv -> attn -> proj+residual
  bn_stats_k<<<256, 256, 0, stream>>>(x, sum1, sq1);
  bn_fin_k<<<1, 256, 0, stream>>>(sum1, sq1, bn1_g, bn1_b, a1, b1);
  lif_k<<<PERT / 1024, 256, 0, stream>>>(x, a1, b1, s1);
  region_sum_k<<<512, 256, 0, stream>>>(s1, smr);
  rgemm_k<<<512, 256, 0, stream>>>(smr, qkv_w, qkv_b, qkm);   // fp32 routing (flip-proof)
  topk_k<<<512, 64, 0, stream>>>(qkm, idxb);

  const int nchunkA = 8 / nc;
  for (int c = 0; c < nchunkA; ++c){
    const size_t ro = (size_t)c * nc * SAMP_TOK;            // row offset (tokens)
    gemm_bt<0><<<dim3(nc * SAMP_TOK / 128, 6), 256, 0, stream>>>(
        s1 + ro * 256, qkv_wb, qkv_b, qkvc, nullptr, nullptr, nullptr, nullptr, 256, 768);
    attn_mfma_k<<<dim3(nc * 64, 8), 256, 0, stream>>>(qkvc, idxb, oc, c * nc * 64);
    gemm_bt<1><<<dim3(nc * SAMP_TOK / 128, 2), 256, 0, stream>>>(
        oc, proj_wb, proj_b, x2 + ro * 256, x + ro * 256, scale, sum2, sq2, 256, 256);
  }

  // branch 2: (BN stats fused into proj epilogue) -> LIF -> FFN(gelu) + residual
  bn_fin_k<<<1, 256, 0, stream>>>(sum2, sq2, bn2_g, bn2_b, a2, b2);
  lif_k<<<PERT / 1024, 256, 0, stream>>>(x2, a2, b2, s2);
  const int nchunkF = 32768 / crows;
  for (int c = 0; c < nchunkF; ++c){
    const size_t ro = (size_t)c * crows;
    gemm_bt<2><<<dim3(crows / 128, 8), 256, 0, stream>>>(
        s2 + ro * 256, ffn_w1b, ffn_b1, h1, nullptr, nullptr, nullptr, nullptr, 256, 1024);
    gemm_bt<3><<<dim3(crows / 128, 2), 256, 0, stream>>>(
        h1, ffn_w2b, ffn_b2, x2 + ro * 256, x2 + ro * 256, scale, nullptr, nullptr, 1024, 256);
  }
}

// Round 6
// 371.125 us; speedup vs baseline: 1.1176x; 1.1176x over previous
//
#include <hip/hip_runtime.h>
#include <hip/hip_bf16.h>
#include <math.h>

typedef __attribute__((ext_vector_type(8))) short short8;
typedef __attribute__((ext_vector_type(4))) float f32x4;

#define DIM 256
#define NROWS 32768      // T*B*Ltot rows
#define PERT 2097152     // B*Ltot*D elements per timestep
#define SAMP_TOK 4096    // tokens per (t,b) sample

__device__ __forceinline__ float b2f(__hip_bfloat16 h){ return __bfloat162float(h); }
__device__ __forceinline__ __hip_bfloat16 f2b(float f){ return __float2bfloat16(f); }
__device__ __forceinline__ unsigned short f2bu(float f){
  __hip_bfloat16 h = __float2bfloat16(f);
  unsigned short u; __builtin_memcpy(&u, &h, 2); return u;
}

// async global -> LDS, 16B per lane (wave-uniform base + lane*16 on LDS side)
#define GLD_LDS16(gp, lp) __builtin_amdgcn_global_load_lds( \
    (const __attribute__((address_space(1))) unsigned int*)(gp), \
    (__attribute__((address_space(3))) unsigned int*)(lp), 16, 0, 0)

// branchless erf-based exact gelu (A&S 7.1.26, |err| <= ~3e-7: below bf16 ulp)
__device__ __forceinline__ float gelu_fast(float v){
  float z  = v * 0.70710678118654752f;
  float az = fabsf(z);
  float t  = __builtin_amdgcn_rcpf(fmaf(0.3275911f, az, 1.0f));
  float p  = fmaf(fmaf(fmaf(fmaf(1.061405429f, t, -1.453152027f), t,
                            1.421413741f), t, -0.284496736f), t, 0.254829592f);
  p *= t;
  float e  = __expf(-z * z);
  float y  = fmaf(-p, e, 1.0f);                 // erf(|z|)
  return fmaf(0.5f * fabsf(v), y, 0.5f * v);    // 0.5*v*(1+sign(v)*erf(|z|))
}

// ---------------- fp32 -> bf16 weight conversion (all 4 weights, one launch) ---
__global__ void f2ball_k(const float* __restrict__ w_qkv, const float* __restrict__ w_proj,
                         const float* __restrict__ w_f1, const float* __restrict__ w_f2,
                         __hip_bfloat16* __restrict__ o_qkv, __hip_bfloat16* __restrict__ o_proj,
                         __hip_bfloat16* __restrict__ o_f1, __hip_bfloat16* __restrict__ o_f2){
  int i = blockIdx.x * 256 + threadIdx.x;        // 0 .. 786431
  if (i < 196608)          o_qkv[i]           = f2b(w_qkv[i]);
  else if (i < 262144)     o_proj[i - 196608] = f2b(w_proj[i - 196608]);
  else if (i < 524288)     o_f1[i - 262144]   = f2b(w_f1[i - 262144]);
  else                     o_f2[i - 524288]   = f2b(w_f2[i - 524288]);
}

// ---------------- BN stats (branch 1): per-channel sum / sumsq -----------------
__global__ void bn_stats_k(const float* __restrict__ x, float* __restrict__ sum, float* __restrict__ sumsq){
  __shared__ __align__(16) float rs[4][256];
  __shared__ __align__(16) float rq[4][256];
  int t = threadIdx.x;
  int g = t & 63, r = t >> 6;
  size_t base = ((size_t)blockIdx.x * 128 + r) * DIM + g * 4;   // 128 rows per block
  float4 s = {0.f,0.f,0.f,0.f}, q = {0.f,0.f,0.f,0.f};
  for (int i = 0; i < 32; ++i){
    float4 v = *reinterpret_cast<const float4*>(x + base + (size_t)i * 4 * DIM);
    s.x += v.x; s.y += v.y; s.z += v.z; s.w += v.w;
    q.x += v.x*v.x; q.y += v.y*v.y; q.z += v.z*v.z; q.w += v.w*v.w;
  }
  *reinterpret_cast<float4*>(&rs[r][g*4]) = s;
  *reinterpret_cast<float4*>(&rq[r][g*4]) = q;
  __syncthreads();
  int c = t;   // one channel per thread
  atomicAdd(&sum[c],   rs[0][c] + rs[1][c] + rs[2][c] + rs[3][c]);
  atomicAdd(&sumsq[c], rq[0][c] + rq[1][c] + rq[2][c] + rq[3][c]);
}

__global__ void bn_fin_k(const float* __restrict__ sum, const float* __restrict__ sumsq,
                         const float* __restrict__ g, const float* __restrict__ b,
                         float* __restrict__ a_out, float* __restrict__ b_out){
  int c = threadIdx.x;
  float mean = sum[c] * (1.f/32768.f);
  float var  = sumsq[c] * (1.f/32768.f) - mean*mean;
  float a = g[c] / sqrtf(var + 1e-5f);
  a_out[c] = a;
  b_out[c] = b[c] - mean * a;
}

// ---------------- BN2 reduce: column-sum the 512x256 partial grids -------------
// pps/ppq written non-atomically by proj's epilogue (one writer per cell).
// Folds bn_fin: emits a2/b2 directly. 1 block x 256 threads; 1MB L2 reads.
__global__ void bn_red_k(const float* __restrict__ pps, const float* __restrict__ ppq,
                         const float* __restrict__ g, const float* __restrict__ b,
                         float* __restrict__ a_out, float* __restrict__ b_out){
  int c = threadIdx.x;
  float s = 0.f, q = 0.f;
  for (int r = 0; r < 512; ++r){
    s += pps[r * 256 + c];
    q += ppq[r * 256 + c];
  }
  float mean = s * (1.f/32768.f);
  float var  = q * (1.f/32768.f) - mean*mean;
  float a = g[c] / sqrtf(var + 1e-5f);
  a_out[c] = a;
  b_out[c] = b[c] - mean * a;
}

// ---------------- LIF over T=4 (binary spike out, bf16 exact) ------------------
__global__ void lif_k(const float* __restrict__ x, const float* __restrict__ av,
                      const float* __restrict__ bv, __hip_bfloat16* __restrict__ s){
  int i = blockIdx.x * 256 + threadIdx.x;       // 0 .. PERT/4-1 (exact grid)
  int e4 = i * 4;
  int c4 = e4 & (DIM - 1);
  float4 a = *reinterpret_cast<const float4*>(av + c4);
  float4 b = *reinterpret_cast<const float4*>(bv + c4);
  float4 v = {0.f,0.f,0.f,0.f};
  #pragma unroll
  for (int t = 0; t < 4; ++t){
    float4 xn = *reinterpret_cast<const float4*>(x + (size_t)t * PERT + e4);
    xn.x = fmaf(xn.x, a.x, b.x); xn.y = fmaf(xn.y, a.y, b.y);
    xn.z = fmaf(xn.z, a.z, b.z); xn.w = fmaf(xn.w, a.w, b.w);
    v.x += (xn.x - v.x) * 0.5f; v.y += (xn.y - v.y) * 0.5f;
    v.z += (xn.z - v.z) * 0.5f; v.w += (xn.w - v.w) * 0.5f;
    ushort4 sp;
    sp.x = (v.x >= 1.0f) ? 0x3F80 : 0;  v.x = (v.x >= 1.0f) ? 0.f : v.x;
    sp.y = (v.y >= 1.0f) ? 0x3F80 : 0;  v.y = (v.y >= 1.0f) ? 0.f : v.y;
    sp.z = (v.z >= 1.0f) ? 0x3F80 : 0;  v.z = (v.z >= 1.0f) ? 0.f : v.z;
    sp.w = (v.w >= 1.0f) ? 0x3F80 : 0;  v.w = (v.w >= 1.0f) ? 0.f : v.w;
    *reinterpret_cast<ushort4*>(reinterpret_cast<unsigned short*>(s) + (size_t)t * PERT + e4) = sp;
  }
}

// ---------------- region means of binary s1 (exact fp32) -----------------------
__global__ void region_sum_k(const __hip_bfloat16* __restrict__ s, float* __restrict__ sm){
  __shared__ __align__(16) float red[4][256];
  int r = blockIdx.x, t = threadIdx.x;    // r = (sample*64 + region), 512 total
  int g = t & 63, sub = t >> 6;
  const unsigned short* sp = reinterpret_cast<const unsigned short*>(s);
  size_t base = ((size_t)r * 64 + sub * 16) * DIM + g * 4;
  float4 acc = {0.f,0.f,0.f,0.f};
  for (int i = 0; i < 16; ++i){
    ushort4 u = *reinterpret_cast<const ushort4*>(sp + base + (size_t)i * DIM);
    acc.x += (u.x != 0) ? 1.f : 0.f; acc.y += (u.y != 0) ? 1.f : 0.f;
    acc.z += (u.z != 0) ? 1.f : 0.f; acc.w += (u.w != 0) ? 1.f : 0.f;
  }
  *reinterpret_cast<float4*>(&red[sub][g*4]) = acc;
  __syncthreads();
  if (sub == 0){
    float4 o;
    o.x = (red[0][g*4+0] + red[1][g*4+0] + red[2][g*4+0] + red[3][g*4+0]) * 0.015625f;
    o.y = (red[0][g*4+1] + red[1][g*4+1] + red[2][g*4+1] + red[3][g*4+1]) * 0.015625f;
    o.z = (red[0][g*4+2] + red[1][g*4+2] + red[2][g*4+2] + red[3][g*4+2]) * 0.015625f;
    o.w = (red[0][g*4+3] + red[1][g*4+3] + red[2][g*4+3] + red[3][g*4+3]) * 0.015625f;
    *reinterpret_cast<float4*>(sm + (size_t)r * DIM + g * 4) = o;
  }
}

// ---------------- routing GEMM fp32: qkm[r][j] = smr[r]·qkv_w[j] + b[j], j<512 -
__global__ void rgemm_k(const float* __restrict__ smr, const float* __restrict__ w,
                        const float* __restrict__ bias, float* __restrict__ qkm){
  __shared__ float arow[256];
  int r = blockIdx.x, t = threadIdx.x;
  arow[t] = smr[(size_t)r * 256 + t];
  __syncthreads();
  for (int j = t; j < 512; j += 256){
    const float* wr = w + (size_t)j * 256;
    float acc = 0.f;
    for (int k = 0; k < 256; ++k) acc += arow[k] * wr[k];
    qkm[(size_t)r * 512 + j] = acc + bias[j];
  }
}

// ---------------- GEMM: C[M,N] = A[M,K] @ W[N,K]^T (+bias, epilogue) -----------
// 2-phase double-buffered staging; linear LDS dest + source-side bank swizzle.
// MFMA operand-swapped: mfma(wf, af) -> lane holds row=l16, cols=quad*4+[0..3].
// bf16 epilogues (EPI 0/2) route C through wave-private LDS (dead staging buf).
// EPI 0: bf16 out = v+bias                  (qkv)
// EPI 1: f32  out = x_f32 + v*scale         (proj + residual) + fused bn2 stats
//        -> NON-ATOMIC per-wave partials (R5's atomicAdd burst to a 2KB window
//           serialized at L2 and stalled the kernel 90us; partial grid + reduce
//           kernel removes the contention entirely)
// EPI 2: bf16 out = gelu_exact(v+bias)      (ffn1)
// EPI 3: f32  out = x2_f32 + v*scale        (ffn2 + residual, in-place on d_out)
template<int EPI>
__global__ __launch_bounds__(256) void gemm_bt(
    const __hip_bfloat16* __restrict__ A, const __hip_bfloat16* __restrict__ W,
    const float* __restrict__ bias, void* __restrict__ outp,
    const void* __restrict__ extra, const float* __restrict__ scaleptr,
    float* __restrict__ pps, float* __restrict__ ppq,
    int K, int N)
{
  __shared__ __align__(16) short As0[128 * 32];   // 8KB each, linear layout
  __shared__ __align__(16) short Ws0[128 * 32];
  __shared__ __align__(16) short As1[128 * 32];
  __shared__ __align__(16) short Ws1[128 * 32];
  int tid = threadIdx.x;
  int bm = blockIdx.x, bn = blockIdx.y;
  int lane = tid & 63;
  int l16 = lane & 15, quad = lane >> 4;
  int wv = tid >> 6;
  int wm = (wv >> 1) << 6, wn = (wv & 1) << 6;

  // staging: thread tid owns LDS granule tid (16B) = row tid>>2, col-block tid&3.
  // source col-block is swizzle-inverse: sq = (tid&3) ^ ((row>>1)&3).
  const int srow = tid >> 2;
  const int sq   = (tid & 3) ^ ((srow >> 1) & 3);
  const __hip_bfloat16* Ag = A + (size_t)(bm * 128 + srow) * K + (sq << 3);
  const __hip_bfloat16* Wg = W + (size_t)(bn * 128 + srow) * K + (sq << 3);
  const size_t rstep = (size_t)64 * K;

  // swizzled ds_read offsets (shorts), hoisted out of the loop
  int roA[4], roW[4];
  #pragma unroll
  for (int i = 0; i < 4; ++i){
    int Ra = wm + i * 16 + l16;
    roA[i] = Ra * 32 + ((quad ^ ((Ra >> 1) & 3)) << 3);
    int Rw = wn + i * 16 + l16;
    roW[i] = Rw * 32 + ((quad ^ ((Rw >> 1) & 3)) << 3);
  }

  f32x4 zero = {0.f, 0.f, 0.f, 0.f};
  f32x4 acc[4][4];
  #pragma unroll
  for (int i = 0; i < 4; ++i)
    #pragma unroll
    for (int j = 0; j < 4; ++j) acc[i][j] = zero;

  auto stage = [&](short* Ad, short* Wd, int k0){
    GLD_LDS16(Ag + k0,         Ad + tid * 8);
    GLD_LDS16(Ag + rstep + k0, Ad + tid * 8 + 2048);
    GLD_LDS16(Wg + k0,         Wd + tid * 8);
    GLD_LDS16(Wg + rstep + k0, Wd + tid * 8 + 2048);
  };
  auto compute = [&](const short* Asb, const short* Wsb){
    short8 af[4];
    #pragma unroll
    for (int mi = 0; mi < 4; ++mi)
      af[mi] = *reinterpret_cast<const short8*>(Asb + roA[mi]);
    #pragma unroll
    for (int ni = 0; ni < 4; ++ni){
      short8 wf = *reinterpret_cast<const short8*>(Wsb + roW[ni]);
      #pragma unroll
      for (int mi = 0; mi < 4; ++mi)
        acc[mi][ni] = __builtin_amdgcn_mfma_f32_16x16x32_bf16(wf, af[mi], acc[mi][ni], 0, 0, 0);
    }
  };

  // K is a multiple of 64 for every call site (256 or 1024)
  stage(As0, Ws0, 0);
  __syncthreads();
  for (int k0 = 0; k0 < K; k0 += 64){
    if (k0 + 32 < K) stage(As1, Ws1, k0 + 32);
    compute(As0, Ws0);
    __syncthreads();                       // drains prefetch (vmcnt 0) + barrier
    if (k0 + 64 < K) stage(As0, Ws0, k0 + 64);
    if (k0 + 32 < K) compute(As1, Ws1);
    __syncthreads();
  }

  if (EPI == 0 || EPI == 2){
    // ---- coalesced bf16 epilogue: wave-private 64x64 C-tile via dead staging LDS
    short* Cw = (wv == 0) ? As0 : (wv == 1) ? Ws0 : (wv == 2) ? As1 : Ws1;
    #pragma unroll
    for (int ni = 0; ni < 4; ++ni){
      int col0 = (bn << 7) + wn + ni * 16 + (quad << 2);
      float4 bv = *reinterpret_cast<const float4*>(bias + col0);
      #pragma unroll
      for (int mi = 0; mi < 4; ++mi){
        float v0 = acc[mi][ni][0] + bv.x;
        float v1 = acc[mi][ni][1] + bv.y;
        float v2 = acc[mi][ni][2] + bv.z;
        float v3 = acc[mi][ni][3] + bv.w;
        if (EPI == 2){
          v0 = gelu_fast(v0); v1 = gelu_fast(v1);
          v2 = gelu_fast(v2); v3 = gelu_fast(v3);
        }
        unsigned lo = (unsigned)f2bu(v0) | ((unsigned)f2bu(v1) << 16);
        unsigned hi = (unsigned)f2bu(v2) | ((unsigned)f2bu(v3) << 16);
        int row = mi * 16 + l16;                                 // 0..63 in wave tile
        int cb  = (ni * 32 + (quad << 3)) ^ ((row & 7) << 4);    // swizzled byte col
        *reinterpret_cast<uint2*>(reinterpret_cast<char*>(Cw) + row * 128 + cb) =
            make_uint2(lo, hi);
      }
    }
    asm volatile("s_waitcnt lgkmcnt(0)" ::: "memory");   // wave-internal ds drain
    #pragma unroll
    for (int p = 0; p < 8; ++p){
      int row = p * 8 + (lane >> 3);
      int cb  = ((lane & 7) << 4) ^ ((row & 7) << 4);    // un-swizzles to col (lane&7)*16B
      uint4 val = *reinterpret_cast<const uint4*>(
          reinterpret_cast<const char*>(Cw) + row * 128 + cb);
      int rowg = (bm << 7) + wm + row;
      int colg = (bn << 7) + wn + ((lane & 7) << 3);     // shorts
      *reinterpret_cast<uint4*>((__hip_bfloat16*)outp + (size_t)rowg * N + colg) = val;
    }
  } else {
    // ---- f32 epilogues: float4 stores already cover full 64B sectors per row.
    // EPI 1: also accumulate this wave's 64-row x 64-col sum/sumsq partials.
    float sc = scaleptr[0];
    float4 ts[4], tq[4];
    if (EPI == 1){
      #pragma unroll
      for (int ni = 0; ni < 4; ++ni){ ts[ni] = {0.f,0.f,0.f,0.f}; tq[ni] = {0.f,0.f,0.f,0.f}; }
    }
    #pragma unroll
    for (int ni = 0; ni < 4; ++ni){
      int col0 = (bn << 7) + wn + ni * 16 + (quad << 2);
      float4 bv = *reinterpret_cast<const float4*>(bias + col0);
      #pragma unroll
      for (int mi = 0; mi < 4; ++mi){
        int rowg = (bm << 7) + wm + mi * 16 + l16;
        size_t off = (size_t)rowg * N + col0;
        float v0 = acc[mi][ni][0] + bv.x;
        float v1 = acc[mi][ni][1] + bv.y;
        float v2 = acc[mi][ni][2] + bv.z;
        float v3 = acc[mi][ni][3] + bv.w;
        float4 xr = *reinterpret_cast<const float4*>((const float*)extra + off);
        float4 ov;
        ov.x = xr.x + v0 * sc; ov.y = xr.y + v1 * sc;
        ov.z = xr.z + v2 * sc; ov.w = xr.w + v3 * sc;
        *reinterpret_cast<float4*>((float*)outp + off) = ov;
        if (EPI == 1){
          ts[ni].x += ov.x; ts[ni].y += ov.y; ts[ni].z += ov.z; ts[ni].w += ov.w;
          tq[ni].x += ov.x*ov.x; tq[ni].y += ov.y*ov.y;
          tq[ni].z += ov.z*ov.z; tq[ni].w += ov.w*ov.w;
        }
      }
    }
    if (EPI == 1){
      // reduce across the 16 lanes of each quad-row group, then ONE non-atomic
      // float4 pair per (ni, quad): ppart row = bm*2 + wm-half (64-row group).
      int prow = (bm << 1) + (wm >> 6);
      #pragma unroll
      for (int ni = 0; ni < 4; ++ni){
        float4 S = ts[ni], Q = tq[ni];
        #pragma unroll
        for (int m = 1; m < 16; m <<= 1){
          S.x += __shfl_xor(S.x, m); S.y += __shfl_xor(S.y, m);
          S.z += __shfl_xor(S.z, m); S.w += __shfl_xor(S.w, m);
          Q.x += __shfl_xor(Q.x, m); Q.y += __shfl_xor(Q.y, m);
          Q.z += __shfl_xor(Q.z, m); Q.w += __shfl_xor(Q.w, m);
        }
        if (l16 == 0){
          int col0 = (bn << 7) + wn + ni * 16 + (quad << 2);
          *reinterpret_cast<float4*>(pps + prow * 256 + col0) = S;
          *reinterpret_cast<float4*>(ppq + prow * 256 + col0) = Q;
        }
      }
    }
  }
}

// ---------------- top-k routing: aff = qm @ km^T per sample, pick top-4 --------
__global__ void topk_k(const float* __restrict__ qkm, int* __restrict__ idx){
  __shared__ float aff[64];
  int r = blockIdx.x;           // sample*64 + query region
  int m = threadIdx.x;          // candidate region 0..63
  int b = r >> 6;
  const float4* qrow = reinterpret_cast<const float4*>(qkm + (size_t)r * 512);
  const float4* krow = reinterpret_cast<const float4*>(qkm + (size_t)(b * 64 + m) * 512 + 256);
  float dot = 0.f;
  for (int d = 0; d < 64; ++d){
    float4 qv = qrow[d], kv = krow[d];
    dot += qv.x * kv.x + qv.y * kv.y + qv.z * kv.z + qv.w * kv.w;
  }
  aff[m] = dot;
  __syncthreads();
  if (m == 0){
    #pragma unroll
    for (int t = 0; t < 4; ++t){
      float best = -INFINITY; int bi = 0;
      for (int i = 0; i < 64; ++i){
        if (aff[i] > best){ best = aff[i]; bi = i; }   // strict >: lowest index on ties (jax top_k)
      }
      aff[bi] = -INFINITY;
      idx[r * 4 + t] = bi;
    }
  }
}

// ---------------- MFMA routed attention: block per (region, head) --------------
// 256 threads = 4 waves; wave w owns q rows [w*16, w*16+16).
// SWAPPED QK^T: s = mfma(kf, qf) -> lane holds S[q=l16][k=nt*16+quad*4+r]:
//   * softmax becomes lane-local (64 vals) + 2 shfl_xor (16,32); den stays in-reg
//   * P write is 16x ds_write_b64 (4 consecutive k packed), not 64x ds_write_b16
// LDS: Ks[256][40] (20480B) -> aliased by Vt[32][264] (16896B) after S;
//      P per wave [16][264] bf16 at short-offset 10240 + w*4224. Total 54272B.
__global__ __launch_bounds__(256) void attn_mfma_k(
    const __hip_bfloat16* __restrict__ qkv, const int* __restrict__ idx,
    __hip_bfloat16* __restrict__ o_out, int rbase)
{
  __shared__ __align__(16) short lds[27136];
  const int rl = blockIdx.x;       // local region in this chunk
  const int h  = blockIdx.y;       // head
  const int rg = rbase + rl;       // global region (for idx)
  const int bl = rl >> 6;          // local sample
  const int tid = threadIdx.x;
  const int w = tid >> 6, lane = tid & 63;
  const int l16 = lane & 15, quad = lane >> 4;
  short* Pw = lds + 10240 + w * 4224;

  // --- staging: thread tid handles gathered token tid (4 regions x 64) ---
  const int reg = idx[rg * 4 + (tid >> 6)] & 63;       // clamp: never OOB
  const size_t srow = (size_t)bl * SAMP_TOK + (size_t)reg * 64 + (tid & 63);
  const __hip_bfloat16* kvsrc = qkv + srow * 768 + 256 + (size_t)h * 32;

  // Q fragment: lane l16 -> q row w*16+l16; k-elems quad*8..+7
  const size_t qrow = (size_t)rl * 64 + w * 16 + l16;
  short8 qf = *reinterpret_cast<const short8*>(qkv + qrow * 768 + (size_t)h * 32 + quad * 8);

  // V into registers now (LDS write deferred until K is dead)
  uint4 vreg[4];
  #pragma unroll
  for (int c = 0; c < 4; ++c)
    vreg[c] = *reinterpret_cast<const uint4*>(kvsrc + 256 + c * 8);

  // K -> Ks[token][40]
  #pragma unroll
  for (int c = 0; c < 4; ++c)
    *reinterpret_cast<uint4*>(&lds[tid * 40 + c * 8]) =
      *reinterpret_cast<const uint4*>(kvsrc + c * 8);
  __syncthreads();

  // --- S^T = K Q^T : A = K-tile rows (k-tokens), B = Q^T (col = q-row l16) ---
  f32x4 s[16];
  #pragma unroll
  for (int nt = 0; nt < 16; ++nt){
    short8 kf = *reinterpret_cast<const short8*>(&lds[(nt * 16 + l16) * 40 + quad * 8]);
    f32x4 z = {0.f, 0.f, 0.f, 0.f};
    s[nt] = __builtin_amdgcn_mfma_f32_16x16x32_bf16(kf, qf, z, 0, 0, 0);
  }
  __syncthreads();   // all waves done reading Ks

  // --- write Vt[d][tok] (overwrites Ks space) ---
  #pragma unroll
  for (int c = 0; c < 4; ++c){
    short8 vv = *reinterpret_cast<short8*>(&vreg[c]);
    #pragma unroll
    for (int e = 0; e < 8; ++e)
      lds[(c * 8 + e) * 264 + tid] = vv[e];
  }

  // --- softmax for q = w*16+l16: lane holds k = {nt*16 + quad*4 + r} ---
  float mx = -1e30f;
  #pragma unroll
  for (int nt = 0; nt < 16; ++nt)
    #pragma unroll
    for (int r = 0; r < 4; ++r) mx = fmaxf(mx, s[nt][r]);
  mx = fmaxf(mx, __shfl_xor(mx, 16));
  mx = fmaxf(mx, __shfl_xor(mx, 32));
  float den = 0.f;
  #pragma unroll
  for (int nt = 0; nt < 16; ++nt)
    #pragma unroll
    for (int r = 0; r < 4; ++r){
      float e = __expf((s[nt][r] - mx) * 0.17677669529663687f);  // scale folded in
      s[nt][r] = e; den += e;
    }
  den += __shfl_xor(den, 16);
  den += __shfl_xor(den, 32);

  // P bf16 [16 q][264 k] per wave: lane writes P[l16][nt*16+quad*4 .. +3] (8B)
  #pragma unroll
  for (int nt = 0; nt < 16; ++nt){
    unsigned lo = (unsigned)f2bu(s[nt][0]) | ((unsigned)f2bu(s[nt][1]) << 16);
    unsigned hi = (unsigned)f2bu(s[nt][2]) | ((unsigned)f2bu(s[nt][3]) << 16);
    *reinterpret_cast<uint2*>(&Pw[l16 * 264 + nt * 16 + quad * 4]) = make_uint2(lo, hi);
  }
  __syncthreads();

  // --- O^T = V^T P^T : M=d (2 tiles), N=q (16), K=256 (8 steps) ---
  f32x4 o0 = {0.f, 0.f, 0.f, 0.f}, o1 = o0;
  #pragma unroll
  for (int kk = 0; kk < 8; ++kk){
    short8 pb = *reinterpret_cast<const short8*>(&Pw[l16 * 264 + kk * 32 + quad * 8]);
    short8 a0 = *reinterpret_cast<const short8*>(&lds[l16 * 264 + kk * 32 + quad * 8]);
    short8 a1 = *reinterpret_cast<const short8*>(&lds[(16 + l16) * 264 + kk * 32 + quad * 8]);
    o0 = __builtin_amdgcn_mfma_f32_16x16x32_bf16(a0, pb, o0, 0, 0, 0);
    o1 = __builtin_amdgcn_mfma_f32_16x16x32_bf16(a1, pb, o1, 0, 0, 0);
  }
  // normalize + store: col(l16)=q_local, row(quad*4+r)=d; o1 tile d+16.
  float inv = 1.f / den;
  size_t obase = ((size_t)rl * 64 + w * 16 + l16) * 256 + (size_t)h * 32;
  unsigned pk0 = (unsigned)f2bu(o0[0] * inv) | ((unsigned)f2bu(o0[1] * inv) << 16);
  unsigned pk1 = (unsigned)f2bu(o0[2] * inv) | ((unsigned)f2bu(o0[3] * inv) << 16);
  unsigned pk2 = (unsigned)f2bu(o1[0] * inv) | ((unsigned)f2bu(o1[1] * inv) << 16);
  unsigned pk3 = (unsigned)f2bu(o1[2] * inv) | ((unsigned)f2bu(o1[3] * inv) << 16);
  *reinterpret_cast<uint2*>(o_out + obase + quad * 4)      = make_uint2(pk0, pk1);
  *reinterpret_cast<uint2*>(o_out + obase + 16 + quad * 4) = make_uint2(pk2, pk3);
}

// -------------------------------------------------------------------------------
// STRICT ws budget (never write beyond ws_size):
//   [0,4MB)   misc: BN sums/coeffs, idxb, smr, qkm, bf16 weights, bn2 partials
//   [4,20MB)  s1 (branch1) then s2 (branch2), bf16 16MB
//   [20MB,..) chunk buffers, adaptively sized from ws_size.
// x2 (fp32 [32768,256], 32MB) lives in d_out; ffn2 updates d_out in place.
// Minimum ws_size supported: 28MB.
extern "C" void kernel_launch(void* const* d_in, const int* in_sizes, int n_in,
                              void* d_out, int out_size, void* d_ws, size_t ws_size,
                              hipStream_t stream)
{
  const float* x      = (const float*)d_in[0];
  const float* bn1_g  = (const float*)d_in[1];
  const float* bn1_b  = (const float*)d_in[2];
  const float* bn2_g  = (const float*)d_in[3];
  const float* bn2_b  = (const float*)d_in[4];
  const float* qkv_w  = (const float*)d_in[5];
  const float* qkv_b  = (const float*)d_in[6];
  const float* proj_w = (const float*)d_in[7];
  const float* proj_b = (const float*)d_in[8];
  const float* ffn_w1 = (const float*)d_in[9];
  const float* ffn_b1 = (const float*)d_in[10];
  const float* ffn_w2 = (const float*)d_in[11];
  const float* ffn_b2 = (const float*)d_in[12];
  const float* scale  = (const float*)d_in[13];
  float* x2 = (float*)d_out;       // residual lives in d_out

  char* ws = (char*)d_ws;
  const size_t MB = 1024 * 1024;
  // misc block [0,4MB)
  float* sum1 = (float*)(ws + 0);
  float* sq1  = (float*)(ws + 1024);
  float* a1   = (float*)(ws + 4096);
  float* b1   = (float*)(ws + 5120);
  float* a2   = (float*)(ws + 6144);
  float* b2   = (float*)(ws + 7168);
  int*   idxb = (int*)(ws + 8192);                              // 8KB
  float* smr  = (float*)(ws + 16384);                           // 512KB
  float* qkm  = (float*)(ws + 540672);                          // 1MB
  __hip_bfloat16* qkv_wb  = (__hip_bfloat16*)(ws + 1589248);    // 384KB
  __hip_bfloat16* proj_wb = (__hip_bfloat16*)(ws + 1982464);    // 128KB
  __hip_bfloat16* ffn_w1b = (__hip_bfloat16*)(ws + 2113536);    // 512KB
  __hip_bfloat16* ffn_w2b = (__hip_bfloat16*)(ws + 2637824);    // 512KB, ends 3162112
  float* ppsum = (float*)(ws + 3162112);                        // 512KB (512x256 f32)
  float* ppsq  = (float*)(ws + 3686400);                        // 512KB, ends 4MB exactly
  __hip_bfloat16* s1 = (__hip_bfloat16*)(ws + 4 * MB);          // 16MB (s2 reuses)
  __hip_bfloat16* s2 = s1;
  char* chunkbuf = ws + 20 * MB;

  // adaptive chunk sizes from ws_size (constant across calls -> graph-safe)
  size_t avail = (ws_size > 20 * MB) ? (ws_size - 20 * MB) : (8 * MB);
  int nc = (avail >= 64 * MB) ? 8 : (avail >= 32 * MB) ? 4 : (avail >= 16 * MB) ? 2 : 1;   // samples/chunk (8MB each)
  int crows = 32768;
  while ((size_t)crows * 2048 > avail && crows > 2048) crows >>= 1;                         // ffn rows/chunk

  __hip_bfloat16* qkvc = (__hip_bfloat16*)chunkbuf;                        // nc*6MB
  __hip_bfloat16* oc   = (__hip_bfloat16*)(chunkbuf + (size_t)nc * 6 * MB); // nc*2MB
  __hip_bfloat16* h1   = (__hip_bfloat16*)chunkbuf;                        // crows*2KB

  hipMemsetAsync(d_ws, 0, 4096, stream);   // zero BN1 accumulators

  // one-time weight conversions fp32 -> bf16 (single launch)
  f2ball_k<<<3072, 256, 0, stream>>>(qkv_w, proj_w, ffn_w1, ffn_w2,
                                     qkv_wb, proj_wb, ffn_w1b, ffn_w2b);

  // branch 1: BN -> LIF -> routing, then per-chunk qkv -> attn -> proj+residual
  bn_stats_k<<<256, 256, 0, stream>>>(x, sum1, sq1);
  bn_fin_k<<<1, 256, 0, stream>>>(sum1, sq1, bn1_g, bn1_b, a1, b1);
  lif_k<<<PERT / 1024, 256, 0, stream>>>(x, a1, b1, s1);
  region_sum_k<<<512, 256, 0, stream>>>(s1, smr);
  rgemm_k<<<512, 256, 0, stream>>>(smr, qkv_w, qkv_b, qkm);   // fp32 routing (flip-proof)
  topk_k<<<512, 64, 0, stream>>>(qkm, idxb);

  const int nchunkA = 8 / nc;
  for (int c = 0; c < nchunkA; ++c){
    const size_t ro = (size_t)c * nc * SAMP_TOK;            // row offset (tokens)
    gemm_bt<0><<<dim3(nc * SAMP_TOK / 128, 6), 256, 0, stream>>>(
        s1 + ro * 256, qkv_wb, qkv_b, qkvc, nullptr, nullptr, nullptr, nullptr, 256, 768);
    attn_mfma_k<<<dim3(nc * 64, 8), 256, 0, stream>>>(qkvc, idxb, oc, c * nc * 64);
    gemm_bt<1><<<dim3(nc * SAMP_TOK / 128, 2), 256, 0, stream>>>(
        oc, proj_wb, proj_b, x2 + ro * 256, x + ro * 256, scale,
        ppsum + (ro >> 6) * 256, ppsq + (ro >> 6) * 256, 256, 256);
  }

  // branch 2: bn2 partial-reduce (atomic-free) -> LIF -> FFN(gelu) + residual
  bn_red_k<<<1, 256, 0, stream>>>(ppsum, ppsq, bn2_g, bn2_b, a2, b2);
  lif_k<<<PERT / 1024, 256, 0, stream>>>(x2, a2, b2, s2);
  const int nchunkF = 32768 / crows;
  for (int c = 0; c < nchunkF; ++c){
    const size_t ro = (size_t)c * crows;
    gemm_bt<2><<<dim3(crows / 128, 8), 256, 0, stream>>>(
        s2 + ro * 256, ffn_w1b, ffn_b1, h1, nullptr, nullptr, nullptr, nullptr, 256, 1024);
    gemm_bt<3><<<dim3(crows / 128, 2), 256, 0, stream>>>(
        h1, ffn_w2b, ffn_b2, x2 + ro * 256, x2 + ro * 256, scale, nullptr, nullptr, 1024, 256);
  }
}

// Round 7
// 357.513 us; speedup vs baseline: 1.1602x; 1.0381x over previous
//
#include <hip/hip_runtime.h>
#include <hip/hip_bf16.h>
#include <math.h>

typedef __attribute__((ext_vector_type(8))) short short8;
typedef __attribute__((ext_vector_type(4))) float f32x4;

#define DIM 256
#define NROWS 32768      // T*B*Ltot rows
#define PERT 2097152     // B*Ltot*D elements per timestep
#define SAMP_TOK 4096    // tokens per (t,b) sample

__device__ __forceinline__ float b2f(__hip_bfloat16 h){ return __bfloat162float(h); }
__device__ __forceinline__ __hip_bfloat16 f2b(float f){ return __float2bfloat16(f); }
__device__ __forceinline__ unsigned short f2bu(float f){
  __hip_bfloat16 h = __float2bfloat16(f);
  unsigned short u; __builtin_memcpy(&u, &h, 2); return u;
}

// async global -> LDS, 16B per lane (wave-uniform base + lane*16 on LDS side)
#define GLD_LDS16(gp, lp) __builtin_amdgcn_global_load_lds( \
    (const __attribute__((address_space(1))) unsigned int*)(gp), \
    (__attribute__((address_space(3))) unsigned int*)(lp), 16, 0, 0)

// branchless erf-based exact gelu (A&S 7.1.26, |err| <= ~3e-7: below bf16 ulp)
__device__ __forceinline__ float gelu_fast(float v){
  float z  = v * 0.70710678118654752f;
  float az = fabsf(z);
  float t  = __builtin_amdgcn_rcpf(fmaf(0.3275911f, az, 1.0f));
  float p  = fmaf(fmaf(fmaf(fmaf(1.061405429f, t, -1.453152027f), t,
                            1.421413741f), t, -0.284496736f), t, 0.254829592f);
  p *= t;
  float e  = __expf(-z * z);
  float y  = fmaf(-p, e, 1.0f);                 // erf(|z|)
  return fmaf(0.5f * fabsf(v), y, 0.5f * v);    // 0.5*v*(1+sign(v)*erf(|z|))
}

// ---------------- fp32 -> bf16 weight conversion (all 4 weights, one launch) ---
__global__ void f2ball_k(const float* __restrict__ w_qkv, const float* __restrict__ w_proj,
                         const float* __restrict__ w_f1, const float* __restrict__ w_f2,
                         __hip_bfloat16* __restrict__ o_qkv, __hip_bfloat16* __restrict__ o_proj,
                         __hip_bfloat16* __restrict__ o_f1, __hip_bfloat16* __restrict__ o_f2){
  int i = blockIdx.x * 256 + threadIdx.x;        // 0 .. 786431
  if (i < 196608)          o_qkv[i]           = f2b(w_qkv[i]);
  else if (i < 262144)     o_proj[i - 196608] = f2b(w_proj[i - 196608]);
  else if (i < 524288)     o_f1[i - 262144]   = f2b(w_f1[i - 262144]);
  else                     o_f2[i - 524288]   = f2b(w_f2[i - 524288]);
}

// ---------------- BN stats (branch 1): per-channel sum / sumsq -----------------
__global__ void bn_stats_k(const float* __restrict__ x, float* __restrict__ sum, float* __restrict__ sumsq){
  __shared__ __align__(16) float rs[4][256];
  __shared__ __align__(16) float rq[4][256];
  int t = threadIdx.x;
  int g = t & 63, r = t >> 6;
  size_t base = ((size_t)blockIdx.x * 128 + r) * DIM + g * 4;   // 128 rows per block
  float4 s = {0.f,0.f,0.f,0.f}, q = {0.f,0.f,0.f,0.f};
  for (int i = 0; i < 32; ++i){
    float4 v = *reinterpret_cast<const float4*>(x + base + (size_t)i * 4 * DIM);
    s.x += v.x; s.y += v.y; s.z += v.z; s.w += v.w;
    q.x += v.x*v.x; q.y += v.y*v.y; q.z += v.z*v.z; q.w += v.w*v.w;
  }
  *reinterpret_cast<float4*>(&rs[r][g*4]) = s;
  *reinterpret_cast<float4*>(&rq[r][g*4]) = q;
  __syncthreads();
  int c = t;   // one channel per thread
  atomicAdd(&sum[c],   rs[0][c] + rs[1][c] + rs[2][c] + rs[3][c]);
  atomicAdd(&sumsq[c], rq[0][c] + rq[1][c] + rq[2][c] + rq[3][c]);
}

__global__ void bn_fin_k(const float* __restrict__ sum, const float* __restrict__ sumsq,
                         const float* __restrict__ g, const float* __restrict__ b,
                         float* __restrict__ a_out, float* __restrict__ b_out){
  int c = threadIdx.x;
  float mean = sum[c] * (1.f/32768.f);
  float var  = sumsq[c] * (1.f/32768.f) - mean*mean;
  float a = g[c] / sqrtf(var + 1e-5f);
  a_out[c] = a;
  b_out[c] = b[c] - mean * a;
}

// ---------------- BN2 reduce: column-sum the 512x256 partial grids -------------
__global__ void bn_red_k(const float* __restrict__ pps, const float* __restrict__ ppq,
                         const float* __restrict__ g, const float* __restrict__ b,
                         float* __restrict__ a_out, float* __restrict__ b_out){
  int c = threadIdx.x;
  float s = 0.f, q = 0.f;
  for (int r = 0; r < 512; ++r){
    s += pps[r * 256 + c];
    q += ppq[r * 256 + c];
  }
  float mean = s * (1.f/32768.f);
  float var  = q * (1.f/32768.f) - mean*mean;
  float a = g[c] / sqrtf(var + 1e-5f);
  a_out[c] = a;
  b_out[c] = b[c] - mean * a;
}

// ---------------- LIF over T=4 (binary spike out, bf16 exact) ------------------
__global__ void lif_k(const float* __restrict__ x, const float* __restrict__ av,
                      const float* __restrict__ bv, __hip_bfloat16* __restrict__ s){
  int i = blockIdx.x * 256 + threadIdx.x;       // 0 .. PERT/4-1 (exact grid)
  int e4 = i * 4;
  int c4 = e4 & (DIM - 1);
  float4 a = *reinterpret_cast<const float4*>(av + c4);
  float4 b = *reinterpret_cast<const float4*>(bv + c4);
  float4 v = {0.f,0.f,0.f,0.f};
  #pragma unroll
  for (int t = 0; t < 4; ++t){
    float4 xn = *reinterpret_cast<const float4*>(x + (size_t)t * PERT + e4);
    xn.x = fmaf(xn.x, a.x, b.x); xn.y = fmaf(xn.y, a.y, b.y);
    xn.z = fmaf(xn.z, a.z, b.z); xn.w = fmaf(xn.w, a.w, b.w);
    v.x += (xn.x - v.x) * 0.5f; v.y += (xn.y - v.y) * 0.5f;
    v.z += (xn.z - v.z) * 0.5f; v.w += (xn.w - v.w) * 0.5f;
    ushort4 sp;
    sp.x = (v.x >= 1.0f) ? 0x3F80 : 0;  v.x = (v.x >= 1.0f) ? 0.f : v.x;
    sp.y = (v.y >= 1.0f) ? 0x3F80 : 0;  v.y = (v.y >= 1.0f) ? 0.f : v.y;
    sp.z = (v.z >= 1.0f) ? 0x3F80 : 0;  v.z = (v.z >= 1.0f) ? 0.f : v.z;
    sp.w = (v.w >= 1.0f) ? 0x3F80 : 0;  v.w = (v.w >= 1.0f) ? 0.f : v.w;
    *reinterpret_cast<ushort4*>(reinterpret_cast<unsigned short*>(s) + (size_t)t * PERT + e4) = sp;
  }
}

// ---------------- region means of binary s1 (exact fp32) -----------------------
__global__ void region_sum_k(const __hip_bfloat16* __restrict__ s, float* __restrict__ sm){
  __shared__ __align__(16) float red[4][256];
  int r = blockIdx.x, t = threadIdx.x;    // r = (sample*64 + region), 512 total
  int g = t & 63, sub = t >> 6;
  const unsigned short* sp = reinterpret_cast<const unsigned short*>(s);
  size_t base = ((size_t)r * 64 + sub * 16) * DIM + g * 4;
  float4 acc = {0.f,0.f,0.f,0.f};
  for (int i = 0; i < 16; ++i){
    ushort4 u = *reinterpret_cast<const ushort4*>(sp + base + (size_t)i * DIM);
    acc.x += (u.x != 0) ? 1.f : 0.f; acc.y += (u.y != 0) ? 1.f : 0.f;
    acc.z += (u.z != 0) ? 1.f : 0.f; acc.w += (u.w != 0) ? 1.f : 0.f;
  }
  *reinterpret_cast<float4*>(&red[sub][g*4]) = acc;
  __syncthreads();
  if (sub == 0){
    float4 o;
    o.x = (red[0][g*4+0] + red[1][g*4+0] + red[2][g*4+0] + red[3][g*4+0]) * 0.015625f;
    o.y = (red[0][g*4+1] + red[1][g*4+1] + red[2][g*4+1] + red[3][g*4+1]) * 0.015625f;
    o.z = (red[0][g*4+2] + red[1][g*4+2] + red[2][g*4+2] + red[3][g*4+2]) * 0.015625f;
    o.w = (red[0][g*4+3] + red[1][g*4+3] + red[2][g*4+3] + red[3][g*4+3]) * 0.015625f;
    *reinterpret_cast<float4*>(sm + (size_t)r * DIM + g * 4) = o;
  }
}

// ---------------- routing GEMM fp32: qkm[r][j] = smr[r]·qkv_w[j] + b[j], j<512 -
__global__ void rgemm_k(const float* __restrict__ smr, const float* __restrict__ w,
                        const float* __restrict__ bias, float* __restrict__ qkm){
  __shared__ float arow[256];
  int r = blockIdx.x, t = threadIdx.x;
  arow[t] = smr[(size_t)r * 256 + t];
  __syncthreads();
  for (int j = t; j < 512; j += 256){
    const float* wr = w + (size_t)j * 256;
    float acc = 0.f;
    for (int k = 0; k < 256; ++k) acc += arow[k] * wr[k];
    qkm[(size_t)r * 512 + j] = acc + bias[j];
  }
}

// ---------------- GEMM: C[M,N] = A[M,K] @ W[N,K]^T (+bias, epilogue) -----------
// (branch 1 only now: EPI 0 = qkv bf16 out, EPI 1 = proj f32 + residual + bn2
//  partial stats, non-atomic)
template<int EPI>
__global__ __launch_bounds__(256) void gemm_bt(
    const __hip_bfloat16* __restrict__ A, const __hip_bfloat16* __restrict__ W,
    const float* __restrict__ bias, void* __restrict__ outp,
    const void* __restrict__ extra, const float* __restrict__ scaleptr,
    float* __restrict__ pps, float* __restrict__ ppq,
    int K, int N)
{
  __shared__ __align__(16) short As0[128 * 32];   // 8KB each, linear layout
  __shared__ __align__(16) short Ws0[128 * 32];
  __shared__ __align__(16) short As1[128 * 32];
  __shared__ __align__(16) short Ws1[128 * 32];
  int tid = threadIdx.x;
  int bm = blockIdx.x, bn = blockIdx.y;
  int lane = tid & 63;
  int l16 = lane & 15, quad = lane >> 4;
  int wv = tid >> 6;
  int wm = (wv >> 1) << 6, wn = (wv & 1) << 6;

  const int srow = tid >> 2;
  const int sq   = (tid & 3) ^ ((srow >> 1) & 3);
  const __hip_bfloat16* Ag = A + (size_t)(bm * 128 + srow) * K + (sq << 3);
  const __hip_bfloat16* Wg = W + (size_t)(bn * 128 + srow) * K + (sq << 3);
  const size_t rstep = (size_t)64 * K;

  int roA[4], roW[4];
  #pragma unroll
  for (int i = 0; i < 4; ++i){
    int Ra = wm + i * 16 + l16;
    roA[i] = Ra * 32 + ((quad ^ ((Ra >> 1) & 3)) << 3);
    int Rw = wn + i * 16 + l16;
    roW[i] = Rw * 32 + ((quad ^ ((Rw >> 1) & 3)) << 3);
  }

  f32x4 zero = {0.f, 0.f, 0.f, 0.f};
  f32x4 acc[4][4];
  #pragma unroll
  for (int i = 0; i < 4; ++i)
    #pragma unroll
    for (int j = 0; j < 4; ++j) acc[i][j] = zero;

  auto stage = [&](short* Ad, short* Wd, int k0){
    GLD_LDS16(Ag + k0,         Ad + tid * 8);
    GLD_LDS16(Ag + rstep + k0, Ad + tid * 8 + 2048);
    GLD_LDS16(Wg + k0,         Wd + tid * 8);
    GLD_LDS16(Wg + rstep + k0, Wd + tid * 8 + 2048);
  };
  auto compute = [&](const short* Asb, const short* Wsb){
    short8 af[4];
    #pragma unroll
    for (int mi = 0; mi < 4; ++mi)
      af[mi] = *reinterpret_cast<const short8*>(Asb + roA[mi]);
    #pragma unroll
    for (int ni = 0; ni < 4; ++ni){
      short8 wf = *reinterpret_cast<const short8*>(Wsb + roW[ni]);
      #pragma unroll
      for (int mi = 0; mi < 4; ++mi)
        acc[mi][ni] = __builtin_amdgcn_mfma_f32_16x16x32_bf16(wf, af[mi], acc[mi][ni], 0, 0, 0);
    }
  };

  stage(As0, Ws0, 0);
  __syncthreads();
  for (int k0 = 0; k0 < K; k0 += 64){
    if (k0 + 32 < K) stage(As1, Ws1, k0 + 32);
    compute(As0, Ws0);
    __syncthreads();
    if (k0 + 64 < K) stage(As0, Ws0, k0 + 64);
    if (k0 + 32 < K) compute(As1, Ws1);
    __syncthreads();
  }

  if (EPI == 0){
    // ---- coalesced bf16 epilogue: wave-private 64x64 C-tile via dead staging LDS
    short* Cw = (wv == 0) ? As0 : (wv == 1) ? Ws0 : (wv == 2) ? As1 : Ws1;
    #pragma unroll
    for (int ni = 0; ni < 4; ++ni){
      int col0 = (bn << 7) + wn + ni * 16 + (quad << 2);
      float4 bv = *reinterpret_cast<const float4*>(bias + col0);
      #pragma unroll
      for (int mi = 0; mi < 4; ++mi){
        float v0 = acc[mi][ni][0] + bv.x;
        float v1 = acc[mi][ni][1] + bv.y;
        float v2 = acc[mi][ni][2] + bv.z;
        float v3 = acc[mi][ni][3] + bv.w;
        unsigned lo = (unsigned)f2bu(v0) | ((unsigned)f2bu(v1) << 16);
        unsigned hi = (unsigned)f2bu(v2) | ((unsigned)f2bu(v3) << 16);
        int row = mi * 16 + l16;
        int cb  = (ni * 32 + (quad << 3)) ^ ((row & 7) << 4);
        *reinterpret_cast<uint2*>(reinterpret_cast<char*>(Cw) + row * 128 + cb) =
            make_uint2(lo, hi);
      }
    }
    asm volatile("s_waitcnt lgkmcnt(0)" ::: "memory");
    #pragma unroll
    for (int p = 0; p < 8; ++p){
      int row = p * 8 + (lane >> 3);
      int cb  = ((lane & 7) << 4) ^ ((row & 7) << 4);
      uint4 val = *reinterpret_cast<const uint4*>(
          reinterpret_cast<const char*>(Cw) + row * 128 + cb);
      int rowg = (bm << 7) + wm + row;
      int colg = (bn << 7) + wn + ((lane & 7) << 3);
      *reinterpret_cast<uint4*>((__hip_bfloat16*)outp + (size_t)rowg * N + colg) = val;
    }
  } else {
    // ---- f32 epilogue (proj): residual + fused bn2 partial stats (non-atomic)
    float sc = scaleptr[0];
    float4 ts[4], tq[4];
    #pragma unroll
    for (int ni = 0; ni < 4; ++ni){ ts[ni] = {0.f,0.f,0.f,0.f}; tq[ni] = {0.f,0.f,0.f,0.f}; }
    #pragma unroll
    for (int ni = 0; ni < 4; ++ni){
      int col0 = (bn << 7) + wn + ni * 16 + (quad << 2);
      float4 bv = *reinterpret_cast<const float4*>(bias + col0);
      #pragma unroll
      for (int mi = 0; mi < 4; ++mi){
        int rowg = (bm << 7) + wm + mi * 16 + l16;
        size_t off = (size_t)rowg * N + col0;
        float v0 = acc[mi][ni][0] + bv.x;
        float v1 = acc[mi][ni][1] + bv.y;
        float v2 = acc[mi][ni][2] + bv.z;
        float v3 = acc[mi][ni][3] + bv.w;
        float4 xr = *reinterpret_cast<const float4*>((const float*)extra + off);
        float4 ov;
        ov.x = xr.x + v0 * sc; ov.y = xr.y + v1 * sc;
        ov.z = xr.z + v2 * sc; ov.w = xr.w + v3 * sc;
        *reinterpret_cast<float4*>((float*)outp + off) = ov;
        ts[ni].x += ov.x; ts[ni].y += ov.y; ts[ni].z += ov.z; ts[ni].w += ov.w;
        tq[ni].x += ov.x*ov.x; tq[ni].y += ov.y*ov.y;
        tq[ni].z += ov.z*ov.z; tq[ni].w += ov.w*ov.w;
      }
    }
    int prow = (bm << 1) + (wm >> 6);
    #pragma unroll
    for (int ni = 0; ni < 4; ++ni){
      float4 S = ts[ni], Q = tq[ni];
      #pragma unroll
      for (int m = 1; m < 16; m <<= 1){
        S.x += __shfl_xor(S.x, m); S.y += __shfl_xor(S.y, m);
        S.z += __shfl_xor(S.z, m); S.w += __shfl_xor(S.w, m);
        Q.x += __shfl_xor(Q.x, m); Q.y += __shfl_xor(Q.y, m);
        Q.z += __shfl_xor(Q.z, m); Q.w += __shfl_xor(Q.w, m);
      }
      if (l16 == 0){
        int col0 = (bn << 7) + wn + ni * 16 + (quad << 2);
        *reinterpret_cast<float4*>(pps + prow * 256 + col0) = S;
        *reinterpret_cast<float4*>(ppq + prow * 256 + col0) = Q;
      }
    }
  }
}

// ---------------- FUSED FFN: out = x2 + (gelu(s2@W1^T+b1)@W2^T+b2)*scale -------
// Block = 64 rows, 4 waves (N-split). Loop c1 over 8 chunks of 128 h-cols:
//   GEMM1 (K=256, dbuf LDS staging, swapped MFMA) -> bias+gelu in regs ->
//   h[64][132] bf16 into LDS -> GEMM2 partial (K=128, W2 slice dbuf) into acc2.
// h never touches HBM (was 64MB write + 64MB read as h1 in the split version).
// LDS carve (shorts): staging [0,16384) = G1{A0 0,W0 2048,A1 6144,W1b 8192} /
// G2{W2_0 0, W2_1 8192};  h [16384, 24832). Total 49664 B.
__global__ __launch_bounds__(256) void ffn_fused_k(
    const __hip_bfloat16* __restrict__ A,   // s2 [32768,256]
    const __hip_bfloat16* __restrict__ W1,  // [1024,256] bf16
    const float* __restrict__ b1,
    const __hip_bfloat16* __restrict__ W2,  // [256,1024] bf16
    const float* __restrict__ b2,
    float* __restrict__ x2,                 // in/out [32768,256] f32
    const float* __restrict__ scaleptr)
{
  __shared__ __align__(16) short lds[24832];
  const int tid = threadIdx.x;
  const int bm = blockIdx.x;               // 512 blocks x 64 rows
  const int lane = tid & 63;
  const int l16 = lane & 15, quad = lane >> 4;
  const int wv = tid >> 6;                 // wave: N-split only

  const int srow = tid >> 2;               // 0..63
  const int sq   = (tid & 3) ^ ((srow >> 1) & 3);
  const __hip_bfloat16* Ag = A + (size_t)(bm * 64 + srow) * 256 + (sq << 3);

  // read offsets (shorts)
  int roA[4], roH[4], roW1[2], roW2[4];
  #pragma unroll
  for (int mi = 0; mi < 4; ++mi){
    int Ra = mi * 16 + l16;
    roA[mi] = Ra * 32 + ((quad ^ ((Ra >> 1) & 3)) << 3);
    roH[mi] = 16384 + Ra * 132 + (quad << 3);
  }
  #pragma unroll
  for (int ni = 0; ni < 2; ++ni){
    int Rw = wv * 32 + ni * 16 + l16;
    roW1[ni] = Rw * 32 + ((quad ^ ((Rw >> 1) & 3)) << 3);
  }
  #pragma unroll
  for (int ni = 0; ni < 4; ++ni){
    int Rw = wv * 64 + ni * 16 + l16;
    roW2[ni] = Rw * 32 + ((quad ^ ((Rw >> 1) & 3)) << 3);
  }

  f32x4 zero = {0.f, 0.f, 0.f, 0.f};
  f32x4 acc2[4][4];
  #pragma unroll
  for (int i = 0; i < 4; ++i)
    #pragma unroll
    for (int j = 0; j < 4; ++j) acc2[i][j] = zero;

  for (int c1 = 0; c1 < 8; ++c1){
    f32x4 acc1[4][2];
    #pragma unroll
    for (int i = 0; i < 4; ++i){ acc1[i][0] = zero; acc1[i][1] = zero; }

    const __hip_bfloat16* W1g = W1 + (size_t)(c1 * 128 + srow) * 256 + (sq << 3);

    // ---- GEMM1: h_chunk[64x128] = A[64x256] @ W1[c1 slice]^T, 8 k-steps dbuf
    auto stage1 = [&](int off, int k0){
      GLD_LDS16(Ag + k0,              lds + off + tid * 8);           // A [64x32]
      GLD_LDS16(W1g + k0,             lds + off + 2048 + tid * 8);    // W1 rows 0..63
      GLD_LDS16(W1g + 64 * 256 + k0,  lds + off + 2048 + tid * 8 + 2048); // rows 64..127
    };
    stage1(0, 0);
    __syncthreads();
    #pragma unroll
    for (int k = 0; k < 8; ++k){
      const int cur = (k & 1) ? 6144 : 0;
      const int nxt = (k & 1) ? 0 : 6144;
      if (k < 7) stage1(nxt, (k + 1) * 32);
      short8 af[4];
      #pragma unroll
      for (int mi = 0; mi < 4; ++mi)
        af[mi] = *reinterpret_cast<const short8*>(lds + cur + roA[mi]);
      #pragma unroll
      for (int ni = 0; ni < 2; ++ni){
        short8 wf = *reinterpret_cast<const short8*>(lds + cur + 2048 + roW1[ni]);
        #pragma unroll
        for (int mi = 0; mi < 4; ++mi)
          acc1[mi][ni] = __builtin_amdgcn_mfma_f32_16x16x32_bf16(wf, af[mi], acc1[mi][ni], 0, 0, 0);
      }
      __syncthreads();
    }

    // ---- bias + gelu + pack h into LDS; prefetch W2 slice kk=0 concurrently
    auto stageW2 = [&](int off, int kk){
      const __hip_bfloat16* p = W2 + (size_t)srow * 1024 + c1 * 128 + kk * 32 + (sq << 3);
      #pragma unroll
      for (int j = 0; j < 4; ++j)
        GLD_LDS16(p + (size_t)j * 64 * 1024, lds + off + tid * 8 + j * 2048);
    };
    stageW2(0, 0);
    #pragma unroll
    for (int ni = 0; ni < 2; ++ni){
      int colg = c1 * 128 + wv * 32 + ni * 16 + (quad << 2);
      float4 bv = *reinterpret_cast<const float4*>(b1 + colg);
      #pragma unroll
      for (int mi = 0; mi < 4; ++mi){
        float g0 = gelu_fast(acc1[mi][ni][0] + bv.x);
        float g1 = gelu_fast(acc1[mi][ni][1] + bv.y);
        float g2 = gelu_fast(acc1[mi][ni][2] + bv.z);
        float g3 = gelu_fast(acc1[mi][ni][3] + bv.w);
        unsigned lo = (unsigned)f2bu(g0) | ((unsigned)f2bu(g1) << 16);
        unsigned hi = (unsigned)f2bu(g2) | ((unsigned)f2bu(g3) << 16);
        *reinterpret_cast<uint2*>(
            lds + 16384 + (mi * 16 + l16) * 132 + wv * 32 + ni * 16 + (quad << 2)) =
            make_uint2(lo, hi);
      }
    }
    __syncthreads();   // h visible + W2_0 staged

    // ---- GEMM2 partial: acc2 += h[64x128] @ W2[:, c1 slice]^T, 4 k-steps dbuf
    #pragma unroll
    for (int kk = 0; kk < 4; ++kk){
      const int cur = (kk & 1) ? 8192 : 0;
      const int nxt = (kk & 1) ? 0 : 8192;
      if (kk < 3) stageW2(nxt, kk + 1);
      short8 af[4];
      #pragma unroll
      for (int mi = 0; mi < 4; ++mi)
        af[mi] = *reinterpret_cast<const short8*>(lds + roH[mi] + kk * 32);
      #pragma unroll
      for (int ni = 0; ni < 4; ++ni){
        short8 wf = *reinterpret_cast<const short8*>(lds + cur + roW2[ni]);
        #pragma unroll
        for (int mi = 0; mi < 4; ++mi)
          acc2[mi][ni] = __builtin_amdgcn_mfma_f32_16x16x32_bf16(wf, af[mi], acc2[mi][ni], 0, 0, 0);
      }
      __syncthreads();
    }
  }

  // ---- epilogue: out = x2 + (acc2 + b2)*scale, float4 (full-sector stores)
  float sc = scaleptr[0];
  #pragma unroll
  for (int ni = 0; ni < 4; ++ni){
    int col0 = wv * 64 + ni * 16 + (quad << 2);
    float4 bv = *reinterpret_cast<const float4*>(b2 + col0);
    #pragma unroll
    for (int mi = 0; mi < 4; ++mi){
      int rowg = bm * 64 + mi * 16 + l16;
      size_t off = (size_t)rowg * 256 + col0;
      float4 xr = *reinterpret_cast<const float4*>(x2 + off);
      float4 ov;
      ov.x = xr.x + (acc2[mi][ni][0] + bv.x) * sc;
      ov.y = xr.y + (acc2[mi][ni][1] + bv.y) * sc;
      ov.z = xr.z + (acc2[mi][ni][2] + bv.z) * sc;
      ov.w = xr.w + (acc2[mi][ni][3] + bv.w) * sc;
      *reinterpret_cast<float4*>(x2 + off) = ov;
    }
  }
}

// ---------------- top-k routing: aff = qm @ km^T per sample, pick top-4 --------
__global__ void topk_k(const float* __restrict__ qkm, int* __restrict__ idx){
  __shared__ float aff[64];
  int r = blockIdx.x;           // sample*64 + query region
  int m = threadIdx.x;          // candidate region 0..63
  int b = r >> 6;
  const float4* qrow = reinterpret_cast<const float4*>(qkm + (size_t)r * 512);
  const float4* krow = reinterpret_cast<const float4*>(qkm + (size_t)(b * 64 + m) * 512 + 256);
  float dot = 0.f;
  for (int d = 0; d < 64; ++d){
    float4 qv = qrow[d], kv = krow[d];
    dot += qv.x * kv.x + qv.y * kv.y + qv.z * kv.z + qv.w * kv.w;
  }
  aff[m] = dot;
  __syncthreads();
  if (m == 0){
    #pragma unroll
    for (int t = 0; t < 4; ++t){
      float best = -INFINITY; int bi = 0;
      for (int i = 0; i < 64; ++i){
        if (aff[i] > best){ best = aff[i]; bi = i; }   // strict >: lowest index on ties (jax top_k)
      }
      aff[bi] = -INFINITY;
      idx[r * 4 + t] = bi;
    }
  }
}

// ---------------- MFMA routed attention: block per (region, head) --------------
__global__ __launch_bounds__(256) void attn_mfma_k(
    const __hip_bfloat16* __restrict__ qkv, const int* __restrict__ idx,
    __hip_bfloat16* __restrict__ o_out, int rbase)
{
  __shared__ __align__(16) short lds[27136];
  const int rl = blockIdx.x;       // local region in this chunk
  const int h  = blockIdx.y;       // head
  const int rg = rbase + rl;       // global region (for idx)
  const int bl = rl >> 6;          // local sample
  const int tid = threadIdx.x;
  const int w = tid >> 6, lane = tid & 63;
  const int l16 = lane & 15, quad = lane >> 4;
  short* Pw = lds + 10240 + w * 4224;

  const int reg = idx[rg * 4 + (tid >> 6)] & 63;       // clamp: never OOB
  const size_t srow = (size_t)bl * SAMP_TOK + (size_t)reg * 64 + (tid & 63);
  const __hip_bfloat16* kvsrc = qkv + srow * 768 + 256 + (size_t)h * 32;

  const size_t qrow = (size_t)rl * 64 + w * 16 + l16;
  short8 qf = *reinterpret_cast<const short8*>(qkv + qrow * 768 + (size_t)h * 32 + quad * 8);

  uint4 vreg[4];
  #pragma unroll
  for (int c = 0; c < 4; ++c)
    vreg[c] = *reinterpret_cast<const uint4*>(kvsrc + 256 + c * 8);

  #pragma unroll
  for (int c = 0; c < 4; ++c)
    *reinterpret_cast<uint4*>(&lds[tid * 40 + c * 8]) =
      *reinterpret_cast<const uint4*>(kvsrc + c * 8);
  __syncthreads();

  f32x4 s[16];
  #pragma unroll
  for (int nt = 0; nt < 16; ++nt){
    short8 kf = *reinterpret_cast<const short8*>(&lds[(nt * 16 + l16) * 40 + quad * 8]);
    f32x4 z = {0.f, 0.f, 0.f, 0.f};
    s[nt] = __builtin_amdgcn_mfma_f32_16x16x32_bf16(kf, qf, z, 0, 0, 0);
  }
  __syncthreads();

  #pragma unroll
  for (int c = 0; c < 4; ++c){
    short8 vv = *reinterpret_cast<short8*>(&vreg[c]);
    #pragma unroll
    for (int e = 0; e < 8; ++e)
      lds[(c * 8 + e) * 264 + tid] = vv[e];
  }

  float mx = -1e30f;
  #pragma unroll
  for (int nt = 0; nt < 16; ++nt)
    #pragma unroll
    for (int r = 0; r < 4; ++r) mx = fmaxf(mx, s[nt][r]);
  mx = fmaxf(mx, __shfl_xor(mx, 16));
  mx = fmaxf(mx, __shfl_xor(mx, 32));
  float den = 0.f;
  #pragma unroll
  for (int nt = 0; nt < 16; ++nt)
    #pragma unroll
    for (int r = 0; r < 4; ++r){
      float e = __expf((s[nt][r] - mx) * 0.17677669529663687f);  // scale folded in
      s[nt][r] = e; den += e;
    }
  den += __shfl_xor(den, 16);
  den += __shfl_xor(den, 32);

  #pragma unroll
  for (int nt = 0; nt < 16; ++nt){
    unsigned lo = (unsigned)f2bu(s[nt][0]) | ((unsigned)f2bu(s[nt][1]) << 16);
    unsigned hi = (unsigned)f2bu(s[nt][2]) | ((unsigned)f2bu(s[nt][3]) << 16);
    *reinterpret_cast<uint2*>(&Pw[l16 * 264 + nt * 16 + quad * 4]) = make_uint2(lo, hi);
  }
  __syncthreads();

  f32x4 o0 = {0.f, 0.f, 0.f, 0.f}, o1 = o0;
  #pragma unroll
  for (int kk = 0; kk < 8; ++kk){
    short8 pb = *reinterpret_cast<const short8*>(&Pw[l16 * 264 + kk * 32 + quad * 8]);
    short8 a0 = *reinterpret_cast<const short8*>(&lds[l16 * 264 + kk * 32 + quad * 8]);
    short8 a1 = *reinterpret_cast<const short8*>(&lds[(16 + l16) * 264 + kk * 32 + quad * 8]);
    o0 = __builtin_amdgcn_mfma_f32_16x16x32_bf16(a0, pb, o0, 0, 0, 0);
    o1 = __builtin_amdgcn_mfma_f32_16x16x32_bf16(a1, pb, o1, 0, 0, 0);
  }
  float inv = 1.f / den;
  size_t obase = ((size_t)rl * 64 + w * 16 + l16) * 256 + (size_t)h * 32;
  unsigned pk0 = (unsigned)f2bu(o0[0] * inv) | ((unsigned)f2bu(o0[1] * inv) << 16);
  unsigned pk1 = (unsigned)f2bu(o0[2] * inv) | ((unsigned)f2bu(o0[3] * inv) << 16);
  unsigned pk2 = (unsigned)f2bu(o1[0] * inv) | ((unsigned)f2bu(o1[1] * inv) << 16);
  unsigned pk3 = (unsigned)f2bu(o1[2] * inv) | ((unsigned)f2bu(o1[3] * inv) << 16);
  *reinterpret_cast<uint2*>(o_out + obase + quad * 4)      = make_uint2(pk0, pk1);
  *reinterpret_cast<uint2*>(o_out + obase + 16 + quad * 4) = make_uint2(pk2, pk3);
}

// -------------------------------------------------------------------------------
// STRICT ws budget (never write beyond ws_size):
//   [0,4MB)   misc: BN sums/coeffs, idxb, smr, qkm, bf16 weights, bn2 partials
//   [4,20MB)  s1 (branch1) then s2 (branch2), bf16 16MB
//   [20MB,..) chunk buffers (branch1 only now), adaptively sized from ws_size.
// x2 (fp32 [32768,256], 32MB) lives in d_out; fused FFN updates d_out in place.
// Minimum ws_size supported: 28MB.
extern "C" void kernel_launch(void* const* d_in, const int* in_sizes, int n_in,
                              void* d_out, int out_size, void* d_ws, size_t ws_size,
                              hipStream_t stream)
{
  const float* x      = (const float*)d_in[0];
  const float* bn1_g  = (const float*)d_in[1];
  const float* bn1_b  = (const float*)d_in[2];
  const float* bn2_g  = (const float*)d_in[3];
  const float* bn2_b  = (const float*)d_in[4];
  const float* qkv_w  = (const float*)d_in[5];
  const float* qkv_b  = (const float*)d_in[6];
  const float* proj_w = (const float*)d_in[7];
  const float* proj_b = (const float*)d_in[8];
  const float* ffn_w1 = (const float*)d_in[9];
  const float* ffn_b1 = (const float*)d_in[10];
  const float* ffn_w2 = (const float*)d_in[11];
  const float* ffn_b2 = (const float*)d_in[12];
  const float* scale  = (const float*)d_in[13];
  float* x2 = (float*)d_out;       // residual lives in d_out

  char* ws = (char*)d_ws;
  const size_t MB = 1024 * 1024;
  float* sum1 = (float*)(ws + 0);
  float* sq1  = (float*)(ws + 1024);
  float* a1   = (float*)(ws + 4096);
  float* b1   = (float*)(ws + 5120);
  float* a2   = (float*)(ws + 6144);
  float* b2   = (float*)(ws + 7168);
  int*   idxb = (int*)(ws + 8192);                              // 8KB
  float* smr  = (float*)(ws + 16384);                           // 512KB
  float* qkm  = (float*)(ws + 540672);                          // 1MB
  __hip_bfloat16* qkv_wb  = (__hip_bfloat16*)(ws + 1589248);    // 384KB
  __hip_bfloat16* proj_wb = (__hip_bfloat16*)(ws + 1982464);    // 128KB
  __hip_bfloat16* ffn_w1b = (__hip_bfloat16*)(ws + 2113536);    // 512KB
  __hip_bfloat16* ffn_w2b = (__hip_bfloat16*)(ws + 2637824);    // 512KB, ends 3162112
  float* ppsum = (float*)(ws + 3162112);                        // 512KB (512x256 f32)
  float* ppsq  = (float*)(ws + 3686400);                        // 512KB, ends 4MB exactly
  __hip_bfloat16* s1 = (__hip_bfloat16*)(ws + 4 * MB);          // 16MB (s2 reuses)
  __hip_bfloat16* s2 = s1;
  char* chunkbuf = ws + 20 * MB;

  // adaptive chunk sizes from ws_size (constant across calls -> graph-safe)
  size_t avail = (ws_size > 20 * MB) ? (ws_size - 20 * MB) : (8 * MB);
  int nc = (avail >= 64 * MB) ? 8 : (avail >= 32 * MB) ? 4 : (avail >= 16 * MB) ? 2 : 1;   // samples/chunk (8MB each)

  __hip_bfloat16* qkvc = (__hip_bfloat16*)chunkbuf;                        // nc*6MB
  __hip_bfloat16* oc   = (__hip_bfloat16*)(chunkbuf + (size_t)nc * 6 * MB); // nc*2MB

  hipMemsetAsync(d_ws, 0, 4096, stream);   // zero BN1 accumulators

  // one-time weight conversions fp32 -> bf16 (single launch)
  f2ball_k<<<3072, 256, 0, stream>>>(qkv_w, proj_w, ffn_w1, ffn_w2,
                                     qkv_wb, proj_wb, ffn_w1b, ffn_w2b);

  // branch 1: BN -> LIF -> routing, then per-chunk qkv -> attn -> proj+residual
  bn_stats_k<<<256, 256, 0, stream>>>(x, sum1, sq1);
  bn_fin_k<<<1, 256, 0, stream>>>(sum1, sq1, bn1_g, bn1_b, a1, b1);
  lif_k<<<PERT / 1024, 256, 0, stream>>>(x, a1, b1, s1);
  region_sum_k<<<512, 256, 0, stream>>>(s1, smr);
  rgemm_k<<<512, 256, 0, stream>>>(smr, qkv_w, qkv_b, qkm);   // fp32 routing (flip-proof)
  topk_k<<<512, 64, 0, stream>>>(qkm, idxb);

  const int nchunkA = 8 / nc;
  for (int c = 0; c < nchunkA; ++c){
    const size_t ro = (size_t)c * nc * SAMP_TOK;            // row offset (tokens)
    gemm_bt<0><<<dim3(nc * SAMP_TOK / 128, 6), 256, 0, stream>>>(
        s1 + ro * 256, qkv_wb, qkv_b, qkvc, nullptr, nullptr, nullptr, nullptr, 256, 768);
    attn_mfma_k<<<dim3(nc * 64, 8), 256, 0, stream>>>(qkvc, idxb, oc, c * nc * 64);
    gemm_bt<1><<<dim3(nc * SAMP_TOK / 128, 2), 256, 0, stream>>>(
        oc, proj_wb, proj_b, x2 + ro * 256, x + ro * 256, scale,
        ppsum + (ro >> 6) * 256, ppsq + (ro >> 6) * 256, 256, 256);
  }

  // branch 2: bn2 partial-reduce (atomic-free) -> LIF -> fused FFN (in-place)
  bn_red_k<<<1, 256, 0, stream>>>(ppsum, ppsq, bn2_g, bn2_b, a2, b2);
  lif_k<<<PERT / 1024, 256, 0, stream>>>(x2, a2, b2, s2);
  ffn_fused_k<<<512, 256, 0, stream>>>(s2, ffn_w1b, ffn_b1, ffn_w2b, ffn_b2, x2, scale);
}

// Round 8
// 349.830 us; speedup vs baseline: 1.1857x; 1.0220x over previous
//
#include <hip/hip_runtime.h>
#include <hip/hip_bf16.h>
#include <math.h>

typedef __attribute__((ext_vector_type(8))) short short8;
typedef __attribute__((ext_vector_type(4))) float f32x4;

#define DIM 256
#define NROWS 32768      // T*B*Ltot rows
#define PERT 2097152     // B*Ltot*D elements per timestep
#define SAMP_TOK 4096    // tokens per (t,b) sample

__device__ __forceinline__ float b2f(__hip_bfloat16 h){ return __bfloat162float(h); }
__device__ __forceinline__ __hip_bfloat16 f2b(float f){ return __float2bfloat16(f); }
__device__ __forceinline__ unsigned short f2bu(float f){
  __hip_bfloat16 h = __float2bfloat16(f);
  unsigned short u; __builtin_memcpy(&u, &h, 2); return u;
}

// async global -> LDS, 16B per lane (wave-uniform base + lane*16 on LDS side)
#define GLD_LDS16(gp, lp) __builtin_amdgcn_global_load_lds( \
    (const __attribute__((address_space(1))) unsigned int*)(gp), \
    (__attribute__((address_space(3))) unsigned int*)(lp), 16, 0, 0)

// counted-vmcnt barrier primitives (T4): memory clobbers fence compiler vmem motion
#define VMCNT3 asm volatile("s_waitcnt vmcnt(3)" ::: "memory")
#define VMCNT0 asm volatile("s_waitcnt vmcnt(0)" ::: "memory")
#define SBAR()  do { __builtin_amdgcn_s_barrier(); asm volatile("" ::: "memory"); } while(0)

// branchless erf-based exact gelu (A&S 7.1.26, |err| <= ~3e-7: below bf16 ulp)
__device__ __forceinline__ float gelu_fast(float v){
  float z  = v * 0.70710678118654752f;
  float az = fabsf(z);
  float t  = __builtin_amdgcn_rcpf(fmaf(0.3275911f, az, 1.0f));
  float p  = fmaf(fmaf(fmaf(fmaf(1.061405429f, t, -1.453152027f), t,
                            1.421413741f), t, -0.284496736f), t, 0.254829592f);
  p *= t;
  float e  = __expf(-z * z);
  float y  = fmaf(-p, e, 1.0f);                 // erf(|z|)
  return fmaf(0.5f * fabsf(v), y, 0.5f * v);    // 0.5*v*(1+sign(v)*erf(|z|))
}

// ---------------- fp32 -> bf16 weight conversion (all 4 weights, one launch) ---
__global__ void f2ball_k(const float* __restrict__ w_qkv, const float* __restrict__ w_proj,
                         const float* __restrict__ w_f1, const float* __restrict__ w_f2,
                         __hip_bfloat16* __restrict__ o_qkv, __hip_bfloat16* __restrict__ o_proj,
                         __hip_bfloat16* __restrict__ o_f1, __hip_bfloat16* __restrict__ o_f2){
  int i = blockIdx.x * 256 + threadIdx.x;        // 0 .. 786431
  if (i < 196608)          o_qkv[i]           = f2b(w_qkv[i]);
  else if (i < 262144)     o_proj[i - 196608] = f2b(w_proj[i - 196608]);
  else if (i < 524288)     o_f1[i - 262144]   = f2b(w_f1[i - 262144]);
  else                     o_f2[i - 524288]   = f2b(w_f2[i - 524288]);
}

// ---------------- BN stats (branch 1): per-channel sum / sumsq -----------------
__global__ void bn_stats_k(const float* __restrict__ x, float* __restrict__ sum, float* __restrict__ sumsq){
  __shared__ __align__(16) float rs[4][256];
  __shared__ __align__(16) float rq[4][256];
  int t = threadIdx.x;
  int g = t & 63, r = t >> 6;
  size_t base = ((size_t)blockIdx.x * 128 + r) * DIM + g * 4;   // 128 rows per block
  float4 s = {0.f,0.f,0.f,0.f}, q = {0.f,0.f,0.f,0.f};
  for (int i = 0; i < 32; ++i){
    float4 v = *reinterpret_cast<const float4*>(x + base + (size_t)i * 4 * DIM);
    s.x += v.x; s.y += v.y; s.z += v.z; s.w += v.w;
    q.x += v.x*v.x; q.y += v.y*v.y; q.z += v.z*v.z; q.w += v.w*v.w;
  }
  *reinterpret_cast<float4*>(&rs[r][g*4]) = s;
  *reinterpret_cast<float4*>(&rq[r][g*4]) = q;
  __syncthreads();
  int c = t;   // one channel per thread
  atomicAdd(&sum[c],   rs[0][c] + rs[1][c] + rs[2][c] + rs[3][c]);
  atomicAdd(&sumsq[c], rq[0][c] + rq[1][c] + rq[2][c] + rq[3][c]);
}

__global__ void bn_fin_k(const float* __restrict__ sum, const float* __restrict__ sumsq,
                         const float* __restrict__ g, const float* __restrict__ b,
                         float* __restrict__ a_out, float* __restrict__ b_out){
  int c = threadIdx.x;
  float mean = sum[c] * (1.f/32768.f);
  float var  = sumsq[c] * (1.f/32768.f) - mean*mean;
  float a = g[c] / sqrtf(var + 1e-5f);
  a_out[c] = a;
  b_out[c] = b[c] - mean * a;
}

// ---------------- BN2 reduce: column-sum the 512x256 partial grids -------------
__global__ void bn_red_k(const float* __restrict__ pps, const float* __restrict__ ppq,
                         const float* __restrict__ g, const float* __restrict__ b,
                         float* __restrict__ a_out, float* __restrict__ b_out){
  int c = threadIdx.x;
  float s = 0.f, q = 0.f;
  for (int r = 0; r < 512; ++r){
    s += pps[r * 256 + c];
    q += ppq[r * 256 + c];
  }
  float mean = s * (1.f/32768.f);
  float var  = q * (1.f/32768.f) - mean*mean;
  float a = g[c] / sqrtf(var + 1e-5f);
  a_out[c] = a;
  b_out[c] = b[c] - mean * a;
}

// ---------------- LIF over T=4 (binary spike out, bf16 exact) ------------------
__global__ void lif_k(const float* __restrict__ x, const float* __restrict__ av,
                      const float* __restrict__ bv, __hip_bfloat16* __restrict__ s){
  int i = blockIdx.x * 256 + threadIdx.x;       // 0 .. PERT/4-1 (exact grid)
  int e4 = i * 4;
  int c4 = e4 & (DIM - 1);
  float4 a = *reinterpret_cast<const float4*>(av + c4);
  float4 b = *reinterpret_cast<const float4*>(bv + c4);
  float4 v = {0.f,0.f,0.f,0.f};
  #pragma unroll
  for (int t = 0; t < 4; ++t){
    float4 xn = *reinterpret_cast<const float4*>(x + (size_t)t * PERT + e4);
    xn.x = fmaf(xn.x, a.x, b.x); xn.y = fmaf(xn.y, a.y, b.y);
    xn.z = fmaf(xn.z, a.z, b.z); xn.w = fmaf(xn.w, a.w, b.w);
    v.x += (xn.x - v.x) * 0.5f; v.y += (xn.y - v.y) * 0.5f;
    v.z += (xn.z - v.z) * 0.5f; v.w += (xn.w - v.w) * 0.5f;
    ushort4 sp;
    sp.x = (v.x >= 1.0f) ? 0x3F80 : 0;  v.x = (v.x >= 1.0f) ? 0.f : v.x;
    sp.y = (v.y >= 1.0f) ? 0x3F80 : 0;  v.y = (v.y >= 1.0f) ? 0.f : v.y;
    sp.z = (v.z >= 1.0f) ? 0x3F80 : 0;  v.z = (v.z >= 1.0f) ? 0.f : v.z;
    sp.w = (v.w >= 1.0f) ? 0x3F80 : 0;  v.w = (v.w >= 1.0f) ? 0.f : v.w;
    *reinterpret_cast<ushort4*>(reinterpret_cast<unsigned short*>(s) + (size_t)t * PERT + e4) = sp;
  }
}

// ---------------- region means of binary s1 (exact fp32) -----------------------
__global__ void region_sum_k(const __hip_bfloat16* __restrict__ s, float* __restrict__ sm){
  __shared__ __align__(16) float red[4][256];
  int r = blockIdx.x, t = threadIdx.x;    // r = (sample*64 + region), 512 total
  int g = t & 63, sub = t >> 6;
  const unsigned short* sp = reinterpret_cast<const unsigned short*>(s);
  size_t base = ((size_t)r * 64 + sub * 16) * DIM + g * 4;
  float4 acc = {0.f,0.f,0.f,0.f};
  for (int i = 0; i < 16; ++i){
    ushort4 u = *reinterpret_cast<const ushort4*>(sp + base + (size_t)i * DIM);
    acc.x += (u.x != 0) ? 1.f : 0.f; acc.y += (u.y != 0) ? 1.f : 0.f;
    acc.z += (u.z != 0) ? 1.f : 0.f; acc.w += (u.w != 0) ? 1.f : 0.f;
  }
  *reinterpret_cast<float4*>(&red[sub][g*4]) = acc;
  __syncthreads();
  if (sub == 0){
    float4 o;
    o.x = (red[0][g*4+0] + red[1][g*4+0] + red[2][g*4+0] + red[3][g*4+0]) * 0.015625f;
    o.y = (red[0][g*4+1] + red[1][g*4+1] + red[2][g*4+1] + red[3][g*4+1]) * 0.015625f;
    o.z = (red[0][g*4+2] + red[1][g*4+2] + red[2][g*4+2] + red[3][g*4+2]) * 0.015625f;
    o.w = (red[0][g*4+3] + red[1][g*4+3] + red[2][g*4+3] + red[3][g*4+3]) * 0.015625f;
    *reinterpret_cast<float4*>(sm + (size_t)r * DIM + g * 4) = o;
  }
}

// ---------------- routing GEMM fp32: qkm[r][j] = smr[r]·qkv_w[j] + b[j], j<512 -
__global__ void rgemm_k(const float* __restrict__ smr, const float* __restrict__ w,
                        const float* __restrict__ bias, float* __restrict__ qkm){
  __shared__ float arow[256];
  int r = blockIdx.x, t = threadIdx.x;
  arow[t] = smr[(size_t)r * 256 + t];
  __syncthreads();
  for (int j = t; j < 512; j += 256){
    const float* wr = w + (size_t)j * 256;
    float acc = 0.f;
    for (int k = 0; k < 256; ++k) acc += arow[k] * wr[k];
    qkm[(size_t)r * 512 + j] = acc + bias[j];
  }
}

// ---------------- GEMM: C[M,N] = A[M,K] @ W[N,K]^T (+bias, epilogue) -----------
// (branch 1 only: EPI 0 = qkv bf16 out, EPI 1 = proj f32 + residual + bn2
//  partial stats, non-atomic)
template<int EPI>
__global__ __launch_bounds__(256) void gemm_bt(
    const __hip_bfloat16* __restrict__ A, const __hip_bfloat16* __restrict__ W,
    const float* __restrict__ bias, void* __restrict__ outp,
    const void* __restrict__ extra, const float* __restrict__ scaleptr,
    float* __restrict__ pps, float* __restrict__ ppq,
    int K, int N)
{
  __shared__ __align__(16) short As0[128 * 32];   // 8KB each, linear layout
  __shared__ __align__(16) short Ws0[128 * 32];
  __shared__ __align__(16) short As1[128 * 32];
  __shared__ __align__(16) short Ws1[128 * 32];
  int tid = threadIdx.x;
  int bm = blockIdx.x, bn = blockIdx.y;
  int lane = tid & 63;
  int l16 = lane & 15, quad = lane >> 4;
  int wv = tid >> 6;
  int wm = (wv >> 1) << 6, wn = (wv & 1) << 6;

  const int srow = tid >> 2;
  const int sq   = (tid & 3) ^ ((srow >> 1) & 3);
  const __hip_bfloat16* Ag = A + (size_t)(bm * 128 + srow) * K + (sq << 3);
  const __hip_bfloat16* Wg = W + (size_t)(bn * 128 + srow) * K + (sq << 3);
  const size_t rstep = (size_t)64 * K;

  int roA[4], roW[4];
  #pragma unroll
  for (int i = 0; i < 4; ++i){
    int Ra = wm + i * 16 + l16;
    roA[i] = Ra * 32 + ((quad ^ ((Ra >> 1) & 3)) << 3);
    int Rw = wn + i * 16 + l16;
    roW[i] = Rw * 32 + ((quad ^ ((Rw >> 1) & 3)) << 3);
  }

  f32x4 zero = {0.f, 0.f, 0.f, 0.f};
  f32x4 acc[4][4];
  #pragma unroll
  for (int i = 0; i < 4; ++i)
    #pragma unroll
    for (int j = 0; j < 4; ++j) acc[i][j] = zero;

  auto stage = [&](short* Ad, short* Wd, int k0){
    GLD_LDS16(Ag + k0,         Ad + tid * 8);
    GLD_LDS16(Ag + rstep + k0, Ad + tid * 8 + 2048);
    GLD_LDS16(Wg + k0,         Wd + tid * 8);
    GLD_LDS16(Wg + rstep + k0, Wd + tid * 8 + 2048);
  };
  auto compute = [&](const short* Asb, const short* Wsb){
    short8 af[4];
    #pragma unroll
    for (int mi = 0; mi < 4; ++mi)
      af[mi] = *reinterpret_cast<const short8*>(Asb + roA[mi]);
    #pragma unroll
    for (int ni = 0; ni < 4; ++ni){
      short8 wf = *reinterpret_cast<const short8*>(Wsb + roW[ni]);
      #pragma unroll
      for (int mi = 0; mi < 4; ++mi)
        acc[mi][ni] = __builtin_amdgcn_mfma_f32_16x16x32_bf16(wf, af[mi], acc[mi][ni], 0, 0, 0);
    }
  };

  stage(As0, Ws0, 0);
  __syncthreads();
  for (int k0 = 0; k0 < K; k0 += 64){
    if (k0 + 32 < K) stage(As1, Ws1, k0 + 32);
    compute(As0, Ws0);
    __syncthreads();
    if (k0 + 64 < K) stage(As0, Ws0, k0 + 64);
    if (k0 + 32 < K) compute(As1, Ws1);
    __syncthreads();
  }

  if (EPI == 0){
    // ---- coalesced bf16 epilogue: wave-private 64x64 C-tile via dead staging LDS
    short* Cw = (wv == 0) ? As0 : (wv == 1) ? Ws0 : (wv == 2) ? As1 : Ws1;
    #pragma unroll
    for (int ni = 0; ni < 4; ++ni){
      int col0 = (bn << 7) + wn + ni * 16 + (quad << 2);
      float4 bv = *reinterpret_cast<const float4*>(bias + col0);
      #pragma unroll
      for (int mi = 0; mi < 4; ++mi){
        float v0 = acc[mi][ni][0] + bv.x;
        float v1 = acc[mi][ni][1] + bv.y;
        float v2 = acc[mi][ni][2] + bv.z;
        float v3 = acc[mi][ni][3] + bv.w;
        unsigned lo = (unsigned)f2bu(v0) | ((unsigned)f2bu(v1) << 16);
        unsigned hi = (unsigned)f2bu(v2) | ((unsigned)f2bu(v3) << 16);
        int row = mi * 16 + l16;
        int cb  = (ni * 32 + (quad << 3)) ^ ((row & 7) << 4);
        *reinterpret_cast<uint2*>(reinterpret_cast<char*>(Cw) + row * 128 + cb) =
            make_uint2(lo, hi);
      }
    }
    asm volatile("s_waitcnt lgkmcnt(0)" ::: "memory");
    #pragma unroll
    for (int p = 0; p < 8; ++p){
      int row = p * 8 + (lane >> 3);
      int cb  = ((lane & 7) << 4) ^ ((row & 7) << 4);
      uint4 val = *reinterpret_cast<const uint4*>(
          reinterpret_cast<const char*>(Cw) + row * 128 + cb);
      int rowg = (bm << 7) + wm + row;
      int colg = (bn << 7) + wn + ((lane & 7) << 3);
      *reinterpret_cast<uint4*>((__hip_bfloat16*)outp + (size_t)rowg * N + colg) = val;
    }
  } else {
    // ---- f32 epilogue (proj): residual + fused bn2 partial stats (non-atomic)
    float sc = scaleptr[0];
    float4 ts[4], tq[4];
    #pragma unroll
    for (int ni = 0; ni < 4; ++ni){ ts[ni] = {0.f,0.f,0.f,0.f}; tq[ni] = {0.f,0.f,0.f,0.f}; }
    #pragma unroll
    for (int ni = 0; ni < 4; ++ni){
      int col0 = (bn << 7) + wn + ni * 16 + (quad << 2);
      float4 bv = *reinterpret_cast<const float4*>(bias + col0);
      #pragma unroll
      for (int mi = 0; mi < 4; ++mi){
        int rowg = (bm << 7) + wm + mi * 16 + l16;
        size_t off = (size_t)rowg * N + col0;
        float v0 = acc[mi][ni][0] + bv.x;
        float v1 = acc[mi][ni][1] + bv.y;
        float v2 = acc[mi][ni][2] + bv.z;
        float v3 = acc[mi][ni][3] + bv.w;
        float4 xr = *reinterpret_cast<const float4*>((const float*)extra + off);
        float4 ov;
        ov.x = xr.x + v0 * sc; ov.y = xr.y + v1 * sc;
        ov.z = xr.z + v2 * sc; ov.w = xr.w + v3 * sc;
        *reinterpret_cast<float4*>((float*)outp + off) = ov;
        ts[ni].x += ov.x; ts[ni].y += ov.y; ts[ni].z += ov.z; ts[ni].w += ov.w;
        tq[ni].x += ov.x*ov.x; tq[ni].y += ov.y*ov.y;
        tq[ni].z += ov.z*ov.z; tq[ni].w += ov.w*ov.w;
      }
    }
    int prow = (bm << 1) + (wm >> 6);
    #pragma unroll
    for (int ni = 0; ni < 4; ++ni){
      float4 S = ts[ni], Q = tq[ni];
      #pragma unroll
      for (int m = 1; m < 16; m <<= 1){
        S.x += __shfl_xor(S.x, m); S.y += __shfl_xor(S.y, m);
        S.z += __shfl_xor(S.z, m); S.w += __shfl_xor(S.w, m);
        Q.x += __shfl_xor(Q.x, m); Q.y += __shfl_xor(Q.y, m);
        Q.z += __shfl_xor(Q.z, m); Q.w += __shfl_xor(Q.w, m);
      }
      if (l16 == 0){
        int col0 = (bn << 7) + wn + ni * 16 + (quad << 2);
        *reinterpret_cast<float4*>(pps + prow * 256 + col0) = S;
        *reinterpret_cast<float4*>(ppq + prow * 256 + col0) = Q;
      }
    }
  }
}

// ---------------- FUSED FFN: out = x2 + (gelu(s2@W1^T+b1)@W2^T+b2)*scale -------
// Counted-vmcnt schedule (T3/T4): GEMM1 uses a TRIPLE-buffered slab with 2-ahead
// prefetch; per k-step: vmcnt(3) -> s_barrier -> stage(k+2) -> ds_read cur ->
// 8 MFMA. Write-after-read is barrier-separated by construction (stage at iter k
// targets the buffer read at k-1; reads complete before barrier_k via the MFMA
// register dependence; the overwriting GLD issues after barrier_k).
// GEMM2 keeps drain-style dbuf (W2 slabs alias the GEMM1 slab region).
// LDS carve (shorts): slab3 [0,18432) stride 6144 {A 0..2047, W1 2048..6143};
// W2 dbuf at 0 and 8192 (each 8192); h [18432,26624) = 64x128 XOR-swizzled
// (col ^ ((row&7)<<3), both write and read sides). Total 53248 B.
__global__ __launch_bounds__(256) void ffn_fused_k(
    const __hip_bfloat16* __restrict__ A,   // s2 [32768,256]
    const __hip_bfloat16* __restrict__ W1,  // [1024,256] bf16
    const float* __restrict__ b1,
    const __hip_bfloat16* __restrict__ W2,  // [256,1024] bf16
    const float* __restrict__ b2,
    float* __restrict__ x2,                 // in/out [32768,256] f32
    const float* __restrict__ scaleptr)
{
  __shared__ __align__(16) short lds[26624];
  const int tid = threadIdx.x;
  const int bm = blockIdx.x;               // 512 blocks x 64 rows
  const int lane = tid & 63;
  const int l16 = lane & 15, quad = lane >> 4;
  const int wv = tid >> 6;                 // wave: N-split only

  const int srow = tid >> 2;               // 0..63
  const int sq   = (tid & 3) ^ ((srow >> 1) & 3);
  const __hip_bfloat16* Ag = A + (size_t)(bm * 64 + srow) * 256 + (sq << 3);

  // read offsets (shorts)
  int roA[4], hbase[4], hx[4], roW1[2], roW2[4];
  #pragma unroll
  for (int mi = 0; mi < 4; ++mi){
    int Ra = mi * 16 + l16;
    roA[mi]   = Ra * 32 + ((quad ^ ((Ra >> 1) & 3)) << 3);
    hbase[mi] = 18432 + Ra * 128;
    hx[mi]    = (Ra & 7) << 3;
  }
  #pragma unroll
  for (int ni = 0; ni < 2; ++ni){
    int Rw = wv * 32 + ni * 16 + l16;
    roW1[ni] = 2048 + Rw * 32 + ((quad ^ ((Rw >> 1) & 3)) << 3);
  }
  #pragma unroll
  for (int ni = 0; ni < 4; ++ni){
    int Rw = wv * 64 + ni * 16 + l16;
    roW2[ni] = Rw * 32 + ((quad ^ ((Rw >> 1) & 3)) << 3);
  }

  f32x4 zero = {0.f, 0.f, 0.f, 0.f};
  f32x4 acc2[4][4];
  #pragma unroll
  for (int i = 0; i < 4; ++i)
    #pragma unroll
    for (int j = 0; j < 4; ++j) acc2[i][j] = zero;

  for (int c1 = 0; c1 < 8; ++c1){
    f32x4 acc1[4][2];
    #pragma unroll
    for (int i = 0; i < 4; ++i){ acc1[i][0] = zero; acc1[i][1] = zero; }

    const __hip_bfloat16* W1g = W1 + (size_t)(c1 * 128 + srow) * 256 + (sq << 3);

    // stage one 64x32 A-chunk + 128x32 W1-chunk into slab buffer `off` (3 GLD)
    auto stage1 = [&](int off, int k0){
      GLD_LDS16(Ag + k0,              lds + off + tid * 8);
      GLD_LDS16(W1g + k0,             lds + off + 2048 + tid * 8);
      GLD_LDS16(W1g + 64 * 256 + k0,  lds + off + 4096 + tid * 8);
    };

    // ---- GEMM1: h_chunk[64x128], K=256, 8 k-steps, triple-buffer counted
    stage1(0, 0);
    stage1(6144, 32);
    #pragma unroll
    for (int k = 0; k < 8; ++k){
      if (k < 7) { VMCNT3; } else { VMCNT0; }   // batch for buf k%3 landed
      SBAR();                                    // ...in every wave
      const int cur = (k % 3) * 6144;
      if (k < 6) stage1(((k + 2) % 3) * 6144, (k + 2) * 32);
      short8 af[4];
      #pragma unroll
      for (int mi = 0; mi < 4; ++mi)
        af[mi] = *reinterpret_cast<const short8*>(lds + cur + roA[mi]);
      #pragma unroll
      for (int ni = 0; ni < 2; ++ni){
        short8 wf = *reinterpret_cast<const short8*>(lds + cur + roW1[ni]);
        #pragma unroll
        for (int mi = 0; mi < 4; ++mi)
          acc1[mi][ni] = __builtin_amdgcn_mfma_f32_16x16x32_bf16(wf, af[mi], acc1[mi][ni], 0, 0, 0);
      }
    }
    SBAR();   // all waves' k=7 reads complete -> slab reusable for W2

    // ---- W2 slab staging (256 rows x 32 k, 16KB, 4 GLD) -----------------------
    auto stageW2 = [&](int off, int kk){
      const __hip_bfloat16* p = W2 + (size_t)srow * 1024 + c1 * 128 + kk * 32 + (sq << 3);
      #pragma unroll
      for (int j = 0; j < 4; ++j)
        GLD_LDS16(p + (size_t)j * 64 * 1024, lds + off + tid * 8 + j * 2048);
    };
    stageW2(0, 0);   // prefetch W2 slice 0 under the gelu VALU work

    // ---- bias + gelu + pack h into XOR-swizzled LDS ---------------------------
    #pragma unroll
    for (int ni = 0; ni < 2; ++ni){
      int colg = c1 * 128 + wv * 32 + ni * 16 + (quad << 2);
      float4 bv = *reinterpret_cast<const float4*>(b1 + colg);
      #pragma unroll
      for (int mi = 0; mi < 4; ++mi){
        float g0 = gelu_fast(acc1[mi][ni][0] + bv.x);
        float g1 = gelu_fast(acc1[mi][ni][1] + bv.y);
        float g2 = gelu_fast(acc1[mi][ni][2] + bv.z);
        float g3 = gelu_fast(acc1[mi][ni][3] + bv.w);
        unsigned lo = (unsigned)f2bu(g0) | ((unsigned)f2bu(g1) << 16);
        unsigned hi = (unsigned)f2bu(g2) | ((unsigned)f2bu(g3) << 16);
        int row = mi * 16 + l16;
        int hc  = (wv * 32 + ni * 16 + (quad << 2)) ^ ((row & 7) << 3);
        *reinterpret_cast<uint2*>(lds + 18432 + row * 128 + hc) = make_uint2(lo, hi);
      }
    }
    __syncthreads();   // h visible + W2_0 staged (full drain; gelu covered latency)

    // ---- GEMM2 partial: acc2 += h[64x128] @ W2[:, c1 slice]^T, 4 k-steps dbuf
    #pragma unroll
    for (int kk = 0; kk < 4; ++kk){
      const int cur = (kk & 1) ? 8192 : 0;
      const int nxt = (kk & 1) ? 0 : 8192;
      if (kk < 3) stageW2(nxt, kk + 1);
      short8 af[4];
      #pragma unroll
      for (int mi = 0; mi < 4; ++mi){
        int ha = hbase[mi] + (((kk << 5) + (quad << 3)) ^ hx[mi]);
        af[mi] = *reinterpret_cast<const short8*>(lds + ha);
      }
      #pragma unroll
      for (int ni = 0; ni < 4; ++ni){
        short8 wf = *reinterpret_cast<const short8*>(lds + cur + roW2[ni]);
        #pragma unroll
        for (int mi = 0; mi < 4; ++mi)
          acc2[mi][ni] = __builtin_amdgcn_mfma_f32_16x16x32_bf16(wf, af[mi], acc2[mi][ni], 0, 0, 0);
      }
      __syncthreads();
    }
  }

  // ---- epilogue: out = x2 + (acc2 + b2)*scale, float4 (full-sector stores)
  float sc = scaleptr[0];
  #pragma unroll
  for (int ni = 0; ni < 4; ++ni){
    int col0 = wv * 64 + ni * 16 + (quad << 2);
    float4 bv = *reinterpret_cast<const float4*>(b2 + col0);
    #pragma unroll
    for (int mi = 0; mi < 4; ++mi){
      int rowg = bm * 64 + mi * 16 + l16;
      size_t off = (size_t)rowg * 256 + col0;
      float4 xr = *reinterpret_cast<const float4*>(x2 + off);
      float4 ov;
      ov.x = xr.x + (acc2[mi][ni][0] + bv.x) * sc;
      ov.y = xr.y + (acc2[mi][ni][1] + bv.y) * sc;
      ov.z = xr.z + (acc2[mi][ni][2] + bv.z) * sc;
      ov.w = xr.w + (acc2[mi][ni][3] + bv.w) * sc;
      *reinterpret_cast<float4*>(x2 + off) = ov;
    }
  }
}

// ---------------- top-k routing: aff = qm @ km^T per sample, pick top-4 --------
__global__ void topk_k(const float* __restrict__ qkm, int* __restrict__ idx){
  __shared__ float aff[64];
  int r = blockIdx.x;           // sample*64 + query region
  int m = threadIdx.x;          // candidate region 0..63
  int b = r >> 6;
  const float4* qrow = reinterpret_cast<const float4*>(qkm + (size_t)r * 512);
  const float4* krow = reinterpret_cast<const float4*>(qkm + (size_t)(b * 64 + m) * 512 + 256);
  float dot = 0.f;
  for (int d = 0; d < 64; ++d){
    float4 qv = qrow[d], kv = krow[d];
    dot += qv.x * kv.x + qv.y * kv.y + qv.z * kv.z + qv.w * kv.w;
  }
  aff[m] = dot;
  __syncthreads();
  if (m == 0){
    #pragma unroll
    for (int t = 0; t < 4; ++t){
      float best = -INFINITY; int bi = 0;
      for (int i = 0; i < 64; ++i){
        if (aff[i] > best){ best = aff[i]; bi = i; }   // strict >: lowest index on ties (jax top_k)
      }
      aff[bi] = -INFINITY;
      idx[r * 4 + t] = bi;
    }
  }
}

// ---------------- MFMA routed attention: block per (region, head) --------------
__global__ __launch_bounds__(256) void attn_mfma_k(
    const __hip_bfloat16* __restrict__ qkv, const int* __restrict__ idx,
    __hip_bfloat16* __restrict__ o_out, int rbase)
{
  __shared__ __align__(16) short lds[27136];
  const int rl = blockIdx.x;       // local region in this chunk
  const int h  = blockIdx.y;       // head
  const int rg = rbase + rl;       // global region (for idx)
  const int bl = rl >> 6;          // local sample
  const int tid = threadIdx.x;
  const int w = tid >> 6, lane = tid & 63;
  const int l16 = lane & 15, quad = lane >> 4;
  short* Pw = lds + 10240 + w * 4224;

  const int reg = idx[rg * 4 + (tid >> 6)] & 63;       // clamp: never OOB
  const size_t srow = (size_t)bl * SAMP_TOK + (size_t)reg * 64 + (tid & 63);
  const __hip_bfloat16* kvsrc = qkv + srow * 768 + 256 + (size_t)h * 32;

  const size_t qrow = (size_t)rl * 64 + w * 16 + l16;
  short8 qf = *reinterpret_cast<const short8*>(qkv + qrow * 768 + (size_t)h * 32 + quad * 8);

  uint4 vreg[4];
  #pragma unroll
  for (int c = 0; c < 4; ++c)
    vreg[c] = *reinterpret_cast<const uint4*>(kvsrc + 256 + c * 8);

  #pragma unroll
  for (int c = 0; c < 4; ++c)
    *reinterpret_cast<uint4*>(&lds[tid * 40 + c * 8]) =
      *reinterpret_cast<const uint4*>(kvsrc + c * 8);
  __syncthreads();

  f32x4 s[16];
  #pragma unroll
  for (int nt = 0; nt < 16; ++nt){
    short8 kf = *reinterpret_cast<const short8*>(&lds[(nt * 16 + l16) * 40 + quad * 8]);
    f32x4 z = {0.f, 0.f, 0.f, 0.f};
    s[nt] = __builtin_amdgcn_mfma_f32_16x16x32_bf16(kf, qf, z, 0, 0, 0);
  }
  __syncthreads();

  #pragma unroll
  for (int c = 0; c < 4; ++c){
    short8 vv = *reinterpret_cast<short8*>(&vreg[c]);
    #pragma unroll
    for (int e = 0; e < 8; ++e)
      lds[(c * 8 + e) * 264 + tid] = vv[e];
  }

  float mx = -1e30f;
  #pragma unroll
  for (int nt = 0; nt < 16; ++nt)
    #pragma unroll
    for (int r = 0; r < 4; ++r) mx = fmaxf(mx, s[nt][r]);
  mx = fmaxf(mx, __shfl_xor(mx, 16));
  mx = fmaxf(mx, __shfl_xor(mx, 32));
  float den = 0.f;
  #pragma unroll
  for (int nt = 0; nt < 16; ++nt)
    #pragma unroll
    for (int r = 0; r < 4; ++r){
      float e = __expf((s[nt][r] - mx) * 0.17677669529663687f);  // scale folded in
      s[nt][r] = e; den += e;
    }
  den += __shfl_xor(den, 16);
  den += __shfl_xor(den, 32);

  #pragma unroll
  for (int nt = 0; nt < 16; ++nt){
    unsigned lo = (unsigned)f2bu(s[nt][0]) | ((unsigned)f2bu(s[nt][1]) << 16);
    unsigned hi = (unsigned)f2bu(s[nt][2]) | ((unsigned)f2bu(s[nt][3]) << 16);
    *reinterpret_cast<uint2*>(&Pw[l16 * 264 + nt * 16 + quad * 4]) = make_uint2(lo, hi);
  }
  __syncthreads();

  f32x4 o0 = {0.f, 0.f, 0.f, 0.f}, o1 = o0;
  #pragma unroll
  for (int kk = 0; kk < 8; ++kk){
    short8 pb = *reinterpret_cast<const short8*>(&Pw[l16 * 264 + kk * 32 + quad * 8]);
    short8 a0 = *reinterpret_cast<const short8*>(&lds[l16 * 264 + kk * 32 + quad * 8]);
    short8 a1 = *reinterpret_cast<const short8*>(&lds[(16 + l16) * 264 + kk * 32 + quad * 8]);
    o0 = __builtin_amdgcn_mfma_f32_16x16x32_bf16(a0, pb, o0, 0, 0, 0);
    o1 = __builtin_amdgcn_mfma_f32_16x16x32_bf16(a1, pb, o1, 0, 0, 0);
  }
  float inv = 1.f / den;
  size_t obase = ((size_t)rl * 64 + w * 16 + l16) * 256 + (size_t)h * 32;
  unsigned pk0 = (unsigned)f2bu(o0[0] * inv) | ((unsigned)f2bu(o0[1] * inv) << 16);
  unsigned pk1 = (unsigned)f2bu(o0[2] * inv) | ((unsigned)f2bu(o0[3] * inv) << 16);
  unsigned pk2 = (unsigned)f2bu(o1[0] * inv) | ((unsigned)f2bu(o1[1] * inv) << 16);
  unsigned pk3 = (unsigned)f2bu(o1[2] * inv) | ((unsigned)f2bu(o1[3] * inv) << 16);
  *reinterpret_cast<uint2*>(o_out + obase + quad * 4)      = make_uint2(pk0, pk1);
  *reinterpret_cast<uint2*>(o_out + obase + 16 + quad * 4) = make_uint2(pk2, pk3);
}

// -------------------------------------------------------------------------------
// STRICT ws budget (never write beyond ws_size):
//   [0,4MB)   misc: BN sums/coeffs, idxb, smr, qkm, bf16 weights, bn2 partials
//   [4,20MB)  s1 (branch1) then s2 (branch2), bf16 16MB
//   [20MB,..) chunk buffers (branch1 only now), adaptively sized from ws_size.
// x2 (fp32 [32768,256], 32MB) lives in d_out; fused FFN updates d_out in place.
// Minimum ws_size supported: 28MB.
extern "C" void kernel_launch(void* const* d_in, const int* in_sizes, int n_in,
                              void* d_out, int out_size, void* d_ws, size_t ws_size,
                              hipStream_t stream)
{
  const float* x      = (const float*)d_in[0];
  const float* bn1_g  = (const float*)d_in[1];
  const float* bn1_b  = (const float*)d_in[2];
  const float* bn2_g  = (const float*)d_in[3];
  const float* bn2_b  = (const float*)d_in[4];
  const float* qkv_w  = (const float*)d_in[5];
  const float* qkv_b  = (const float*)d_in[6];
  const float* proj_w = (const float*)d_in[7];
  const float* proj_b = (const float*)d_in[8];
  const float* ffn_w1 = (const float*)d_in[9];
  const float* ffn_b1 = (const float*)d_in[10];
  const float* ffn_w2 = (const float*)d_in[11];
  const float* ffn_b2 = (const float*)d_in[12];
  const float* scale  = (const float*)d_in[13];
  float* x2 = (float*)d_out;       // residual lives in d_out

  char* ws = (char*)d_ws;
  const size_t MB = 1024 * 1024;
  float* sum1 = (float*)(ws + 0);
  float* sq1  = (float*)(ws + 1024);
  float* a1   = (float*)(ws + 4096);
  float* b1   = (float*)(ws + 5120);
  float* a2   = (float*)(ws + 6144);
  float* b2   = (float*)(ws + 7168);
  int*   idxb = (int*)(ws + 8192);                              // 8KB
  float* smr  = (float*)(ws + 16384);                           // 512KB
  float* qkm  = (float*)(ws + 540672);                          // 1MB
  __hip_bfloat16* qkv_wb  = (__hip_bfloat16*)(ws + 1589248);    // 384KB
  __hip_bfloat16* proj_wb = (__hip_bfloat16*)(ws + 1982464);    // 128KB
  __hip_bfloat16* ffn_w1b = (__hip_bfloat16*)(ws + 2113536);    // 512KB
  __hip_bfloat16* ffn_w2b = (__hip_bfloat16*)(ws + 2637824);    // 512KB, ends 3162112
  float* ppsum = (float*)(ws + 3162112);                        // 512KB (512x256 f32)
  float* ppsq  = (float*)(ws + 3686400);                        // 512KB, ends 4MB exactly
  __hip_bfloat16* s1 = (__hip_bfloat16*)(ws + 4 * MB);          // 16MB (s2 reuses)
  __hip_bfloat16* s2 = s1;
  char* chunkbuf = ws + 20 * MB;

  // adaptive chunk sizes from ws_size (constant across calls -> graph-safe)
  size_t avail = (ws_size > 20 * MB) ? (ws_size - 20 * MB) : (8 * MB);
  int nc = (avail >= 64 * MB) ? 8 : (avail >= 32 * MB) ? 4 : (avail >= 16 * MB) ? 2 : 1;   // samples/chunk (8MB each)

  __hip_bfloat16* qkvc = (__hip_bfloat16*)chunkbuf;                        // nc*6MB
  __hip_bfloat16* oc   = (__hip_bfloat16*)(chunkbuf + (size_t)nc * 6 * MB); // nc*2MB

  hipMemsetAsync(d_ws, 0, 4096, stream);   // zero BN1 accumulators

  // one-time weight conversions fp32 -> bf16 (single launch)
  f2ball_k<<<3072, 256, 0, stream>>>(qkv_w, proj_w, ffn_w1, ffn_w2,
                                     qkv_wb, proj_wb, ffn_w1b, ffn_w2b);

  // branch 1: BN -> LIF -> routing, then per-chunk qkv -> attn -> proj+residual
  bn_stats_k<<<256, 256, 0, stream>>>(x, sum1, sq1);
  bn_fin_k<<<1, 256, 0, stream>>>(sum1, sq1, bn1_g, bn1_b, a1, b1);
  lif_k<<<PERT / 1024, 256, 0, stream>>>(x, a1, b1, s1);
  region_sum_k<<<512, 256, 0, stream>>>(s1, smr);
  rgemm_k<<<512, 256, 0, stream>>>(smr, qkv_w, qkv_b, qkm);   // fp32 routing (flip-proof)
  topk_k<<<512, 64, 0, stream>>>(qkm, idxb);

  const int nchunkA = 8 / nc;
  for (int c = 0; c < nchunkA; ++c){
    const size_t ro = (size_t)c * nc * SAMP_TOK;            // row offset (tokens)
    gemm_bt<0><<<dim3(nc * SAMP_TOK / 128, 6), 256, 0, stream>>>(
        s1 + ro * 256, qkv_wb, qkv_b, qkvc, nullptr, nullptr, nullptr, nullptr, 256, 768);
    attn_mfma_k<<<dim3(nc * 64, 8), 256, 0, stream>>>(qkvc, idxb, oc, c * nc * 64);
    gemm_bt<1><<<dim3(nc * SAMP_TOK / 128, 2), 256, 0, stream>>>(
        oc, proj_wb, proj_b, x2 + ro * 256, x + ro * 256, scale,
        ppsum + (ro >> 6) * 256, ppsq + (ro >> 6) * 256, 256, 256);
  }

  // branch 2: bn2 partial-reduce (atomic-free) -> LIF -> fused FFN (in-place)
  bn_red_k<<<1, 256, 0, stream>>>(ppsum, ppsq, bn2_g, bn2_b, a2, b2);
  lif_k<<<PERT / 1024, 256, 0, stream>>>(x2, a2, b2, s2);
  ffn_fused_k<<<512, 256, 0, stream>>>(s2, ffn_w1b, ffn_b1, ffn_w2b, ffn_b2, x2, scale);
}

// Round 9
// 347.863 us; speedup vs baseline: 1.1924x; 1.0057x over previous
//
#include <hip/hip_runtime.h>
#include <hip/hip_bf16.h>
#include <math.h>

typedef __attribute__((ext_vector_type(8))) short short8;
typedef __attribute__((ext_vector_type(4))) float f32x4;

#define DIM 256
#define NROWS 32768      // T*B*Ltot rows
#define PERT 2097152     // B*Ltot*D elements per timestep
#define SAMP_TOK 4096    // tokens per (t,b) sample

__device__ __forceinline__ float b2f(__hip_bfloat16 h){ return __bfloat162float(h); }
__device__ __forceinline__ __hip_bfloat16 f2b(float f){ return __float2bfloat16(f); }
__device__ __forceinline__ unsigned short f2bu(float f){
  __hip_bfloat16 h = __float2bfloat16(f);
  unsigned short u; __builtin_memcpy(&u, &h, 2); return u;
}

// async global -> LDS, 16B per lane (wave-uniform base + lane*16 on LDS side)
#define GLD_LDS16(gp, lp) __builtin_amdgcn_global_load_lds( \
    (const __attribute__((address_space(1))) unsigned int*)(gp), \
    (__attribute__((address_space(3))) unsigned int*)(lp), 16, 0, 0)

// branchless erf-based exact gelu (A&S 7.1.26, |err| <= ~3e-7: below bf16 ulp)
__device__ __forceinline__ float gelu_fast(float v){
  float z  = v * 0.70710678118654752f;
  float az = fabsf(z);
  float t  = __builtin_amdgcn_rcpf(fmaf(0.3275911f, az, 1.0f));
  float p  = fmaf(fmaf(fmaf(fmaf(1.061405429f, t, -1.453152027f), t,
                            1.421413741f), t, -0.284496736f), t, 0.254829592f);
  p *= t;
  float e  = __expf(-z * z);
  float y  = fmaf(-p, e, 1.0f);                 // erf(|z|)
  return fmaf(0.5f * fabsf(v), y, 0.5f * v);    // 0.5*v*(1+sign(v)*erf(|z|))
}

// ---------------- fp32 -> bf16 weight conversion (all 4 weights, one launch) ---
__global__ void f2ball_k(const float* __restrict__ w_qkv, const float* __restrict__ w_proj,
                         const float* __restrict__ w_f1, const float* __restrict__ w_f2,
                         __hip_bfloat16* __restrict__ o_qkv, __hip_bfloat16* __restrict__ o_proj,
                         __hip_bfloat16* __restrict__ o_f1, __hip_bfloat16* __restrict__ o_f2){
  int i = blockIdx.x * 256 + threadIdx.x;        // 0 .. 786431
  if (i < 196608)          o_qkv[i]           = f2b(w_qkv[i]);
  else if (i < 262144)     o_proj[i - 196608] = f2b(w_proj[i - 196608]);
  else if (i < 524288)     o_f1[i - 262144]   = f2b(w_f1[i - 262144]);
  else                     o_f2[i - 524288]   = f2b(w_f2[i - 524288]);
}

// ---------------- BN stats (branch 1): per-channel sum / sumsq -----------------
__global__ void bn_stats_k(const float* __restrict__ x, float* __restrict__ sum, float* __restrict__ sumsq){
  __shared__ __align__(16) float rs[4][256];
  __shared__ __align__(16) float rq[4][256];
  int t = threadIdx.x;
  int g = t & 63, r = t >> 6;
  size_t base = ((size_t)blockIdx.x * 128 + r) * DIM + g * 4;   // 128 rows per block
  float4 s = {0.f,0.f,0.f,0.f}, q = {0.f,0.f,0.f,0.f};
  for (int i = 0; i < 32; ++i){
    float4 v = *reinterpret_cast<const float4*>(x + base + (size_t)i * 4 * DIM);
    s.x += v.x; s.y += v.y; s.z += v.z; s.w += v.w;
    q.x += v.x*v.x; q.y += v.y*v.y; q.z += v.z*v.z; q.w += v.w*v.w;
  }
  *reinterpret_cast<float4*>(&rs[r][g*4]) = s;
  *reinterpret_cast<float4*>(&rq[r][g*4]) = q;
  __syncthreads();
  int c = t;   // one channel per thread
  atomicAdd(&sum[c],   rs[0][c] + rs[1][c] + rs[2][c] + rs[3][c]);
  atomicAdd(&sumsq[c], rq[0][c] + rq[1][c] + rq[2][c] + rq[3][c]);
}

__global__ void bn_fin_k(const float* __restrict__ sum, const float* __restrict__ sumsq,
                         const float* __restrict__ g, const float* __restrict__ b,
                         float* __restrict__ a_out, float* __restrict__ b_out){
  int c = threadIdx.x;
  float mean = sum[c] * (1.f/32768.f);
  float var  = sumsq[c] * (1.f/32768.f) - mean*mean;
  float a = g[c] / sqrtf(var + 1e-5f);
  a_out[c] = a;
  b_out[c] = b[c] - mean * a;
}

// ---------------- BN2 reduce: column-sum the 512x256 partial grids -------------
__global__ void bn_red_k(const float* __restrict__ pps, const float* __restrict__ ppq,
                         const float* __restrict__ g, const float* __restrict__ b,
                         float* __restrict__ a_out, float* __restrict__ b_out){
  int c = threadIdx.x;
  float s = 0.f, q = 0.f;
  for (int r = 0; r < 512; ++r){
    s += pps[r * 256 + c];
    q += ppq[r * 256 + c];
  }
  float mean = s * (1.f/32768.f);
  float var  = q * (1.f/32768.f) - mean*mean;
  float a = g[c] / sqrtf(var + 1e-5f);
  a_out[c] = a;
  b_out[c] = b[c] - mean * a;
}

// ---------------- LIF over T=4 (binary spike out, bf16 exact) ------------------
__global__ void lif_k(const float* __restrict__ x, const float* __restrict__ av,
                      const float* __restrict__ bv, __hip_bfloat16* __restrict__ s){
  int i = blockIdx.x * 256 + threadIdx.x;       // 0 .. PERT/4-1 (exact grid)
  int e4 = i * 4;
  int c4 = e4 & (DIM - 1);
  float4 a = *reinterpret_cast<const float4*>(av + c4);
  float4 b = *reinterpret_cast<const float4*>(bv + c4);
  float4 v = {0.f,0.f,0.f,0.f};
  #pragma unroll
  for (int t = 0; t < 4; ++t){
    float4 xn = *reinterpret_cast<const float4*>(x + (size_t)t * PERT + e4);
    xn.x = fmaf(xn.x, a.x, b.x); xn.y = fmaf(xn.y, a.y, b.y);
    xn.z = fmaf(xn.z, a.z, b.z); xn.w = fmaf(xn.w, a.w, b.w);
    v.x += (xn.x - v.x) * 0.5f; v.y += (xn.y - v.y) * 0.5f;
    v.z += (xn.z - v.z) * 0.5f; v.w += (xn.w - v.w) * 0.5f;
    ushort4 sp;
    sp.x = (v.x >= 1.0f) ? 0x3F80 : 0;  v.x = (v.x >= 1.0f) ? 0.f : v.x;
    sp.y = (v.y >= 1.0f) ? 0x3F80 : 0;  v.y = (v.y >= 1.0f) ? 0.f : v.y;
    sp.z = (v.z >= 1.0f) ? 0x3F80 : 0;  v.z = (v.z >= 1.0f) ? 0.f : v.z;
    sp.w = (v.w >= 1.0f) ? 0x3F80 : 0;  v.w = (v.w >= 1.0f) ? 0.f : v.w;
    *reinterpret_cast<ushort4*>(reinterpret_cast<unsigned short*>(s) + (size_t)t * PERT + e4) = sp;
  }
}

// ---------------- region means of binary s1 (exact fp32) -----------------------
__global__ void region_sum_k(const __hip_bfloat16* __restrict__ s, float* __restrict__ sm){
  __shared__ __align__(16) float red[4][256];
  int r = blockIdx.x, t = threadIdx.x;    // r = (sample*64 + region), 512 total
  int g = t & 63, sub = t >> 6;
  const unsigned short* sp = reinterpret_cast<const unsigned short*>(s);
  size_t base = ((size_t)r * 64 + sub * 16) * DIM + g * 4;
  float4 acc = {0.f,0.f,0.f,0.f};
  for (int i = 0; i < 16; ++i){
    ushort4 u = *reinterpret_cast<const ushort4*>(sp + base + (size_t)i * DIM);
    acc.x += (u.x != 0) ? 1.f : 0.f; acc.y += (u.y != 0) ? 1.f : 0.f;
    acc.z += (u.z != 0) ? 1.f : 0.f; acc.w += (u.w != 0) ? 1.f : 0.f;
  }
  *reinterpret_cast<float4*>(&red[sub][g*4]) = acc;
  __syncthreads();
  if (sub == 0){
    float4 o;
    o.x = (red[0][g*4+0] + red[1][g*4+0] + red[2][g*4+0] + red[3][g*4+0]) * 0.015625f;
    o.y = (red[0][g*4+1] + red[1][g*4+1] + red[2][g*4+1] + red[3][g*4+1]) * 0.015625f;
    o.z = (red[0][g*4+2] + red[1][g*4+2] + red[2][g*4+2] + red[3][g*4+2]) * 0.015625f;
    o.w = (red[0][g*4+3] + red[1][g*4+3] + red[2][g*4+3] + red[3][g*4+3]) * 0.015625f;
    *reinterpret_cast<float4*>(sm + (size_t)r * DIM + g * 4) = o;
  }
}

// ---------------- routing GEMM fp32: qkm[r][j] = smr[r]·qkv_w[j] + b[j], j<512 -
__global__ void rgemm_k(const float* __restrict__ smr, const float* __restrict__ w,
                        const float* __restrict__ bias, float* __restrict__ qkm){
  __shared__ float arow[256];
  int r = blockIdx.x, t = threadIdx.x;
  arow[t] = smr[(size_t)r * 256 + t];
  __syncthreads();
  for (int j = t; j < 512; j += 256){
    const float* wr = w + (size_t)j * 256;
    float acc = 0.f;
    for (int k = 0; k < 256; ++k) acc += arow[k] * wr[k];
    qkm[(size_t)r * 512 + j] = acc + bias[j];
  }
}

// ---------------- GEMM: C[M,N] = A[M,K] @ W[N,K]^T (+bias, epilogue) -----------
// (branch 1 only: EPI 0 = qkv bf16 out, EPI 1 = proj f32 + residual + bn2
//  partial stats, non-atomic)
template<int EPI>
__global__ __launch_bounds__(256) void gemm_bt(
    const __hip_bfloat16* __restrict__ A, const __hip_bfloat16* __restrict__ W,
    const float* __restrict__ bias, void* __restrict__ outp,
    const void* __restrict__ extra, const float* __restrict__ scaleptr,
    float* __restrict__ pps, float* __restrict__ ppq,
    int K, int N)
{
  __shared__ __align__(16) short As0[128 * 32];   // 8KB each, linear layout
  __shared__ __align__(16) short Ws0[128 * 32];
  __shared__ __align__(16) short As1[128 * 32];
  __shared__ __align__(16) short Ws1[128 * 32];
  int tid = threadIdx.x;
  int bm = blockIdx.x, bn = blockIdx.y;
  int lane = tid & 63;
  int l16 = lane & 15, quad = lane >> 4;
  int wv = tid >> 6;
  int wm = (wv >> 1) << 6, wn = (wv & 1) << 6;

  const int srow = tid >> 2;
  const int sq   = (tid & 3) ^ ((srow >> 1) & 3);
  const __hip_bfloat16* Ag = A + (size_t)(bm * 128 + srow) * K + (sq << 3);
  const __hip_bfloat16* Wg = W + (size_t)(bn * 128 + srow) * K + (sq << 3);
  const size_t rstep = (size_t)64 * K;

  int roA[4], roW[4];
  #pragma unroll
  for (int i = 0; i < 4; ++i){
    int Ra = wm + i * 16 + l16;
    roA[i] = Ra * 32 + ((quad ^ ((Ra >> 1) & 3)) << 3);
    int Rw = wn + i * 16 + l16;
    roW[i] = Rw * 32 + ((quad ^ ((Rw >> 1) & 3)) << 3);
  }

  f32x4 zero = {0.f, 0.f, 0.f, 0.f};
  f32x4 acc[4][4];
  #pragma unroll
  for (int i = 0; i < 4; ++i)
    #pragma unroll
    for (int j = 0; j < 4; ++j) acc[i][j] = zero;

  auto stage = [&](short* Ad, short* Wd, int k0){
    GLD_LDS16(Ag + k0,         Ad + tid * 8);
    GLD_LDS16(Ag + rstep + k0, Ad + tid * 8 + 2048);
    GLD_LDS16(Wg + k0,         Wd + tid * 8);
    GLD_LDS16(Wg + rstep + k0, Wd + tid * 8 + 2048);
  };
  auto compute = [&](const short* Asb, const short* Wsb){
    short8 af[4];
    #pragma unroll
    for (int mi = 0; mi < 4; ++mi)
      af[mi] = *reinterpret_cast<const short8*>(Asb + roA[mi]);
    #pragma unroll
    for (int ni = 0; ni < 4; ++ni){
      short8 wf = *reinterpret_cast<const short8*>(Wsb + roW[ni]);
      #pragma unroll
      for (int mi = 0; mi < 4; ++mi)
        acc[mi][ni] = __builtin_amdgcn_mfma_f32_16x16x32_bf16(wf, af[mi], acc[mi][ni], 0, 0, 0);
    }
  };

  stage(As0, Ws0, 0);
  __syncthreads();
  for (int k0 = 0; k0 < K; k0 += 64){
    if (k0 + 32 < K) stage(As1, Ws1, k0 + 32);
    compute(As0, Ws0);
    __syncthreads();
    if (k0 + 64 < K) stage(As0, Ws0, k0 + 64);
    if (k0 + 32 < K) compute(As1, Ws1);
    __syncthreads();
  }

  if (EPI == 0){
    // ---- coalesced bf16 epilogue: wave-private 64x64 C-tile via dead staging LDS
    short* Cw = (wv == 0) ? As0 : (wv == 1) ? Ws0 : (wv == 2) ? As1 : Ws1;
    #pragma unroll
    for (int ni = 0; ni < 4; ++ni){
      int col0 = (bn << 7) + wn + ni * 16 + (quad << 2);
      float4 bv = *reinterpret_cast<const float4*>(bias + col0);
      #pragma unroll
      for (int mi = 0; mi < 4; ++mi){
        float v0 = acc[mi][ni][0] + bv.x;
        float v1 = acc[mi][ni][1] + bv.y;
        float v2 = acc[mi][ni][2] + bv.z;
        float v3 = acc[mi][ni][3] + bv.w;
        unsigned lo = (unsigned)f2bu(v0) | ((unsigned)f2bu(v1) << 16);
        unsigned hi = (unsigned)f2bu(v2) | ((unsigned)f2bu(v3) << 16);
        int row = mi * 16 + l16;
        int cb  = (ni * 32 + (quad << 3)) ^ ((row & 7) << 4);
        *reinterpret_cast<uint2*>(reinterpret_cast<char*>(Cw) + row * 128 + cb) =
            make_uint2(lo, hi);
      }
    }
    asm volatile("s_waitcnt lgkmcnt(0)" ::: "memory");
    #pragma unroll
    for (int p = 0; p < 8; ++p){
      int row = p * 8 + (lane >> 3);
      int cb  = ((lane & 7) << 4) ^ ((row & 7) << 4);
      uint4 val = *reinterpret_cast<const uint4*>(
          reinterpret_cast<const char*>(Cw) + row * 128 + cb);
      int rowg = (bm << 7) + wm + row;
      int colg = (bn << 7) + wn + ((lane & 7) << 3);
      *reinterpret_cast<uint4*>((__hip_bfloat16*)outp + (size_t)rowg * N + colg) = val;
    }
  } else {
    // ---- f32 epilogue (proj): residual + fused bn2 partial stats (non-atomic)
    float sc = scaleptr[0];
    float4 ts[4], tq[4];
    #pragma unroll
    for (int ni = 0; ni < 4; ++ni){ ts[ni] = {0.f,0.f,0.f,0.f}; tq[ni] = {0.f,0.f,0.f,0.f}; }
    #pragma unroll
    for (int ni = 0; ni < 4; ++ni){
      int col0 = (bn << 7) + wn + ni * 16 + (quad << 2);
      float4 bv = *reinterpret_cast<const float4*>(bias + col0);
      #pragma unroll
      for (int mi = 0; mi < 4; ++mi){
        int rowg = (bm << 7) + wm + mi * 16 + l16;
        size_t off = (size_t)rowg * N + col0;
        float v0 = acc[mi][ni][0] + bv.x;
        float v1 = acc[mi][ni][1] + bv.y;
        float v2 = acc[mi][ni][2] + bv.z;
        float v3 = acc[mi][ni][3] + bv.w;
        float4 xr = *reinterpret_cast<const float4*>((const float*)extra + off);
        float4 ov;
        ov.x = xr.x + v0 * sc; ov.y = xr.y + v1 * sc;
        ov.z = xr.z + v2 * sc; ov.w = xr.w + v3 * sc;
        *reinterpret_cast<float4*>((float*)outp + off) = ov;
        ts[ni].x += ov.x; ts[ni].y += ov.y; ts[ni].z += ov.z; ts[ni].w += ov.w;
        tq[ni].x += ov.x*ov.x; tq[ni].y += ov.y*ov.y;
        tq[ni].z += ov.z*ov.z; tq[ni].w += ov.w*ov.w;
      }
    }
    int prow = (bm << 1) + (wm >> 6);
    #pragma unroll
    for (int ni = 0; ni < 4; ++ni){
      float4 S = ts[ni], Q = tq[ni];
      #pragma unroll
      for (int m = 1; m < 16; m <<= 1){
        S.x += __shfl_xor(S.x, m); S.y += __shfl_xor(S.y, m);
        S.z += __shfl_xor(S.z, m); S.w += __shfl_xor(S.w, m);
        Q.x += __shfl_xor(Q.x, m); Q.y += __shfl_xor(Q.y, m);
        Q.z += __shfl_xor(Q.z, m); Q.w += __shfl_xor(Q.w, m);
      }
      if (l16 == 0){
        int col0 = (bn << 7) + wn + ni * 16 + (quad << 2);
        *reinterpret_cast<float4*>(pps + prow * 256 + col0) = S;
        *reinterpret_cast<float4*>(ppq + prow * 256 + col0) = Q;
      }
    }
  }
}

// ---------------- FUSED FFN: out = x2 + (gelu(s2@W1^T+b1)@W2^T+b2)*scale -------
// 512 threads / 8 waves per 64-row block (16 waves/CU at 2 blocks/CU: the R8
// version had only 8 waves/CU -> latency-bound at MfmaUtil 16%).
// GEMM1 (per c1 chunk of 128 h-cols): K-step 64, dbuf 24KB slabs, 3 GLD/thread.
// GEMM2: W2 slices dbuf in the same slab regions; h[64][128] lives at LDS 0.
// Swizzles (involutions, matched source<->read per rule #21):
//   A/W1: slot t of row r holds global col-block t^(r&7); read col
//         ((kh<<5)|(quad<<3)) ^ ((row&7)<<3).
//   h:    phys col = logical ^ ((row&15)<<3) on both ds_write and ds_read
//         (read: 16 distinct 16B slots per 16-lane group -> conflict-free).
//   W2:   slot t of row r holds block t^(r&3); read (quad^(Rw&3))<<3.
// LDS (shorts): h [0,8192) | slab0 [8192,20480) {A 4096, W1 8192} | slab1
// [20480,32768). Total exactly 65536 B.
__global__ __launch_bounds__(512, 4) void ffn_fused_k(
    const __hip_bfloat16* __restrict__ A,   // s2 [32768,256]
    const __hip_bfloat16* __restrict__ W1,  // [1024,256] bf16
    const float* __restrict__ b1,
    const __hip_bfloat16* __restrict__ W2,  // [256,1024] bf16
    const float* __restrict__ b2,
    float* __restrict__ x2,                 // in/out [32768,256] f32
    const float* __restrict__ scaleptr)
{
  __shared__ __align__(16) short lds[32768];   // 64KB exactly
  const int tid = threadIdx.x;                 // 0..511
  const int bm = blockIdx.x;                   // 512 blocks x 64 rows
  const int lane = tid & 63;
  const int l16 = lane & 15, quad = lane >> 4;
  const int wv = tid >> 6;                     // wave 0..7

  const int H = 0, S0 = 8192, S1 = 20480;      // short offsets

  // ---- staging source addresses (pre-swizzled col-blocks) ----
  const int ar = tid >> 3, as = tid & 7;                    // A/W1 granule: row, slot
  const int asq = (as ^ (ar & 7)) << 3;
  const __hip_bfloat16* Ag = A + (size_t)(bm * 64 + ar) * 256 + asq;   // rows 0..63
  const int w2r = tid >> 2, w2s = tid & 3;                  // W2 granule: row, slot
  const int w2q = (w2s ^ (w2r & 3)) << 3;

  // ---- read offsets (shorts, slab-relative / h-relative) ----
  int roA[4][2];                        // A: [mi][kh]
  #pragma unroll
  for (int mi = 0; mi < 4; ++mi){
    int Ra = mi * 16 + l16;
    #pragma unroll
    for (int kh = 0; kh < 2; ++kh)
      roA[mi][kh] = Ra * 64 + ((((kh << 5) | (quad << 3)) ^ ((Ra & 7) << 3)));
  }
  int roW1[2];
  {
    int Rw = wv * 16 + l16;
    #pragma unroll
    for (int kh = 0; kh < 2; ++kh)
      roW1[kh] = 4096 + Rw * 64 + ((((kh << 5) | (quad << 3)) ^ ((Rw & 7) << 3)));
  }
  int hwr[4], hrb[4];                   // h write / read bases per mi
  const int hxor = l16 << 3;            // (row&15)<<3 with row = mi*16+l16
  #pragma unroll
  for (int mi = 0; mi < 4; ++mi){
    int row = mi * 16 + l16;
    hwr[mi] = row * 128 + (((wv * 16 + quad * 4)) ^ hxor);
    hrb[mi] = row * 128;
  }
  int roW2[2];
  #pragma unroll
  for (int ni = 0; ni < 2; ++ni){
    int Rw = wv * 32 + ni * 16 + l16;
    roW2[ni] = Rw * 32 + (((quad ^ (Rw & 3))) << 3);
  }

  f32x4 zero = {0.f, 0.f, 0.f, 0.f};
  f32x4 acc2[4][2];
  #pragma unroll
  for (int i = 0; i < 4; ++i){ acc2[i][0] = zero; acc2[i][1] = zero; }

  float sc = scaleptr[0];

  for (int c1 = 0; c1 < 8; ++c1){
    f32x4 acc1[4];
    #pragma unroll
    for (int i = 0; i < 4; ++i) acc1[i] = zero;

    const __hip_bfloat16* W1g = W1 + (size_t)(c1 * 128 + ar) * 256 + asq;

    // stage one K-step: A[64x64] (4KB sh) + W1[128x64] (8KB sh) = 3 GLD/thread
    auto stage1 = [&](int S, int k0){
      GLD_LDS16(Ag + k0,              lds + S + tid * 8);
      GLD_LDS16(W1g + k0,             lds + S + 4096 + tid * 8);
      GLD_LDS16(W1g + 64 * 256 + k0,  lds + S + 8192 + tid * 8);
    };
    auto compute1 = [&](int S){
      #pragma unroll
      for (int kh = 0; kh < 2; ++kh){
        short8 wf = *reinterpret_cast<const short8*>(lds + S + roW1[kh]);
        #pragma unroll
        for (int mi = 0; mi < 4; ++mi){
          short8 af = *reinterpret_cast<const short8*>(lds + S + roA[mi][kh]);
          acc1[mi] = __builtin_amdgcn_mfma_f32_16x16x32_bf16(wf, af, acc1[mi], 0, 0, 0);
        }
      }
    };

    // ---- GEMM1: 4 K-steps of 64, double-buffered ----
    stage1(S0, 0);
    __syncthreads();
    #pragma unroll
    for (int k = 0; k < 4; ++k){
      const int cur = (k & 1) ? S1 : S0;
      const int nxt = (k & 1) ? S0 : S1;
      if (k < 3) stage1(nxt, (k + 1) * 64);
      compute1(cur);
      __syncthreads();
    }

    // ---- W2 slice staging: [256 rows N][32 k] = 16KB, 2 GLD/thread ----
    auto stageW2 = [&](int S, int kk){
      const __hip_bfloat16* p = W2 + (size_t)w2r * 1024 + c1 * 128 + kk * 32 + w2q;
      GLD_LDS16(p,               lds + S + tid * 8);
      GLD_LDS16(p + 128 * 1024,  lds + S + 4096 + tid * 8);
    };
    stageW2(S0, 0);   // prefetch under gelu VALU work

    // ---- bias + gelu + pack h (swizzled) ----
    {
      int colg = c1 * 128 + wv * 16 + quad * 4;
      float4 bv = *reinterpret_cast<const float4*>(b1 + colg);
      #pragma unroll
      for (int mi = 0; mi < 4; ++mi){
        float g0 = gelu_fast(acc1[mi][0] + bv.x);
        float g1 = gelu_fast(acc1[mi][1] + bv.y);
        float g2 = gelu_fast(acc1[mi][2] + bv.z);
        float g3 = gelu_fast(acc1[mi][3] + bv.w);
        unsigned lo = (unsigned)f2bu(g0) | ((unsigned)f2bu(g1) << 16);
        unsigned hi = (unsigned)f2bu(g2) | ((unsigned)f2bu(g3) << 16);
        *reinterpret_cast<uint2*>(lds + H + hwr[mi]) = make_uint2(lo, hi);
      }
    }
    __syncthreads();   // h visible + W2_0 landed

    // ---- GEMM2 partial: acc2 += h[64x128] @ W2[:, c1]^T, 4 k-steps dbuf ----
    #pragma unroll
    for (int kk = 0; kk < 4; ++kk){
      const int cur = (kk & 1) ? S1 : S0;
      const int nxt = (kk & 1) ? S0 : S1;
      if (kk < 3) stageW2(nxt, kk + 1);
      short8 af[4];
      #pragma unroll
      for (int mi = 0; mi < 4; ++mi){
        int hc = (((kk << 5) | (quad << 3)) ^ hxor);
        af[mi] = *reinterpret_cast<const short8*>(lds + H + hrb[mi] + hc);
      }
      #pragma unroll
      for (int ni = 0; ni < 2; ++ni){
        short8 wf = *reinterpret_cast<const short8*>(lds + cur + roW2[ni]);
        #pragma unroll
        for (int mi = 0; mi < 4; ++mi)
          acc2[mi][ni] = __builtin_amdgcn_mfma_f32_16x16x32_bf16(wf, af[mi], acc2[mi][ni], 0, 0, 0);
      }
      __syncthreads();
    }
  }

  // ---- epilogue: out = x2 + (acc2 + b2)*scale, float4 (full-sector stores)
  #pragma unroll
  for (int ni = 0; ni < 2; ++ni){
    int col0 = wv * 32 + ni * 16 + (quad << 2);
    float4 bv = *reinterpret_cast<const float4*>(b2 + col0);
    #pragma unroll
    for (int mi = 0; mi < 4; ++mi){
      int rowg = bm * 64 + mi * 16 + l16;
      size_t off = (size_t)rowg * 256 + col0;
      float4 xr = *reinterpret_cast<const float4*>(x2 + off);
      float4 ov;
      ov.x = xr.x + (acc2[mi][ni][0] + bv.x) * sc;
      ov.y = xr.y + (acc2[mi][ni][1] + bv.y) * sc;
      ov.z = xr.z + (acc2[mi][ni][2] + bv.z) * sc;
      ov.w = xr.w + (acc2[mi][ni][3] + bv.w) * sc;
      *reinterpret_cast<float4*>(x2 + off) = ov;
    }
  }
}

// ---------------- top-k routing: aff = qm @ km^T per sample, pick top-4 --------
__global__ void topk_k(const float* __restrict__ qkm, int* __restrict__ idx){
  __shared__ float aff[64];
  int r = blockIdx.x;           // sample*64 + query region
  int m = threadIdx.x;          // candidate region 0..63
  int b = r >> 6;
  const float4* qrow = reinterpret_cast<const float4*>(qkm + (size_t)r * 512);
  const float4* krow = reinterpret_cast<const float4*>(qkm + (size_t)(b * 64 + m) * 512 + 256);
  float dot = 0.f;
  for (int d = 0; d < 64; ++d){
    float4 qv = qrow[d], kv = krow[d];
    dot += qv.x * kv.x + qv.y * kv.y + qv.z * kv.z + qv.w * kv.w;
  }
  aff[m] = dot;
  __syncthreads();
  if (m == 0){
    #pragma unroll
    for (int t = 0; t < 4; ++t){
      float best = -INFINITY; int bi = 0;
      for (int i = 0; i < 64; ++i){
        if (aff[i] > best){ best = aff[i]; bi = i; }   // strict >: lowest index on ties (jax top_k)
      }
      aff[bi] = -INFINITY;
      idx[r * 4 + t] = bi;
    }
  }
}

// ---------------- MFMA routed attention: block per (region, head) --------------
__global__ __launch_bounds__(256) void attn_mfma_k(
    const __hip_bfloat16* __restrict__ qkv, const int* __restrict__ idx,
    __hip_bfloat16* __restrict__ o_out, int rbase)
{
  __shared__ __align__(16) short lds[27136];
  const int rl = blockIdx.x;       // local region in this chunk
  const int h  = blockIdx.y;       // head
  const int rg = rbase + rl;       // global region (for idx)
  const int bl = rl >> 6;          // local sample
  const int tid = threadIdx.x;
  const int w = tid >> 6, lane = tid & 63;
  const int l16 = lane & 15, quad = lane >> 4;
  short* Pw = lds + 10240 + w * 4224;

  const int reg = idx[rg * 4 + (tid >> 6)] & 63;       // clamp: never OOB
  const size_t srow = (size_t)bl * SAMP_TOK + (size_t)reg * 64 + (tid & 63);
  const __hip_bfloat16* kvsrc = qkv + srow * 768 + 256 + (size_t)h * 32;

  const size_t qrow = (size_t)rl * 64 + w * 16 + l16;
  short8 qf = *reinterpret_cast<const short8*>(qkv + qrow * 768 + (size_t)h * 32 + quad * 8);

  uint4 vreg[4];
  #pragma unroll
  for (int c = 0; c < 4; ++c)
    vreg[c] = *reinterpret_cast<const uint4*>(kvsrc + 256 + c * 8);

  #pragma unroll
  for (int c = 0; c < 4; ++c)
    *reinterpret_cast<uint4*>(&lds[tid * 40 + c * 8]) =
      *reinterpret_cast<const uint4*>(kvsrc + c * 8);
  __syncthreads();

  f32x4 s[16];
  #pragma unroll
  for (int nt = 0; nt < 16; ++nt){
    short8 kf = *reinterpret_cast<const short8*>(&lds[(nt * 16 + l16) * 40 + quad * 8]);
    f32x4 z = {0.f, 0.f, 0.f, 0.f};
    s[nt] = __builtin_amdgcn_mfma_f32_16x16x32_bf16(kf, qf, z, 0, 0, 0);
  }
  __syncthreads();

  #pragma unroll
  for (int c = 0; c < 4; ++c){
    short8 vv = *reinterpret_cast<short8*>(&vreg[c]);
    #pragma unroll
    for (int e = 0; e < 8; ++e)
      lds[(c * 8 + e) * 264 + tid] = vv[e];
  }

  float mx = -1e30f;
  #pragma unroll
  for (int nt = 0; nt < 16; ++nt)
    #pragma unroll
    for (int r = 0; r < 4; ++r) mx = fmaxf(mx, s[nt][r]);
  mx = fmaxf(mx, __shfl_xor(mx, 16));
  mx = fmaxf(mx, __shfl_xor(mx, 32));
  float den = 0.f;
  #pragma unroll
  for (int nt = 0; nt < 16; ++nt)
    #pragma unroll
    for (int r = 0; r < 4; ++r){
      float e = __expf((s[nt][r] - mx) * 0.17677669529663687f);  // scale folded in
      s[nt][r] = e; den += e;
    }
  den += __shfl_xor(den, 16);
  den += __shfl_xor(den, 32);

  #pragma unroll
  for (int nt = 0; nt < 16; ++nt){
    unsigned lo = (unsigned)f2bu(s[nt][0]) | ((unsigned)f2bu(s[nt][1]) << 16);
    unsigned hi = (unsigned)f2bu(s[nt][2]) | ((unsigned)f2bu(s[nt][3]) << 16);
    *reinterpret_cast<uint2*>(&Pw[l16 * 264 + nt * 16 + quad * 4]) = make_uint2(lo, hi);
  }
  __syncthreads();

  f32x4 o0 = {0.f, 0.f, 0.f, 0.f}, o1 = o0;
  #pragma unroll
  for (int kk = 0; kk < 8; ++kk){
    short8 pb = *reinterpret_cast<const short8*>(&Pw[l16 * 264 + kk * 32 + quad * 8]);
    short8 a0 = *reinterpret_cast<const short8*>(&lds[l16 * 264 + kk * 32 + quad * 8]);
    short8 a1 = *reinterpret_cast<const short8*>(&lds[(16 + l16) * 264 + kk * 32 + quad * 8]);
    o0 = __builtin_amdgcn_mfma_f32_16x16x32_bf16(a0, pb, o0, 0, 0, 0);
    o1 = __builtin_amdgcn_mfma_f32_16x16x32_bf16(a1, pb, o1, 0, 0, 0);
  }
  float inv = 1.f / den;
  size_t obase = ((size_t)rl * 64 + w * 16 + l16) * 256 + (size_t)h * 32;
  unsigned pk0 = (unsigned)f2bu(o0[0] * inv) | ((unsigned)f2bu(o0[1] * inv) << 16);
  unsigned pk1 = (unsigned)f2bu(o0[2] * inv) | ((unsigned)f2bu(o0[3] * inv) << 16);
  unsigned pk2 = (unsigned)f2bu(o1[0] * inv) | ((unsigned)f2bu(o1[1] * inv) << 16);
  unsigned pk3 = (unsigned)f2bu(o1[2] * inv) | ((unsigned)f2bu(o1[3] * inv) << 16);
  *reinterpret_cast<uint2*>(o_out + obase + quad * 4)      = make_uint2(pk0, pk1);
  *reinterpret_cast<uint2*>(o_out + obase + 16 + quad * 4) = make_uint2(pk2, pk3);
}

// -------------------------------------------------------------------------------
// STRICT ws budget (never write beyond ws_size):
//   [0,4MB)   misc: BN sums/coeffs, idxb, smr, qkm, bf16 weights, bn2 partials
//   [4,20MB)  s1 (branch1) then s2 (branch2), bf16 16MB
//   [20MB,..) chunk buffers (branch1 only now), adaptively sized from ws_size.
// x2 (fp32 [32768,256], 32MB) lives in d_out; fused FFN updates d_out in place.
// Minimum ws_size supported: 28MB.
extern "C" void kernel_launch(void* const* d_in, const int* in_sizes, int n_in,
                              void* d_out, int out_size, void* d_ws, size_t ws_size,
                              hipStream_t stream)
{
  const float* x      = (const float*)d_in[0];
  const float* bn1_g  = (const float*)d_in[1];
  const float* bn1_b  = (const float*)d_in[2];
  const float* bn2_g  = (const float*)d_in[3];
  const float* bn2_b  = (const float*)d_in[4];
  const float* qkv_w  = (const float*)d_in[5];
  const float* qkv_b  = (const float*)d_in[6];
  const float* proj_w = (const float*)d_in[7];
  const float* proj_b = (const float*)d_in[8];
  const float* ffn_w1 = (const float*)d_in[9];
  const float* ffn_b1 = (const float*)d_in[10];
  const float* ffn_w2 = (const float*)d_in[11];
  const float* ffn_b2 = (const float*)d_in[12];
  const float* scale  = (const float*)d_in[13];
  float* x2 = (float*)d_out;       // residual lives in d_out

  char* ws = (char*)d_ws;
  const size_t MB = 1024 * 1024;
  float* sum1 = (float*)(ws + 0);
  float* sq1  = (float*)(ws + 1024);
  float* a1   = (float*)(ws + 4096);
  float* b1   = (float*)(ws + 5120);
  float* a2   = (float*)(ws + 6144);
  float* b2   = (float*)(ws + 7168);
  int*   idxb = (int*)(ws + 8192);                              // 8KB
  float* smr  = (float*)(ws + 16384);                           // 512KB
  float* qkm  = (float*)(ws + 540672);                          // 1MB
  __hip_bfloat16* qkv_wb  = (__hip_bfloat16*)(ws + 1589248);    // 384KB
  __hip_bfloat16* proj_wb = (__hip_bfloat16*)(ws + 1982464);    // 128KB
  __hip_bfloat16* ffn_w1b = (__hip_bfloat16*)(ws + 2113536);    // 512KB
  __hip_bfloat16* ffn_w2b = (__hip_bfloat16*)(ws + 2637824);    // 512KB, ends 3162112
  float* ppsum = (float*)(ws + 3162112);                        // 512KB (512x256 f32)
  float* ppsq  = (float*)(ws + 3686400);                        // 512KB, ends 4MB exactly
  __hip_bfloat16* s1 = (__hip_bfloat16*)(ws + 4 * MB);          // 16MB (s2 reuses)
  __hip_bfloat16* s2 = s1;
  char* chunkbuf = ws + 20 * MB;

  // adaptive chunk sizes from ws_size (constant across calls -> graph-safe)
  size_t avail = (ws_size > 20 * MB) ? (ws_size - 20 * MB) : (8 * MB);
  int nc = (avail >= 64 * MB) ? 8 : (avail >= 32 * MB) ? 4 : (avail >= 16 * MB) ? 2 : 1;   // samples/chunk (8MB each)

  __hip_bfloat16* qkvc = (__hip_bfloat16*)chunkbuf;                        // nc*6MB
  __hip_bfloat16* oc   = (__hip_bfloat16*)(chunkbuf + (size_t)nc * 6 * MB); // nc*2MB

  hipMemsetAsync(d_ws, 0, 4096, stream);   // zero BN1 accumulators

  // one-time weight conversions fp32 -> bf16 (single launch)
  f2ball_k<<<3072, 256, 0, stream>>>(qkv_w, proj_w, ffn_w1, ffn_w2,
                                     qkv_wb, proj_wb, ffn_w1b, ffn_w2b);

  // branch 1: BN -> LIF -> routing, then per-chunk qkv -> attn -> proj+residual
  bn_stats_k<<<256, 256, 0, stream>>>(x, sum1, sq1);
  bn_fin_k<<<1, 256, 0, stream>>>(sum1, sq1, bn1_g, bn1_b, a1, b1);
  lif_k<<<PERT / 1024, 256, 0, stream>>>(x, a1, b1, s1);
  region_sum_k<<<512, 256, 0, stream>>>(s1, smr);
  rgemm_k<<<512, 256, 0, stream>>>(smr, qkv_w, qkv_b, qkm);   // fp32 routing (flip-proof)
  topk_k<<<512, 64, 0, stream>>>(qkm, idxb);

  const int nchunkA = 8 / nc;
  for (int c = 0; c < nchunkA; ++c){
    const size_t ro = (size_t)c * nc * SAMP_TOK;            // row offset (tokens)
    gemm_bt<0><<<dim3(nc * SAMP_TOK / 128, 6), 256, 0, stream>>>(
        s1 + ro * 256, qkv_wb, qkv_b, qkvc, nullptr, nullptr, nullptr, nullptr, 256, 768);
    attn_mfma_k<<<dim3(nc * 64, 8), 256, 0, stream>>>(qkvc, idxb, oc, c * nc * 64);
    gemm_bt<1><<<dim3(nc * SAMP_TOK / 128, 2), 256, 0, stream>>>(
        oc, proj_wb, proj_b, x2 + ro * 256, x + ro * 256, scale,
        ppsum + (ro >> 6) * 256, ppsq + (ro >> 6) * 256, 256, 256);
  }

  // branch 2: bn2 partial-reduce (atomic-free) -> LIF -> fused FFN (in-place)
  bn_red_k<<<1, 256, 0, stream>>>(ppsum, ppsq, bn2_g, bn2_b, a2, b2);
  lif_k<<<PERT / 1024, 256, 0, stream>>>(x2, a2, b2, s2);
  ffn_fused_k<<<512, 512, 0, stream>>>(s2, ffn_w1b, ffn_b1, ffn_w2b, ffn_b2, x2, scale);
}

// Round 10
// 339.849 us; speedup vs baseline: 1.2205x; 1.0236x over previous
//
#include <hip/hip_runtime.h>
#include <hip/hip_bf16.h>
#include <math.h>

typedef __attribute__((ext_vector_type(8))) short short8;
typedef __attribute__((ext_vector_type(4))) float f32x4;

#define DIM 256
#define NROWS 32768      // T*B*Ltot rows
#define PERT 2097152     // B*Ltot*D elements per timestep
#define SAMP_TOK 4096    // tokens per (t,b) sample

__device__ __forceinline__ float b2f(__hip_bfloat16 h){ return __bfloat162float(h); }
__device__ __forceinline__ __hip_bfloat16 f2b(float f){ return __float2bfloat16(f); }
__device__ __forceinline__ unsigned short f2bu(float f){
  __hip_bfloat16 h = __float2bfloat16(f);
  unsigned short u; __builtin_memcpy(&u, &h, 2); return u;
}

// async global -> LDS, 16B per lane (wave-uniform base + lane*16 on LDS side)
#define GLD_LDS16(gp, lp) __builtin_amdgcn_global_load_lds( \
    (const __attribute__((address_space(1))) unsigned int*)(gp), \
    (__attribute__((address_space(3))) unsigned int*)(lp), 16, 0, 0)

// branchless erf-based exact gelu (A&S 7.1.26, |err| <= ~3e-7: below bf16 ulp)
__device__ __forceinline__ float gelu_fast(float v){
  float z  = v * 0.70710678118654752f;
  float az = fabsf(z);
  float t  = __builtin_amdgcn_rcpf(fmaf(0.3275911f, az, 1.0f));
  float p  = fmaf(fmaf(fmaf(fmaf(1.061405429f, t, -1.453152027f), t,
                            1.421413741f), t, -0.284496736f), t, 0.254829592f);
  p *= t;
  float e  = __expf(-z * z);
  float y  = fmaf(-p, e, 1.0f);                 // erf(|z|)
  return fmaf(0.5f * fabsf(v), y, 0.5f * v);    // 0.5*v*(1+sign(v)*erf(|z|))
}

// ---------------- fp32 -> bf16 weight conversion (all 4 weights, one launch) ---
__global__ void f2ball_k(const float* __restrict__ w_qkv, const float* __restrict__ w_proj,
                         const float* __restrict__ w_f1, const float* __restrict__ w_f2,
                         __hip_bfloat16* __restrict__ o_qkv, __hip_bfloat16* __restrict__ o_proj,
                         __hip_bfloat16* __restrict__ o_f1, __hip_bfloat16* __restrict__ o_f2){
  int i = blockIdx.x * 256 + threadIdx.x;        // 0 .. 786431
  if (i < 196608)          o_qkv[i]           = f2b(w_qkv[i]);
  else if (i < 262144)     o_proj[i - 196608] = f2b(w_proj[i - 196608]);
  else if (i < 524288)     o_f1[i - 262144]   = f2b(w_f1[i - 262144]);
  else                     o_f2[i - 524288]   = f2b(w_f2[i - 524288]);
}

// ---------------- BN stats (branch 1): per-channel sum / sumsq -----------------
__global__ void bn_stats_k(const float* __restrict__ x, float* __restrict__ sum, float* __restrict__ sumsq){
  __shared__ __align__(16) float rs[4][256];
  __shared__ __align__(16) float rq[4][256];
  int t = threadIdx.x;
  int g = t & 63, r = t >> 6;
  size_t base = ((size_t)blockIdx.x * 128 + r) * DIM + g * 4;   // 128 rows per block
  float4 s = {0.f,0.f,0.f,0.f}, q = {0.f,0.f,0.f,0.f};
  for (int i = 0; i < 32; ++i){
    float4 v = *reinterpret_cast<const float4*>(x + base + (size_t)i * 4 * DIM);
    s.x += v.x; s.y += v.y; s.z += v.z; s.w += v.w;
    q.x += v.x*v.x; q.y += v.y*v.y; q.z += v.z*v.z; q.w += v.w*v.w;
  }
  *reinterpret_cast<float4*>(&rs[r][g*4]) = s;
  *reinterpret_cast<float4*>(&rq[r][g*4]) = q;
  __syncthreads();
  int c = t;   // one channel per thread
  atomicAdd(&sum[c],   rs[0][c] + rs[1][c] + rs[2][c] + rs[3][c]);
  atomicAdd(&sumsq[c], rq[0][c] + rq[1][c] + rq[2][c] + rq[3][c]);
}

__global__ void bn_fin_k(const float* __restrict__ sum, const float* __restrict__ sumsq,
                         const float* __restrict__ g, const float* __restrict__ b,
                         float* __restrict__ a_out, float* __restrict__ b_out){
  int c = threadIdx.x;
  float mean = sum[c] * (1.f/32768.f);
  float var  = sumsq[c] * (1.f/32768.f) - mean*mean;
  float a = g[c] / sqrtf(var + 1e-5f);
  a_out[c] = a;
  b_out[c] = b[c] - mean * a;
}

// ---------------- BN2 reduce: column-sum the 512x256 partial grids -------------
__global__ void bn_red_k(const float* __restrict__ pps, const float* __restrict__ ppq,
                         const float* __restrict__ g, const float* __restrict__ b,
                         float* __restrict__ a_out, float* __restrict__ b_out){
  int c = threadIdx.x;
  float s = 0.f, q = 0.f;
  for (int r = 0; r < 512; ++r){
    s += pps[r * 256 + c];
    q += ppq[r * 256 + c];
  }
  float mean = s * (1.f/32768.f);
  float var  = q * (1.f/32768.f) - mean*mean;
  float a = g[c] / sqrtf(var + 1e-5f);
  a_out[c] = a;
  b_out[c] = b[c] - mean * a;
}

// ---------------- LIF over T=4 (binary spike out, bf16 exact) ------------------
__global__ void lif_k(const float* __restrict__ x, const float* __restrict__ av,
                      const float* __restrict__ bv, __hip_bfloat16* __restrict__ s){
  int i = blockIdx.x * 256 + threadIdx.x;       // 0 .. PERT/4-1 (exact grid)
  int e4 = i * 4;
  int c4 = e4 & (DIM - 1);
  float4 a = *reinterpret_cast<const float4*>(av + c4);
  float4 b = *reinterpret_cast<const float4*>(bv + c4);
  float4 v = {0.f,0.f,0.f,0.f};
  #pragma unroll
  for (int t = 0; t < 4; ++t){
    float4 xn = *reinterpret_cast<const float4*>(x + (size_t)t * PERT + e4);
    xn.x = fmaf(xn.x, a.x, b.x); xn.y = fmaf(xn.y, a.y, b.y);
    xn.z = fmaf(xn.z, a.z, b.z); xn.w = fmaf(xn.w, a.w, b.w);
    v.x += (xn.x - v.x) * 0.5f; v.y += (xn.y - v.y) * 0.5f;
    v.z += (xn.z - v.z) * 0.5f; v.w += (xn.w - v.w) * 0.5f;
    ushort4 sp;
    sp.x = (v.x >= 1.0f) ? 0x3F80 : 0;  v.x = (v.x >= 1.0f) ? 0.f : v.x;
    sp.y = (v.y >= 1.0f) ? 0x3F80 : 0;  v.y = (v.y >= 1.0f) ? 0.f : v.y;
    sp.z = (v.z >= 1.0f) ? 0x3F80 : 0;  v.z = (v.z >= 1.0f) ? 0.f : v.z;
    sp.w = (v.w >= 1.0f) ? 0x3F80 : 0;  v.w = (v.w >= 1.0f) ? 0.f : v.w;
    *reinterpret_cast<ushort4*>(reinterpret_cast<unsigned short*>(s) + (size_t)t * PERT + e4) = sp;
  }
}

// ---------------- region means of binary s1 (exact fp32) -----------------------
__global__ void region_sum_k(const __hip_bfloat16* __restrict__ s, float* __restrict__ sm){
  __shared__ __align__(16) float red[4][256];
  int r = blockIdx.x, t = threadIdx.x;    // r = (sample*64 + region), 512 total
  int g = t & 63, sub = t >> 6;
  const unsigned short* sp = reinterpret_cast<const unsigned short*>(s);
  size_t base = ((size_t)r * 64 + sub * 16) * DIM + g * 4;
  float4 acc = {0.f,0.f,0.f,0.f};
  for (int i = 0; i < 16; ++i){
    ushort4 u = *reinterpret_cast<const ushort4*>(sp + base + (size_t)i * DIM);
    acc.x += (u.x != 0) ? 1.f : 0.f; acc.y += (u.y != 0) ? 1.f : 0.f;
    acc.z += (u.z != 0) ? 1.f : 0.f; acc.w += (u.w != 0) ? 1.f : 0.f;
  }
  *reinterpret_cast<float4*>(&red[sub][g*4]) = acc;
  __syncthreads();
  if (sub == 0){
    float4 o;
    o.x = (red[0][g*4+0] + red[1][g*4+0] + red[2][g*4+0] + red[3][g*4+0]) * 0.015625f;
    o.y = (red[0][g*4+1] + red[1][g*4+1] + red[2][g*4+1] + red[3][g*4+1]) * 0.015625f;
    o.z = (red[0][g*4+2] + red[1][g*4+2] + red[2][g*4+2] + red[3][g*4+2]) * 0.015625f;
    o.w = (red[0][g*4+3] + red[1][g*4+3] + red[2][g*4+3] + red[3][g*4+3]) * 0.015625f;
    *reinterpret_cast<float4*>(sm + (size_t)r * DIM + g * 4) = o;
  }
}

// ---------------- routing GEMM fp32: qkm[r][j] = smr[r]·qkv_w[j] + b[j], j<512 -
__global__ void rgemm_k(const float* __restrict__ smr, const float* __restrict__ w,
                        const float* __restrict__ bias, float* __restrict__ qkm){
  __shared__ float arow[256];
  int r = blockIdx.x, t = threadIdx.x;
  arow[t] = smr[(size_t)r * 256 + t];
  __syncthreads();
  for (int j = t; j < 512; j += 256){
    const float* wr = w + (size_t)j * 256;
    float acc = 0.f;
    for (int k = 0; k < 256; ++k) acc += arow[k] * wr[k];
    qkm[(size_t)r * 512 + j] = acc + bias[j];
  }
}

// ---------------- GEMM: C[M,N] = A[M,K] @ W[N,K]^T (+bias, epilogue) -----------
// (branch 1 only: EPI 0 = qkv bf16 out, EPI 1 = proj f32 + residual + bn2
//  partial stats, non-atomic)
template<int EPI>
__global__ __launch_bounds__(256) void gemm_bt(
    const __hip_bfloat16* __restrict__ A, const __hip_bfloat16* __restrict__ W,
    const float* __restrict__ bias, void* __restrict__ outp,
    const void* __restrict__ extra, const float* __restrict__ scaleptr,
    float* __restrict__ pps, float* __restrict__ ppq,
    int K, int N)
{
  __shared__ __align__(16) short As0[128 * 32];   // 8KB each, linear layout
  __shared__ __align__(16) short Ws0[128 * 32];
  __shared__ __align__(16) short As1[128 * 32];
  __shared__ __align__(16) short Ws1[128 * 32];
  int tid = threadIdx.x;
  int bm = blockIdx.x, bn = blockIdx.y;
  int lane = tid & 63;
  int l16 = lane & 15, quad = lane >> 4;
  int wv = tid >> 6;
  int wm = (wv >> 1) << 6, wn = (wv & 1) << 6;

  const int srow = tid >> 2;
  const int sq   = (tid & 3) ^ ((srow >> 1) & 3);
  const __hip_bfloat16* Ag = A + (size_t)(bm * 128 + srow) * K + (sq << 3);
  const __hip_bfloat16* Wg = W + (size_t)(bn * 128 + srow) * K + (sq << 3);
  const size_t rstep = (size_t)64 * K;

  int roA[4], roW[4];
  #pragma unroll
  for (int i = 0; i < 4; ++i){
    int Ra = wm + i * 16 + l16;
    roA[i] = Ra * 32 + ((quad ^ ((Ra >> 1) & 3)) << 3);
    int Rw = wn + i * 16 + l16;
    roW[i] = Rw * 32 + ((quad ^ ((Rw >> 1) & 3)) << 3);
  }

  f32x4 zero = {0.f, 0.f, 0.f, 0.f};
  f32x4 acc[4][4];
  #pragma unroll
  for (int i = 0; i < 4; ++i)
    #pragma unroll
    for (int j = 0; j < 4; ++j) acc[i][j] = zero;

  auto stage = [&](short* Ad, short* Wd, int k0){
    GLD_LDS16(Ag + k0,         Ad + tid * 8);
    GLD_LDS16(Ag + rstep + k0, Ad + tid * 8 + 2048);
    GLD_LDS16(Wg + k0,         Wd + tid * 8);
    GLD_LDS16(Wg + rstep + k0, Wd + tid * 8 + 2048);
  };
  auto compute = [&](const short* Asb, const short* Wsb){
    short8 af[4];
    #pragma unroll
    for (int mi = 0; mi < 4; ++mi)
      af[mi] = *reinterpret_cast<const short8*>(Asb + roA[mi]);
    #pragma unroll
    for (int ni = 0; ni < 4; ++ni){
      short8 wf = *reinterpret_cast<const short8*>(Wsb + roW[ni]);
      #pragma unroll
      for (int mi = 0; mi < 4; ++mi)
        acc[mi][ni] = __builtin_amdgcn_mfma_f32_16x16x32_bf16(wf, af[mi], acc[mi][ni], 0, 0, 0);
    }
  };

  stage(As0, Ws0, 0);
  __syncthreads();
  for (int k0 = 0; k0 < K; k0 += 64){
    if (k0 + 32 < K) stage(As1, Ws1, k0 + 32);
    compute(As0, Ws0);
    __syncthreads();
    if (k0 + 64 < K) stage(As0, Ws0, k0 + 64);
    if (k0 + 32 < K) compute(As1, Ws1);
    __syncthreads();
  }

  if (EPI == 0){
    // ---- coalesced bf16 epilogue: wave-private 64x64 C-tile via dead staging LDS
    short* Cw = (wv == 0) ? As0 : (wv == 1) ? Ws0 : (wv == 2) ? As1 : Ws1;
    #pragma unroll
    for (int ni = 0; ni < 4; ++ni){
      int col0 = (bn << 7) + wn + ni * 16 + (quad << 2);
      float4 bv = *reinterpret_cast<const float4*>(bias + col0);
      #pragma unroll
      for (int mi = 0; mi < 4; ++mi){
        float v0 = acc[mi][ni][0] + bv.x;
        float v1 = acc[mi][ni][1] + bv.y;
        float v2 = acc[mi][ni][2] + bv.z;
        float v3 = acc[mi][ni][3] + bv.w;
        unsigned lo = (unsigned)f2bu(v0) | ((unsigned)f2bu(v1) << 16);
        unsigned hi = (unsigned)f2bu(v2) | ((unsigned)f2bu(v3) << 16);
        int row = mi * 16 + l16;
        int cb  = (ni * 32 + (quad << 3)) ^ ((row & 7) << 4);
        *reinterpret_cast<uint2*>(reinterpret_cast<char*>(Cw) + row * 128 + cb) =
            make_uint2(lo, hi);
      }
    }
    asm volatile("s_waitcnt lgkmcnt(0)" ::: "memory");
    #pragma unroll
    for (int p = 0; p < 8; ++p){
      int row = p * 8 + (lane >> 3);
      int cb  = ((lane & 7) << 4) ^ ((row & 7) << 4);
      uint4 val = *reinterpret_cast<const uint4*>(
          reinterpret_cast<const char*>(Cw) + row * 128 + cb);
      int rowg = (bm << 7) + wm + row;
      int colg = (bn << 7) + wn + ((lane & 7) << 3);
      *reinterpret_cast<uint4*>((__hip_bfloat16*)outp + (size_t)rowg * N + colg) = val;
    }
  } else {
    // ---- f32 epilogue (proj): residual + fused bn2 partial stats (non-atomic)
    float sc = scaleptr[0];
    float4 ts[4], tq[4];
    #pragma unroll
    for (int ni = 0; ni < 4; ++ni){ ts[ni] = {0.f,0.f,0.f,0.f}; tq[ni] = {0.f,0.f,0.f,0.f}; }
    #pragma unroll
    for (int ni = 0; ni < 4; ++ni){
      int col0 = (bn << 7) + wn + ni * 16 + (quad << 2);
      float4 bv = *reinterpret_cast<const float4*>(bias + col0);
      #pragma unroll
      for (int mi = 0; mi < 4; ++mi){
        int rowg = (bm << 7) + wm + mi * 16 + l16;
        size_t off = (size_t)rowg * N + col0;
        float v0 = acc[mi][ni][0] + bv.x;
        float v1 = acc[mi][ni][1] + bv.y;
        float v2 = acc[mi][ni][2] + bv.z;
        float v3 = acc[mi][ni][3] + bv.w;
        float4 xr = *reinterpret_cast<const float4*>((const float*)extra + off);
        float4 ov;
        ov.x = xr.x + v0 * sc; ov.y = xr.y + v1 * sc;
        ov.z = xr.z + v2 * sc; ov.w = xr.w + v3 * sc;
        *reinterpret_cast<float4*>((float*)outp + off) = ov;
        ts[ni].x += ov.x; ts[ni].y += ov.y; ts[ni].z += ov.z; ts[ni].w += ov.w;
        tq[ni].x += ov.x*ov.x; tq[ni].y += ov.y*ov.y;
        tq[ni].z += ov.z*ov.z; tq[ni].w += ov.w*ov.w;
      }
    }
    int prow = (bm << 1) + (wm >> 6);
    #pragma unroll
    for (int ni = 0; ni < 4; ++ni){
      float4 S = ts[ni], Q = tq[ni];
      #pragma unroll
      for (int m = 1; m < 16; m <<= 1){
        S.x += __shfl_xor(S.x, m); S.y += __shfl_xor(S.y, m);
        S.z += __shfl_xor(S.z, m); S.w += __shfl_xor(S.w, m);
        Q.x += __shfl_xor(Q.x, m); Q.y += __shfl_xor(Q.y, m);
        Q.z += __shfl_xor(Q.z, m); Q.w += __shfl_xor(Q.w, m);
      }
      if (l16 == 0){
        int col0 = (bn << 7) + wn + ni * 16 + (quad << 2);
        *reinterpret_cast<float4*>(pps + prow * 256 + col0) = S;
        *reinterpret_cast<float4*>(ppq + prow * 256 + col0) = Q;
      }
    }
  }
}

// ---------------- FUSED FFN: out = x2 + (gelu(s2@W1^T+b1)@W2^T+b2)*scale -------
// 512 threads / 8 waves per 64-row block (16 waves/CU at 2 blocks/CU).
// R10 fixes vs R9:
//  * W2 swizzle over (Rw>>1)&3 on BOTH sides (R9's (Rw&3) collapsed to 4 slots
//    because row parity bit aliased -> 4-way conflict, the 1.57M counter).
//    Bank slot = (Rw&1)*64 + (quad^((Rw>>1)&3))*16: 8 slots x 2 lanes = free.
//  * next-c1 stage1(S0) folded into GEMM2 kk=3 (S0 last read kk=2, sync'd;
//    kk=3's end-sync drains the GLD) -> one barrier + one latency bubble less
//    per c1.
// LDS (shorts): h [0,8192) | slab0 [8192,20480) {A 4096, W1 8192} | slab1
// [20480,32768). Total exactly 65536 B.
__global__ __launch_bounds__(512, 4) void ffn_fused_k(
    const __hip_bfloat16* __restrict__ A,   // s2 [32768,256]
    const __hip_bfloat16* __restrict__ W1,  // [1024,256] bf16
    const float* __restrict__ b1,
    const __hip_bfloat16* __restrict__ W2,  // [256,1024] bf16
    const float* __restrict__ b2,
    float* __restrict__ x2,                 // in/out [32768,256] f32
    const float* __restrict__ scaleptr)
{
  __shared__ __align__(16) short lds[32768];   // 64KB exactly
  const int tid = threadIdx.x;                 // 0..511
  const int bm = blockIdx.x;                   // 512 blocks x 64 rows
  const int lane = tid & 63;
  const int l16 = lane & 15, quad = lane >> 4;
  const int wv = tid >> 6;                     // wave 0..7

  const int H = 0, S0 = 8192, S1 = 20480;      // short offsets

  // ---- staging source addresses (pre-swizzled col-blocks) ----
  const int ar = tid >> 3, as = tid & 7;                    // A/W1 granule: row, slot
  const int asq = (as ^ (ar & 7)) << 3;
  const __hip_bfloat16* Ag = A + (size_t)(bm * 64 + ar) * 256 + asq;   // rows 0..63
  const int w2r = tid >> 2, w2s = tid & 3;                  // W2 granule: row, slot
  const int w2q = (w2s ^ ((w2r >> 1) & 3)) << 3;            // involution over (row>>1)&3

  // ---- read offsets (shorts, slab-relative / h-relative) ----
  int roA[4][2];                        // A: [mi][kh]
  #pragma unroll
  for (int mi = 0; mi < 4; ++mi){
    int Ra = mi * 16 + l16;
    #pragma unroll
    for (int kh = 0; kh < 2; ++kh)
      roA[mi][kh] = Ra * 64 + ((((kh << 5) | (quad << 3)) ^ ((Ra & 7) << 3)));
  }
  int roW1[2];
  {
    int Rw = wv * 16 + l16;
    #pragma unroll
    for (int kh = 0; kh < 2; ++kh)
      roW1[kh] = 4096 + Rw * 64 + ((((kh << 5) | (quad << 3)) ^ ((Rw & 7) << 3)));
  }
  int hwr[4], hrb[4];                   // h write / read bases per mi
  const int hxor = l16 << 3;            // (row&15)<<3 with row = mi*16+l16
  #pragma unroll
  for (int mi = 0; mi < 4; ++mi){
    int row = mi * 16 + l16;
    hwr[mi] = row * 128 + (((wv * 16 + quad * 4)) ^ hxor);
    hrb[mi] = row * 128;
  }
  int roW2[2];
  #pragma unroll
  for (int ni = 0; ni < 2; ++ni){
    int Rw = wv * 32 + ni * 16 + l16;
    roW2[ni] = Rw * 32 + (((quad ^ ((Rw >> 1) & 3))) << 3);
  }

  f32x4 zero = {0.f, 0.f, 0.f, 0.f};
  f32x4 acc2[4][2];
  #pragma unroll
  for (int i = 0; i < 4; ++i){ acc2[i][0] = zero; acc2[i][1] = zero; }

  float sc = scaleptr[0];

  // stage one GEMM1 K-step for chunk cc into slab S: A[64x64] + W1[128x64]
  auto stage1 = [&](int S, int cc, int k0){
    const __hip_bfloat16* W1g = W1 + (size_t)(cc * 128 + ar) * 256 + asq;
    GLD_LDS16(Ag + k0,              lds + S + tid * 8);
    GLD_LDS16(W1g + k0,             lds + S + 4096 + tid * 8);
    GLD_LDS16(W1g + 64 * 256 + k0,  lds + S + 8192 + tid * 8);
  };
  auto stageW2 = [&](int S, int cc, int kk){
    const __hip_bfloat16* p = W2 + (size_t)w2r * 1024 + cc * 128 + kk * 32 + w2q;
    GLD_LDS16(p,               lds + S + tid * 8);
    GLD_LDS16(p + 128 * 1024,  lds + S + 4096 + tid * 8);
  };

  stage1(S0, 0, 0);
  __syncthreads();

  for (int c1 = 0; c1 < 8; ++c1){
    f32x4 acc1[4];
    #pragma unroll
    for (int i = 0; i < 4; ++i) acc1[i] = zero;

    auto compute1 = [&](int S){
      #pragma unroll
      for (int kh = 0; kh < 2; ++kh){
        short8 wf = *reinterpret_cast<const short8*>(lds + S + roW1[kh]);
        #pragma unroll
        for (int mi = 0; mi < 4; ++mi){
          short8 af = *reinterpret_cast<const short8*>(lds + S + roA[mi][kh]);
          acc1[mi] = __builtin_amdgcn_mfma_f32_16x16x32_bf16(wf, af, acc1[mi], 0, 0, 0);
        }
      }
    };

    // ---- GEMM1: 4 K-steps of 64, double-buffered (S0 pre-staged) ----
    #pragma unroll
    for (int k = 0; k < 4; ++k){
      const int cur = (k & 1) ? S1 : S0;
      const int nxt = (k & 1) ? S0 : S1;
      if (k < 3) stage1(nxt, c1, (k + 1) * 64);
      compute1(cur);
      __syncthreads();
    }

    // ---- W2 slice 0 prefetch (lands under gelu VALU work) ----
    stageW2(S0, c1, 0);

    // ---- bias + gelu + pack h (swizzled) ----
    {
      int colg = c1 * 128 + wv * 16 + quad * 4;
      float4 bv = *reinterpret_cast<const float4*>(b1 + colg);
      #pragma unroll
      for (int mi = 0; mi < 4; ++mi){
        float g0 = gelu_fast(acc1[mi][0] + bv.x);
        float g1 = gelu_fast(acc1[mi][1] + bv.y);
        float g2 = gelu_fast(acc1[mi][2] + bv.z);
        float g3 = gelu_fast(acc1[mi][3] + bv.w);
        unsigned lo = (unsigned)f2bu(g0) | ((unsigned)f2bu(g1) << 16);
        unsigned hi = (unsigned)f2bu(g2) | ((unsigned)f2bu(g3) << 16);
        *reinterpret_cast<uint2*>(lds + H + hwr[mi]) = make_uint2(lo, hi);
      }
    }
    __syncthreads();   // h visible + W2_0 landed

    // ---- GEMM2 partial: acc2 += h[64x128] @ W2[:, c1]^T, 4 k-steps dbuf.
    //      At kk==3 stage next c1's GEMM1 step-0 into S0 (last read kk=2).
    #pragma unroll
    for (int kk = 0; kk < 4; ++kk){
      const int cur = (kk & 1) ? S1 : S0;
      const int nxt = (kk & 1) ? S0 : S1;
      if (kk < 3)            stageW2(nxt, c1, kk + 1);
      else if (c1 < 7)       stage1(S0, c1 + 1, 0);
      short8 af[4];
      #pragma unroll
      for (int mi = 0; mi < 4; ++mi){
        int hc = (((kk << 5) | (quad << 3)) ^ hxor);
        af[mi] = *reinterpret_cast<const short8*>(lds + H + hrb[mi] + hc);
      }
      #pragma unroll
      for (int ni = 0; ni < 2; ++ni){
        short8 wf = *reinterpret_cast<const short8*>(lds + cur + roW2[ni]);
        #pragma unroll
        for (int mi = 0; mi < 4; ++mi)
          acc2[mi][ni] = __builtin_amdgcn_mfma_f32_16x16x32_bf16(wf, af[mi], acc2[mi][ni], 0, 0, 0);
      }
      __syncthreads();
    }
  }

  // ---- epilogue: out = x2 + (acc2 + b2)*scale, float4 (full-sector stores)
  #pragma unroll
  for (int ni = 0; ni < 2; ++ni){
    int col0 = wv * 32 + ni * 16 + (quad << 2);
    float4 bv = *reinterpret_cast<const float4*>(b2 + col0);
    #pragma unroll
    for (int mi = 0; mi < 4; ++mi){
      int rowg = bm * 64 + mi * 16 + l16;
      size_t off = (size_t)rowg * 256 + col0;
      float4 xr = *reinterpret_cast<const float4*>(x2 + off);
      float4 ov;
      ov.x = xr.x + (acc2[mi][ni][0] + bv.x) * sc;
      ov.y = xr.y + (acc2[mi][ni][1] + bv.y) * sc;
      ov.z = xr.z + (acc2[mi][ni][2] + bv.z) * sc;
      ov.w = xr.w + (acc2[mi][ni][3] + bv.w) * sc;
      *reinterpret_cast<float4*>(x2 + off) = ov;
    }
  }
}

// ---------------- top-k routing: aff = qm @ km^T per sample, pick top-4 --------
__global__ void topk_k(const float* __restrict__ qkm, int* __restrict__ idx){
  __shared__ float aff[64];
  int r = blockIdx.x;           // sample*64 + query region
  int m = threadIdx.x;          // candidate region 0..63
  int b = r >> 6;
  const float4* qrow = reinterpret_cast<const float4*>(qkm + (size_t)r * 512);
  const float4* krow = reinterpret_cast<const float4*>(qkm + (size_t)(b * 64 + m) * 512 + 256);
  float dot = 0.f;
  for (int d = 0; d < 64; ++d){
    float4 qv = qrow[d], kv = krow[d];
    dot += qv.x * kv.x + qv.y * kv.y + qv.z * kv.z + qv.w * kv.w;
  }
  aff[m] = dot;
  __syncthreads();
  if (m == 0){
    #pragma unroll
    for (int t = 0; t < 4; ++t){
      float best = -INFINITY; int bi = 0;
      for (int i = 0; i < 64; ++i){
        if (aff[i] > best){ best = aff[i]; bi = i; }   // strict >: lowest index on ties (jax top_k)
      }
      aff[bi] = -INFINITY;
      idx[r * 4 + t] = bi;
    }
  }
}

// ---------------- MFMA routed attention: block per (region, head) --------------
// R10: P region moved down to short-offset 8448 (Vt only needs [0,8448); the
// Ks tail [8448,10240) is dead after the post-S barrier). LDS 54272 -> 50688 B
// => 3 blocks/CU (12 waves/CU) instead of 2 — attn was latency-bound at 19% occ.
__global__ __launch_bounds__(256) void attn_mfma_k(
    const __hip_bfloat16* __restrict__ qkv, const int* __restrict__ idx,
    __hip_bfloat16* __restrict__ o_out, int rbase)
{
  __shared__ __align__(16) short lds[25344];   // 50688 B
  const int rl = blockIdx.x;       // local region in this chunk
  const int h  = blockIdx.y;       // head
  const int rg = rbase + rl;       // global region (for idx)
  const int bl = rl >> 6;          // local sample
  const int tid = threadIdx.x;
  const int w = tid >> 6, lane = tid & 63;
  const int l16 = lane & 15, quad = lane >> 4;
  short* Pw = lds + 8448 + w * 4224;

  const int reg = idx[rg * 4 + (tid >> 6)] & 63;       // clamp: never OOB
  const size_t srow = (size_t)bl * SAMP_TOK + (size_t)reg * 64 + (tid & 63);
  const __hip_bfloat16* kvsrc = qkv + srow * 768 + 256 + (size_t)h * 32;

  const size_t qrow = (size_t)rl * 64 + w * 16 + l16;
  short8 qf = *reinterpret_cast<const short8*>(qkv + qrow * 768 + (size_t)h * 32 + quad * 8);

  uint4 vreg[4];
  #pragma unroll
  for (int c = 0; c < 4; ++c)
    vreg[c] = *reinterpret_cast<const uint4*>(kvsrc + 256 + c * 8);

  // K -> Ks[token][40] occupies [0,10240); its tail overlaps the P region,
  // which is only written after the post-S barrier (Ks dead by then).
  #pragma unroll
  for (int c = 0; c < 4; ++c)
    *reinterpret_cast<uint4*>(&lds[tid * 40 + c * 8]) =
      *reinterpret_cast<const uint4*>(kvsrc + c * 8);
  __syncthreads();

  f32x4 s[16];
  #pragma unroll
  for (int nt = 0; nt < 16; ++nt){
    short8 kf = *reinterpret_cast<const short8*>(&lds[(nt * 16 + l16) * 40 + quad * 8]);
    f32x4 z = {0.f, 0.f, 0.f, 0.f};
    s[nt] = __builtin_amdgcn_mfma_f32_16x16x32_bf16(kf, qf, z, 0, 0, 0);
  }
  __syncthreads();   // all waves done reading Ks -> whole Ks region reusable

  #pragma unroll
  for (int c = 0; c < 4; ++c){
    short8 vv = *reinterpret_cast<short8*>(&vreg[c]);
    #pragma unroll
    for (int e = 0; e < 8; ++e)
      lds[(c * 8 + e) * 264 + tid] = vv[e];
  }

  float mx = -1e30f;
  #pragma unroll
  for (int nt = 0; nt < 16; ++nt)
    #pragma unroll
    for (int r = 0; r < 4; ++r) mx = fmaxf(mx, s[nt][r]);
  mx = fmaxf(mx, __shfl_xor(mx, 16));
  mx = fmaxf(mx, __shfl_xor(mx, 32));
  float den = 0.f;
  #pragma unroll
  for (int nt = 0; nt < 16; ++nt)
    #pragma unroll
    for (int r = 0; r < 4; ++r){
      float e = __expf((s[nt][r] - mx) * 0.17677669529663687f);  // scale folded in
      s[nt][r] = e; den += e;
    }
  den += __shfl_xor(den, 16);
  den += __shfl_xor(den, 32);

  #pragma unroll
  for (int nt = 0; nt < 16; ++nt){
    unsigned lo = (unsigned)f2bu(s[nt][0]) | ((unsigned)f2bu(s[nt][1]) << 16);
    unsigned hi = (unsigned)f2bu(s[nt][2]) | ((unsigned)f2bu(s[nt][3]) << 16);
    *reinterpret_cast<uint2*>(&Pw[l16 * 264 + nt * 16 + quad * 4]) = make_uint2(lo, hi);
  }
  __syncthreads();

  f32x4 o0 = {0.f, 0.f, 0.f, 0.f}, o1 = o0;
  #pragma unroll
  for (int kk = 0; kk < 8; ++kk){
    short8 pb = *reinterpret_cast<const short8*>(&Pw[l16 * 264 + kk * 32 + quad * 8]);
    short8 a0 = *reinterpret_cast<const short8*>(&lds[l16 * 264 + kk * 32 + quad * 8]);
    short8 a1 = *reinterpret_cast<const short8*>(&lds[(16 + l16) * 264 + kk * 32 + quad * 8]);
    o0 = __builtin_amdgcn_mfma_f32_16x16x32_bf16(a0, pb, o0, 0, 0, 0);
    o1 = __builtin_amdgcn_mfma_f32_16x16x32_bf16(a1, pb, o1, 0, 0, 0);
  }
  float inv = 1.f / den;
  size_t obase = ((size_t)rl * 64 + w * 16 + l16) * 256 + (size_t)h * 32;
  unsigned pk0 = (unsigned)f2bu(o0[0] * inv) | ((unsigned)f2bu(o0[1] * inv) << 16);
  unsigned pk1 = (unsigned)f2bu(o0[2] * inv) | ((unsigned)f2bu(o0[3] * inv) << 16);
  unsigned pk2 = (unsigned)f2bu(o1[0] * inv) | ((unsigned)f2bu(o1[1] * inv) << 16);
  unsigned pk3 = (unsigned)f2bu(o1[2] * inv) | ((unsigned)f2bu(o1[3] * inv) << 16);
  *reinterpret_cast<uint2*>(o_out + obase + quad * 4)      = make_uint2(pk0, pk1);
  *reinterpret_cast<uint2*>(o_out + obase + 16 + quad * 4) = make_uint2(pk2, pk3);
}

// -------------------------------------------------------------------------------
// STRICT ws budget (never write beyond ws_size):
//   [0,4MB)   misc: BN sums/coeffs, idxb, smr, qkm, bf16 weights, bn2 partials
//   [4,20MB)  s1 (branch1) then s2 (branch2), bf16 16MB
//   [20MB,..) chunk buffers (branch1 only now), adaptively sized from ws_size.
// x2 (fp32 [32768,256], 32MB) lives in d_out; fused FFN updates d_out in place.
// Minimum ws_size supported: 28MB.
extern "C" void kernel_launch(void* const* d_in, const int* in_sizes, int n_in,
                              void* d_out, int out_size, void* d_ws, size_t ws_size,
                              hipStream_t stream)
{
  const float* x      = (const float*)d_in[0];
  const float* bn1_g  = (const float*)d_in[1];
  const float* bn1_b  = (const float*)d_in[2];
  const float* bn2_g  = (const float*)d_in[3];
  const float* bn2_b  = (const float*)d_in[4];
  const float* qkv_w  = (const float*)d_in[5];
  const float* qkv_b  = (const float*)d_in[6];
  const float* proj_w = (const float*)d_in[7];
  const float* proj_b = (const float*)d_in[8];
  const float* ffn_w1 = (const float*)d_in[9];
  const float* ffn_b1 = (const float*)d_in[10];
  const float* ffn_w2 = (const float*)d_in[11];
  const float* ffn_b2 = (const float*)d_in[12];
  const float* scale  = (const float*)d_in[13];
  float* x2 = (float*)d_out;       // residual lives in d_out

  char* ws = (char*)d_ws;
  const size_t MB = 1024 * 1024;
  float* sum1 = (float*)(ws + 0);
  float* sq1  = (float*)(ws + 1024);
  float* a1   = (float*)(ws + 4096);
  float* b1   = (float*)(ws + 5120);
  float* a2   = (float*)(ws + 6144);
  float* b2   = (float*)(ws + 7168);
  int*   idxb = (int*)(ws + 8192);                              // 8KB
  float* smr  = (float*)(ws + 16384);                           // 512KB
  float* qkm  = (float*)(ws + 540672);                          // 1MB
  __hip_bfloat16* qkv_wb  = (__hip_bfloat16*)(ws + 1589248);    // 384KB
  __hip_bfloat16* proj_wb = (__hip_bfloat16*)(ws + 1982464);    // 128KB
  __hip_bfloat16* ffn_w1b = (__hip_bfloat16*)(ws + 2113536);    // 512KB
  __hip_bfloat16* ffn_w2b = (__hip_bfloat16*)(ws + 2637824);    // 512KB, ends 3162112
  float* ppsum = (float*)(ws + 3162112);                        // 512KB (512x256 f32)
  float* ppsq  = (float*)(ws + 3686400);                        // 512KB, ends 4MB exactly
  __hip_bfloat16* s1 = (__hip_bfloat16*)(ws + 4 * MB);          // 16MB (s2 reuses)
  __hip_bfloat16* s2 = s1;
  char* chunkbuf = ws + 20 * MB;

  // adaptive chunk sizes from ws_size (constant across calls -> graph-safe)
  size_t avail = (ws_size > 20 * MB) ? (ws_size - 20 * MB) : (8 * MB);
  int nc = (avail >= 64 * MB) ? 8 : (avail >= 32 * MB) ? 4 : (avail >= 16 * MB) ? 2 : 1;   // samples/chunk (8MB each)

  __hip_bfloat16* qkvc = (__hip_bfloat16*)chunkbuf;                        // nc*6MB
  __hip_bfloat16* oc   = (__hip_bfloat16*)(chunkbuf + (size_t)nc * 6 * MB); // nc*2MB

  hipMemsetAsync(d_ws, 0, 4096, stream);   // zero BN1 accumulators

  // one-time weight conversions fp32 -> bf16 (single launch)
  f2ball_k<<<3072, 256, 0, stream>>>(qkv_w, proj_w, ffn_w1, ffn_w2,
                                     qkv_wb, proj_wb, ffn_w1b, ffn_w2b);

  // branch 1: BN -> LIF -> routing, then per-chunk qkv -> attn -> proj+residual
  bn_stats_k<<<256, 256, 0, stream>>>(x, sum1, sq1);
  bn_fin_k<<<1, 256, 0, stream>>>(sum1, sq1, bn1_g, bn1_b, a1, b1);
  lif_k<<<PERT / 1024, 256, 0, stream>>>(x, a1, b1, s1);
  region_sum_k<<<512, 256, 0, stream>>>(s1, smr);
  rgemm_k<<<512, 256, 0, stream>>>(smr, qkv_w, qkv_b, qkm);   // fp32 routing (flip-proof)
  topk_k<<<512, 64, 0, stream>>>(qkm, idxb);

  const int nchunkA = 8 / nc;
  for (int c = 0; c < nchunkA; ++c){
    const size_t ro = (size_t)c * nc * SAMP_TOK;            // row offset (tokens)
    gemm_bt<0><<<dim3(nc * SAMP_TOK / 128, 6), 256, 0, stream>>>(
        s1 + ro * 256, qkv_wb, qkv_b, qkvc, nullptr, nullptr, nullptr, nullptr, 256, 768);
    attn_mfma_k<<<dim3(nc * 64, 8), 256, 0, stream>>>(qkvc, idxb, oc, c * nc * 64);
    gemm_bt<1><<<dim3(nc * SAMP_TOK / 128, 2), 256, 0, stream>>>(
        oc, proj_wb, proj_b, x2 + ro * 256, x + ro * 256, scale,
        ppsum + (ro >> 6) * 256, ppsq + (ro >> 6) * 256, 256, 256);
  }

  // branch 2: bn2 partial-reduce (atomic-free) -> LIF -> fused FFN (in-place)
  bn_red_k<<<1, 256, 0, stream>>>(ppsum, ppsq, bn2_g, bn2_b, a2, b2);
  lif_k<<<PERT / 1024, 256, 0, stream>>>(x2, a2, b2, s2);
  ffn_fused_k<<<512, 512, 0, stream>>>(s2, ffn_w1b, ffn_b1, ffn_w2b, ffn_b2, x2, scale);
}